// Round 1
// baseline (2155.814 us; speedup 1.0000x reference)
//
#include <hip/hip_runtime.h>
#include <math.h>

#define N_NODES 10000
#define NFEAT   2000
#define NFE     256
#define NH      128
#define NHE     64
#define NOUT    20
#define DCAT    192   // NH + NHE
#define BN_EPS  1e-5f
#define BKK     16

__device__ __forceinline__ float sigm(float x) { return 1.0f / (1.0f + expf(-x)); }

// ---------------------------------------------------------------------------
// rowsum of adj: one block per row
// ---------------------------------------------------------------------------
__global__ __launch_bounds__(256) void rowsum_kernel(const float* __restrict__ adj,
                                                     float* __restrict__ s)
{
    const int r = blockIdx.x;
    const float4* row = (const float4*)(adj + (size_t)r * N_NODES);
    const int nf4 = N_NODES / 4; // 2500
    float acc = 0.f;
    for (int i = threadIdx.x; i < nf4; i += 256) {
        float4 v = row[i];
        acc += v.x + v.y + v.z + v.w;
    }
    #pragma unroll
    for (int msk = 32; msk >= 1; msk >>= 1) acc += __shfl_xor(acc, msk);
    __shared__ float wsum[4];
    if ((threadIdx.x & 63) == 0) wsum[threadIdx.x >> 6] = acc;
    __syncthreads();
    if (threadIdx.x == 0) s[r] = wsum[0] + wsum[1] + wsum[2] + wsum[3];
}

// ---------------------------------------------------------------------------
// adjmm: neigh = (adj @ h) / s   (row-normalized mean aggregation)
// BM=32, BN=128(full), BK=16.  256 thr, 4x4 acc/thread.
// ---------------------------------------------------------------------------
__global__ __launch_bounds__(256) void adjmm_kernel(const float* __restrict__ adj,
                                                    const float* __restrict__ h,
                                                    const float* __restrict__ s,
                                                    float* __restrict__ neigh)
{
    constexpr int BM = 32, LDAP = BM + 4, LDBP = 128 + 4;
    __shared__ float sa[BKK * LDAP];
    __shared__ float sb[BKK * LDBP];
    const int tid = threadIdx.x;
    const int tx = tid & 31, ty = tid >> 5;
    const int m0 = blockIdx.x * BM;
    float acc[4][4] = {};
    for (int k0 = 0; k0 < N_NODES; k0 += BKK) {
        if (tid < 128) {
            int row = tid >> 2, kq = tid & 3;
            int mg = m0 + row; if (mg > N_NODES - 1) mg = N_NODES - 1;
            float4 v = *(const float4*)(adj + (size_t)mg * N_NODES + k0 + kq * 4);
            int kb = kq * 4;
            sa[(kb + 0) * LDAP + row] = v.x;
            sa[(kb + 1) * LDAP + row] = v.y;
            sa[(kb + 2) * LDAP + row] = v.z;
            sa[(kb + 3) * LDAP + row] = v.w;
        }
        #pragma unroll
        for (int t = 0; t < 2; ++t) {
            int fb = tid + t * 256;
            int kk = fb >> 5, n4 = fb & 31;
            float4 v = *(const float4*)(h + (size_t)(k0 + kk) * NH + n4 * 4);
            *(float4*)&sb[kk * LDBP + n4 * 4] = v;
        }
        __syncthreads();
        #pragma unroll
        for (int kk = 0; kk < BKK; ++kk) {
            float4 av = *(const float4*)&sa[kk * LDAP + ty * 4];
            float4 bv = *(const float4*)&sb[kk * LDBP + tx * 4];
            float ar[4] = {av.x, av.y, av.z, av.w};
            float br[4] = {bv.x, bv.y, bv.z, bv.w};
            #pragma unroll
            for (int i = 0; i < 4; ++i)
                #pragma unroll
                for (int j = 0; j < 4; ++j)
                    acc[i][j] += ar[i] * br[j];
        }
        __syncthreads();
    }
    #pragma unroll
    for (int i = 0; i < 4; ++i) {
        int m = m0 + ty * 4 + i;
        if (m < N_NODES) {
            float inv = 1.0f / s[m];
            float4 o;
            o.x = acc[i][0] * inv; o.y = acc[i][1] * inv;
            o.z = acc[i][2] * inv; o.w = acc[i][3] * inv;
            *(float4*)&neigh[(size_t)m * NH + tx * 4] = o;
        }
    }
}

// ---------------------------------------------------------------------------
// Generic weight GEMM:  out[m, n0+n] = sum_k A[m,k] * B[n,k]  (+ epilogue)
// A may be a virtual concat (a1 | a2) split at kSplitA; same for B at kSplitB.
// EPI: 1 = bias+BN+ELU   2 = bias+ReLU+row-normalize (needs BN==128, grid.y==1)
//      3 = bias1+bias2 (LSTM z)
// ---------------------------------------------------------------------------
template<int BM, int BN, int EPI>
__global__ __launch_bounds__(256) void wgemm_kernel(
    int M, int K, int kSplitA,
    const float* __restrict__ a1, int lda1,
    const float* __restrict__ a2, int lda2,
    int kSplitB,
    const float* __restrict__ b1, int ldb1,
    const float* __restrict__ b2, int ldb2,
    float* __restrict__ out, int ldo,
    const float* __restrict__ bias1, const float* __restrict__ bias2,
    const float* __restrict__ bng, const float* __restrict__ bnb,
    const float* __restrict__ bnrm, const float* __restrict__ bnrv)
{
    constexpr int TX = BN / 4;
    constexpr int TY = 256 / TX;
    static_assert(TY * 4 == BM, "geometry");
    static_assert(EPI != 2 || TX == 32, "rownorm needs TX==32");
    constexpr int LDAP = BM + 4, LDBP = BN + 4;
    __shared__ float sa[BKK * LDAP];
    __shared__ float sb[BKK * LDBP];
    const int tid = threadIdx.x;
    const int tx = tid % TX, ty = tid / TX;
    const int m0 = blockIdx.x * BM, n0 = blockIdx.y * BN;
    float acc[4][4] = {};
    constexpr int AF4 = BM * BKK / 4;
    constexpr int BF4 = BN * BKK / 4;
    for (int k0 = 0; k0 < K; k0 += BKK) {
        #pragma unroll
        for (int t = 0; t < (AF4 + 255) / 256; ++t) {
            int fa = tid + t * 256;
            if ((AF4 % 256 == 0) || (fa < AF4)) {
                int row = fa >> 2, kq = fa & 3;
                int mg = m0 + row; if (mg > M - 1) mg = M - 1;
                int kg = k0 + kq * 4;
                const float* src = (kg < kSplitA) ? (a1 + (size_t)mg * lda1 + kg)
                                                  : (a2 + (size_t)mg * lda2 + (kg - kSplitA));
                float4 v = *(const float4*)src;
                int kb = kq * 4;
                sa[(kb + 0) * LDAP + row] = v.x;
                sa[(kb + 1) * LDAP + row] = v.y;
                sa[(kb + 2) * LDAP + row] = v.z;
                sa[(kb + 3) * LDAP + row] = v.w;
            }
        }
        #pragma unroll
        for (int t = 0; t < (BF4 + 255) / 256; ++t) {
            int fb = tid + t * 256;
            if ((BF4 % 256 == 0) || (fb < BF4)) {
                int n = fb >> 2, kq = fb & 3;
                int ng = n0 + n;
                int kg = k0 + kq * 4;
                const float* src = (kg < kSplitB) ? (b1 + (size_t)ng * ldb1 + kg)
                                                  : (b2 + (size_t)ng * ldb2 + (kg - kSplitB));
                float4 v = *(const float4*)src;
                int kb = kq * 4;
                sb[(kb + 0) * LDBP + n] = v.x;
                sb[(kb + 1) * LDBP + n] = v.y;
                sb[(kb + 2) * LDBP + n] = v.z;
                sb[(kb + 3) * LDBP + n] = v.w;
            }
        }
        __syncthreads();
        #pragma unroll
        for (int kk = 0; kk < BKK; ++kk) {
            float4 av = *(const float4*)&sa[kk * LDAP + ty * 4];
            float4 bv = *(const float4*)&sb[kk * LDBP + tx * 4];
            float ar[4] = {av.x, av.y, av.z, av.w};
            float br[4] = {bv.x, bv.y, bv.z, bv.w};
            #pragma unroll
            for (int i = 0; i < 4; ++i)
                #pragma unroll
                for (int j = 0; j < 4; ++j)
                    acc[i][j] += ar[i] * br[j];
        }
        __syncthreads();
    }
    const int nb = n0 + tx * 4;
    if constexpr (EPI == 2) {
        float v[4][4]; float ssq[4] = {0.f, 0.f, 0.f, 0.f};
        #pragma unroll
        for (int i = 0; i < 4; ++i)
            #pragma unroll
            for (int j = 0; j < 4; ++j) {
                float t = acc[i][j] + bias1[nb + j];
                t = fmaxf(t, 0.f);
                v[i][j] = t; ssq[i] += t * t;
            }
        #pragma unroll
        for (int msk = 1; msk < 32; msk <<= 1) {
            #pragma unroll
            for (int i = 0; i < 4; ++i) ssq[i] += __shfl_xor(ssq[i], msk);
        }
        #pragma unroll
        for (int i = 0; i < 4; ++i) {
            int m = m0 + ty * 4 + i;
            if (m < M) {
                float sc = 1.0f / fmaxf(sqrtf(ssq[i]), 1e-12f);
                float4 o;
                o.x = v[i][0] * sc; o.y = v[i][1] * sc;
                o.z = v[i][2] * sc; o.w = v[i][3] * sc;
                *(float4*)&out[(size_t)m * ldo + nb] = o;
            }
        }
    } else {
        float bvv[4];
        #pragma unroll
        for (int j = 0; j < 4; ++j) {
            float bb = bias1[nb + j];
            if constexpr (EPI == 3) bb += bias2[nb + j];
            bvv[j] = bb;
        }
        float scv[4], shv[4];
        if constexpr (EPI == 1) {
            #pragma unroll
            for (int j = 0; j < 4; ++j) {
                float sc = bng[nb + j] / sqrtf(bnrv[nb + j] + BN_EPS);
                scv[j] = sc;
                shv[j] = bnb[nb + j] - bnrm[nb + j] * sc;
            }
        }
        #pragma unroll
        for (int i = 0; i < 4; ++i) {
            int m = m0 + ty * 4 + i;
            if (m < M) {
                float o[4];
                #pragma unroll
                for (int j = 0; j < 4; ++j) {
                    float t = acc[i][j] + bvv[j];
                    if constexpr (EPI == 1) {
                        t = t * scv[j] + shv[j];
                        t = t > 0.f ? t : expm1f(t);
                    }
                    o[j] = t;
                }
                float4 ov; ov.x = o[0]; ov.y = o[1]; ov.z = o[2]; ov.w = o[3];
                *(float4*)&out[(size_t)m * ldo + nb] = ov;
            }
        }
    }
}

// ---------------------------------------------------------------------------
// LSTM gate kernel: z [N,512] (i,f,g,o), c_prev -> h_out, c_out
// ---------------------------------------------------------------------------
__global__ __launch_bounds__(256) void lstm_gate_kernel(const float* __restrict__ z,
                                                        const float* __restrict__ cprev,
                                                        float* __restrict__ hout,
                                                        float* __restrict__ cout)
{
    int idx = blockIdx.x * 256 + threadIdx.x;            // float4 index
    if (idx >= N_NODES * NH / 4) return;
    int m = idx >> 5, c4 = (idx & 31) * 4;
    const float* zr = z + (size_t)m * 512 + c4;
    float4 zi = *(const float4*)(zr);
    float4 zf = *(const float4*)(zr + 128);
    float4 zg = *(const float4*)(zr + 256);
    float4 zo = *(const float4*)(zr + 384);
    float4 cp = *(const float4*)(cprev + (size_t)m * NH + c4);
    float zia[4] = {zi.x, zi.y, zi.z, zi.w};
    float zfa[4] = {zf.x, zf.y, zf.z, zf.w};
    float zga[4] = {zg.x, zg.y, zg.z, zg.w};
    float zoa[4] = {zo.x, zo.y, zo.z, zo.w};
    float cpa[4] = {cp.x, cp.y, cp.z, cp.w};
    float ho[4], co[4];
    #pragma unroll
    for (int j = 0; j < 4; ++j) {
        float ig = sigm(zia[j]);
        float fg = sigm(zfa[j]);
        float gg = tanhf(zga[j]);
        float og = sigm(zoa[j]);
        float cn = fg * cpa[j] + ig * gg;
        co[j] = cn;
        ho[j] = og * tanhf(cn);
    }
    float4 hv; hv.x = ho[0]; hv.y = ho[1]; hv.z = ho[2]; hv.w = ho[3];
    float4 cv; cv.x = co[0]; cv.y = co[1]; cv.z = co[2]; cv.w = co[3];
    *(float4*)(hout + (size_t)m * NH + c4) = hv;
    *(float4*)(cout + (size_t)m * NH + c4) = cv;
}

// ---------------------------------------------------------------------------
// hpost = elu(bn_in(0.5*(a+b)))  elementwise over [N, NH]
// ---------------------------------------------------------------------------
__global__ __launch_bounds__(256) void jkmean_bnelu_kernel(const float* __restrict__ a,
                                                           const float* __restrict__ b,
                                                           const float* __restrict__ g,
                                                           const float* __restrict__ bb,
                                                           const float* __restrict__ rm,
                                                           const float* __restrict__ rv,
                                                           float* __restrict__ out)
{
    int idx = blockIdx.x * 256 + threadIdx.x;            // float4 index
    if (idx >= N_NODES * NH / 4) return;
    int c4 = (idx & 31) * 4;
    float4 va = *(const float4*)(a + (size_t)idx * 4);
    float4 vb = *(const float4*)(b + (size_t)idx * 4);
    float av[4] = {va.x, va.y, va.z, va.w};
    float bv[4] = {vb.x, vb.y, vb.z, vb.w};
    float o[4];
    #pragma unroll
    for (int j = 0; j < 4; ++j) {
        int c = c4 + j;
        float t = 0.5f * (av[j] + bv[j]);
        float sc = g[c] / sqrtf(rv[c] + BN_EPS);
        t = (t - rm[c]) * sc + bb[c];
        o[j] = t > 0.f ? t : expm1f(t);
    }
    float4 ov; ov.x = o[0]; ov.y = o[1]; ov.z = o[2]; ov.w = o[3];
    *(float4*)(out + (size_t)idx * 4) = ov;
}

// ---------------------------------------------------------------------------
// out = log_softmax(hfc @ W_out.T + b_out).  One wave per row (4 rows/block).
// ---------------------------------------------------------------------------
__global__ __launch_bounds__(256) void out_kernel(const float* __restrict__ hfc,
                                                  const float* __restrict__ W_out,
                                                  const float* __restrict__ b_out,
                                                  float* __restrict__ out)
{
    __shared__ float wl[NOUT * 193];   // padded to kill bank conflicts
    __shared__ float rl[4][DCAT];
    const int tid = threadIdx.x;
    for (int i = tid; i < NOUT * DCAT; i += 256)
        wl[(i / DCAT) * 193 + (i % DCAT)] = W_out[i];
    const int w = tid >> 6, lane = tid & 63;
    const int r = blockIdx.x * 4 + w;
    for (int k = lane; k < DCAT; k += 64) rl[w][k] = hfc[(size_t)r * DCAT + k];
    __syncthreads();
    const int c = lane;
    float acc = -INFINITY;
    if (c < NOUT) {
        acc = b_out[c];
        #pragma unroll 4
        for (int k = 0; k < DCAT; ++k) acc += rl[w][k] * wl[c * 193 + k];
    }
    float mx = acc;
    #pragma unroll
    for (int msk = 16; msk >= 1; msk >>= 1) mx = fmaxf(mx, __shfl_xor(mx, msk));
    float ex = (c < NOUT) ? expf(acc - mx) : 0.f;
    float sm = ex;
    #pragma unroll
    for (int msk = 16; msk >= 1; msk >>= 1) sm += __shfl_xor(sm, msk);
    if (c < NOUT) out[(size_t)r * NOUT + c] = acc - mx - logf(sm);
}

// ---------------------------------------------------------------------------
extern "C" void kernel_launch(void* const* d_in, const int* in_sizes, int n_in,
                              void* d_out, int out_size, void* d_ws, size_t ws_size,
                              hipStream_t stream)
{
    const float* x       = (const float*)d_in[0];
    const float* embed   = (const float*)d_in[1];
    const float* adj     = (const float*)d_in[2];
    const float* W_in    = (const float*)d_in[3];
    const float* b_in    = (const float*)d_in[4];
    const float* bn_in_g = (const float*)d_in[5];
    const float* bn_in_b = (const float*)d_in[6];
    const float* bn_in_rm= (const float*)d_in[7];
    const float* bn_in_rv= (const float*)d_in[8];
    const float* W_gs    = (const float*)d_in[9];
    const float* b_gs    = (const float*)d_in[10];
    const float* Wih0    = (const float*)d_in[11];
    const float* Whh0    = (const float*)d_in[12];
    const float* bih0    = (const float*)d_in[13];
    const float* bhh0    = (const float*)d_in[14];
    const float* Wih1    = (const float*)d_in[15];
    const float* Whh1    = (const float*)d_in[16];
    const float* bih1    = (const float*)d_in[17];
    const float* bhh1    = (const float*)d_in[18];
    const float* W_emb   = (const float*)d_in[19];
    const float* b_emb   = (const float*)d_in[20];
    const float* bn_e_g  = (const float*)d_in[21];
    const float* bn_e_b  = (const float*)d_in[22];
    const float* bn_e_rm = (const float*)d_in[23];
    const float* bn_e_rv = (const float*)d_in[24];
    const float* W_fc    = (const float*)d_in[25];
    const float* b_fc    = (const float*)d_in[26];
    const float* bn_f_g  = (const float*)d_in[27];
    const float* bn_f_b  = (const float*)d_in[28];
    const float* bn_f_rm = (const float*)d_in[29];
    const float* bn_f_rv = (const float*)d_in[30];
    const float* W_out   = (const float*)d_in[31];
    const float* b_out   = (const float*)d_in[32];
    float* outp = (float*)d_out;

    // ---- workspace carve (all f32, 1KB-aligned chunks) ----
    const size_t HB = (size_t)N_NODES * NH * sizeof(float);      // 5,120,000
    char* wp = (char*)d_ws;
    auto carve = [&](size_t bytes) {
        float* p = (float*)wp;
        wp += (bytes + 1023) & ~(size_t)1023;
        return p;
    };
    float* s     = carve(N_NODES * sizeof(float));
    float* h_in  = carve(HB);
    float* neigh = carve(HB);
    float* jk0   = carve(HB);
    float* jk1   = carve(HB);
    float* zero  = carve(HB);
    float* h1_0  = carve(HB);
    float* h1_1  = carve(HB);
    float* c1    = carve(HB);
    float* h2_0  = carve(HB);
    float* h2_1  = carve(HB);
    float* c2    = carve(HB);
    float* hpost = carve(HB);
    float* z     = carve((size_t)N_NODES * 512 * sizeof(float)); // 20,480,000
    float* e     = carve((size_t)N_NODES * NHE * sizeof(float)); // 2,560,000
    float* hfc   = carve((size_t)N_NODES * DCAT * sizeof(float));// 7,680,000
    if ((size_t)(wp - (char*)d_ws) > ws_size) return;            // loud failure

    const dim3 blk(256);
    hipMemsetAsync(zero, 0, HB, stream);

    // 1. rowsum
    rowsum_kernel<<<N_NODES, blk, 0, stream>>>(adj, s);

    // 2. h = elu(bn_in(x @ W_in.T + b_in))
    wgemm_kernel<32, 128, 1><<<dim3(313, 1), blk, 0, stream>>>(
        N_NODES, NFEAT, NFEAT, x, NFEAT, nullptr, 0,
        NFEAT, W_in, NFEAT, nullptr, 0,
        h_in, NH, b_in, nullptr, bn_in_g, bn_in_b, bn_in_rm, bn_in_rv);

    // 3. layer 0: neigh = adj_norm @ h ; jk0 = normalize(relu([h|neigh]@Wgs0.T+b))
    adjmm_kernel<<<313, blk, 0, stream>>>(adj, h_in, s, neigh);
    wgemm_kernel<32, 128, 2><<<dim3(313, 1), blk, 0, stream>>>(
        N_NODES, 2 * NH, NH, h_in, NH, neigh, NH,
        2 * NH, W_gs, 2 * NH, nullptr, 0,
        jk0, NH, b_gs, nullptr, nullptr, nullptr, nullptr, nullptr);

    // 4. layer 1
    adjmm_kernel<<<313, blk, 0, stream>>>(adj, jk0, s, neigh);
    wgemm_kernel<32, 128, 2><<<dim3(313, 1), blk, 0, stream>>>(
        N_NODES, 2 * NH, NH, jk0, NH, neigh, NH,
        2 * NH, W_gs + 128 * 256, 2 * NH, nullptr, 0,
        jk1, NH, b_gs + 128, nullptr, nullptr, nullptr, nullptr, nullptr);

    // 5. LSTM jumping-knowledge (2 layers x 2 steps)
    auto lstm_step = [&](const float* xt, const float* hp,
                         const float* Wih, const float* Whh,
                         const float* bih, const float* bhh,
                         const float* cp, float* hn, float* cn) {
        wgemm_kernel<32, 128, 3><<<dim3(313, 4), blk, 0, stream>>>(
            N_NODES, 2 * NH, NH, xt, NH, hp, NH,
            NH, Wih, NH, Whh, NH,
            z, 4 * NH, bih, bhh, nullptr, nullptr, nullptr, nullptr);
        lstm_gate_kernel<<<1250, blk, 0, stream>>>(z, cp, hn, cn);
    };
    lstm_step(jk0,  zero, Wih0, Whh0, bih0, bhh0, zero, h1_0, c1);
    lstm_step(jk1,  h1_0, Wih0, Whh0, bih0, bhh0, c1,   h1_1, c1);
    lstm_step(h1_0, zero, Wih1, Whh1, bih1, bhh1, zero, h2_0, c2);
    lstm_step(h1_1, h2_0, Wih1, Whh1, bih1, bhh1, c2,   h2_1, c2);

    // 6. JK mean + bn_in + elu
    jkmean_bnelu_kernel<<<1250, blk, 0, stream>>>(h2_0, h2_1, bn_in_g, bn_in_b,
                                                  bn_in_rm, bn_in_rv, hpost);

    // 7. e = elu(bn_emb(embed @ W_emb.T + b_emb))
    wgemm_kernel<64, 64, 1><<<dim3(157, 1), blk, 0, stream>>>(
        N_NODES, NFE, NFE, embed, NFE, nullptr, 0,
        NFE, W_emb, NFE, nullptr, 0,
        e, NHE, b_emb, nullptr, bn_e_g, bn_e_b, bn_e_rm, bn_e_rv);

    // 8-9. hfc = elu(bn_fc([hpost|e] @ W_fc.T + b_fc))
    wgemm_kernel<64, 64, 1><<<dim3(157, 3), blk, 0, stream>>>(
        N_NODES, DCAT, NH, hpost, NH, e, NHE,
        DCAT, W_fc, DCAT, nullptr, 0,
        hfc, DCAT, b_fc, nullptr, bn_f_g, bn_f_b, bn_f_rm, bn_f_rv);

    // 10. logits + log_softmax
    out_kernel<<<2500, blk, 0, stream>>>(hfc, W_out, b_out, outp);
}

// Round 2
// 797.469 us; speedup vs baseline: 2.7033x; 2.7033x over previous
//
#include <hip/hip_runtime.h>
#include <hip/hip_bf16.h>
#include <math.h>

#define N_NODES 10000
#define NFEAT   2000
#define NFE     256
#define NH      128
#define NHE     64
#define NOUT    20
#define DCAT    192   // NH + NHE
#define BN_EPS  1e-5f
#define BKK     16

#define KP      10016        // N_NODES padded to multiple of 32 (bf16 K-dim)
#define KSTEPS  313          // KP / 32
#define MT      157          // ceil(N_NODES / 64) m-tiles
#define NSPLIT  8
#define KC      40           // ceil(KSTEPS / NSPLIT)

typedef __attribute__((ext_vector_type(8))) short  bf16x8;
typedef __attribute__((ext_vector_type(4))) float  f32x4;

__device__ __forceinline__ float sigm(float x) { return 1.0f / (1.0f + expf(-x)); }

__device__ __forceinline__ unsigned short f2bf(float x) {
    union { __hip_bfloat16 h; unsigned short u; } c;
    c.h = __float2bfloat16(x);
    return c.u;
}

// ---------------------------------------------------------------------------
// adj f32 -> bf16 (K padded/zeroed to KP) + fused row-sum.  One block per row.
// ---------------------------------------------------------------------------
__global__ __launch_bounds__(256) void adj_conv_kernel(const float* __restrict__ adj,
                                                       unsigned short* __restrict__ adjb,
                                                       float* __restrict__ s)
{
    const int r = blockIdx.x;
    const float4* row = (const float4*)(adj + (size_t)r * N_NODES);
    unsigned short* orow = adjb + (size_t)r * KP;
    float acc = 0.f;
    for (int i = threadIdx.x; i < N_NODES / 4; i += 256) {
        float4 v = row[i];
        acc += v.x + v.y + v.z + v.w;
        ushort4 o;
        o.x = f2bf(v.x); o.y = f2bf(v.y); o.z = f2bf(v.z); o.w = f2bf(v.w);
        *(ushort4*)(orow + i * 4) = o;
    }
    if (threadIdx.x < 4) {  // zero the K pad (10000..10015)
        ushort4 zz; zz.x = zz.y = zz.z = zz.w = 0;
        *(ushort4*)(orow + N_NODES + threadIdx.x * 4) = zz;
    }
    #pragma unroll
    for (int msk = 32; msk >= 1; msk >>= 1) acc += __shfl_xor(acc, msk);
    __shared__ float wsum[4];
    if ((threadIdx.x & 63) == 0) wsum[threadIdx.x >> 6] = acc;
    __syncthreads();
    if (threadIdx.x == 0) s[r] = wsum[0] + wsum[1] + wsum[2] + wsum[3];
}

// ---------------------------------------------------------------------------
// h [N_NODES][NH] f32  ->  hT [NH][KP] bf16 (transposed, K-pad zeroed)
// grid: (KP/32 = 313, NH/32 = 4), 32x32 tiles via LDS
// ---------------------------------------------------------------------------
__global__ __launch_bounds__(256) void htrans_kernel(const float* __restrict__ h,
                                                     unsigned short* __restrict__ hT)
{
    __shared__ float t[32][36];
    const int k0 = blockIdx.x * 32, c0 = blockIdx.y * 32;
    {
        int r = threadIdx.x >> 3, ci = threadIdx.x & 7;
        int kg = k0 + r;
        float4 v = {0.f, 0.f, 0.f, 0.f};
        if (kg < N_NODES) v = *(const float4*)(h + (size_t)kg * NH + c0 + ci * 4);
        t[r][ci * 4 + 0] = v.x; t[r][ci * 4 + 1] = v.y;
        t[r][ci * 4 + 2] = v.z; t[r][ci * 4 + 3] = v.w;
    }
    __syncthreads();
    {
        int c = threadIdx.x >> 3, ki = threadIdx.x & 7;
        ushort4 o;
        o.x = f2bf(t[ki * 4 + 0][c]); o.y = f2bf(t[ki * 4 + 1][c]);
        o.z = f2bf(t[ki * 4 + 2][c]); o.w = f2bf(t[ki * 4 + 3][c]);
        *(ushort4*)(hT + (size_t)(c0 + c) * KP + k0 + ki * 4) = o;
    }
}

// ---------------------------------------------------------------------------
// MFMA split-K:  part[chunk] += adjb[64-row tile] @ hT^T   (bf16 -> f32)
// grid (MT, NSPLIT), 256 thr = 4 waves, each wave owns 32x64 of the 64x128 tile
// ---------------------------------------------------------------------------
__global__ __launch_bounds__(256) void adjmm_mfma_kernel(const unsigned short* __restrict__ adjb,
                                                         const unsigned short* __restrict__ hT,
                                                         float* __restrict__ part)
{
    __shared__ unsigned short sa[64 * 32];   // adj tile  [64 rows][32 k]
    __shared__ unsigned short sb[128 * 32];  // hT tile   [128 cols][32 k]
    const int tid  = threadIdx.x;
    const int lane = tid & 63, w = tid >> 6;
    const int m0   = blockIdx.x * 64;
    const int ks0  = blockIdx.y * KC;
    const int ks1  = min(ks0 + KC, KSTEPS);
    const int r0   = (w & 1) * 32;           // wave row base within tile
    const int c0   = (w >> 1) * 64;          // wave col base within tile

    // staging coords
    const int arow = tid >> 2, agrp = tid & 3;              // 64 rows x 4 granules
    const size_t abase = (size_t)min(m0 + arow, N_NODES - 1) * KP;
    const int bcol = tid >> 1, bg0 = (tid & 1) * 2;         // 128 cols x 2 granules each

    // fragment read offsets (XOR-swizzled 16B granules, same involution as store)
    f32x4 acc[2][4];
    #pragma unroll
    for (int i = 0; i < 2; ++i)
        #pragma unroll
        for (int j = 0; j < 4; ++j) acc[i][j] = (f32x4){0.f, 0.f, 0.f, 0.f};

    for (int ks = ks0; ks < ks1; ++ks) {
        const int k0 = ks * 32;
        bf16x8 va  = *(const bf16x8*)(adjb + abase + k0 + agrp * 8);
        bf16x8 vb0 = *(const bf16x8*)(hT + (size_t)bcol * KP + k0 + bg0 * 8);
        bf16x8 vb1 = *(const bf16x8*)(hT + (size_t)bcol * KP + k0 + (bg0 + 1) * 8);
        __syncthreads();   // previous iter's reads done before overwrite
        *(bf16x8*)(sa + arow * 32 + ((agrp ^ (arow & 3)) << 3)) = va;
        *(bf16x8*)(sb + bcol * 32 + (((bg0 + 0) ^ (bcol & 3)) << 3)) = vb0;
        *(bf16x8*)(sb + bcol * 32 + (((bg0 + 1) ^ (bcol & 3)) << 3)) = vb1;
        __syncthreads();
        bf16x8 av[2], bv[4];
        #pragma unroll
        for (int rb = 0; rb < 2; ++rb) {
            int row = r0 + rb * 16 + (lane & 15);
            int g   = lane >> 4;
            av[rb] = *(const bf16x8*)(sa + row * 32 + ((g ^ (row & 3)) << 3));
        }
        #pragma unroll
        for (int cb = 0; cb < 4; ++cb) {
            int col = c0 + cb * 16 + (lane & 15);
            int g   = lane >> 4;
            bv[cb] = *(const bf16x8*)(sb + col * 32 + ((g ^ (col & 3)) << 3));
        }
        #pragma unroll
        for (int rb = 0; rb < 2; ++rb)
            #pragma unroll
            for (int cb = 0; cb < 4; ++cb)
                acc[rb][cb] = __builtin_amdgcn_mfma_f32_16x16x32_bf16(av[rb], bv[cb],
                                                                      acc[rb][cb], 0, 0, 0);
    }

    // C/D layout (m89): col = lane&15, row = (lane>>4)*4 + reg
    float* pout = part + (size_t)blockIdx.y * (MT * 64) * NH;
    #pragma unroll
    for (int rb = 0; rb < 2; ++rb) {
        #pragma unroll
        for (int cb = 0; cb < 4; ++cb) {
            int rowb = m0 + r0 + rb * 16 + (lane >> 4) * 4;
            int col  = c0 + cb * 16 + (lane & 15);
            #pragma unroll
            for (int reg = 0; reg < 4; ++reg)
                pout[(size_t)(rowb + reg) * NH + col] = acc[rb][cb][reg];
        }
    }
}

// ---------------------------------------------------------------------------
// neigh[m][c] = (sum over chunks of part) / s[m]
// ---------------------------------------------------------------------------
__global__ __launch_bounds__(256) void nreduce_kernel(const float* __restrict__ part,
                                                      const float* __restrict__ s,
                                                      float* __restrict__ neigh)
{
    int idx = blockIdx.x * 256 + threadIdx.x;   // float4 index over [N_NODES][NH]
    if (idx >= N_NODES * NH / 4) return;
    const int m = idx >> 5;
    const size_t ch = (size_t)(MT * 64) * NH / 4;
    const float4* p = (const float4*)part;
    float a0 = 0.f, a1 = 0.f, a2 = 0.f, a3 = 0.f;
    #pragma unroll
    for (int c = 0; c < NSPLIT; ++c) {
        float4 v = p[c * ch + idx];
        a0 += v.x; a1 += v.y; a2 += v.z; a3 += v.w;
    }
    const float inv = 1.0f / s[m];
    float4 o; o.x = a0 * inv; o.y = a1 * inv; o.z = a2 * inv; o.w = a3 * inv;
    *(float4*)(neigh + (size_t)idx * 4) = o;
}

// ---------------------------------------------------------------------------
// Generic weight GEMM:  out[m, n0+n] = sum_k A[m,k] * B[n,k]  (+ epilogue)
// A may be a virtual concat (a1 | a2) split at kSplitA; same for B at kSplitB.
// EPI: 1 = bias+BN+ELU   2 = bias+ReLU+row-normalize (needs BN==128, grid.y==1)
//      3 = bias1+bias2 (LSTM z)
// ---------------------------------------------------------------------------
template<int BM, int BN, int EPI>
__global__ __launch_bounds__(256) void wgemm_kernel(
    int M, int K, int kSplitA,
    const float* __restrict__ a1, int lda1,
    const float* __restrict__ a2, int lda2,
    int kSplitB,
    const float* __restrict__ b1, int ldb1,
    const float* __restrict__ b2, int ldb2,
    float* __restrict__ out, int ldo,
    const float* __restrict__ bias1, const float* __restrict__ bias2,
    const float* __restrict__ bng, const float* __restrict__ bnb,
    const float* __restrict__ bnrm, const float* __restrict__ bnrv)
{
    constexpr int TX = BN / 4;
    constexpr int TY = 256 / TX;
    static_assert(TY * 4 == BM, "geometry");
    static_assert(EPI != 2 || TX == 32, "rownorm needs TX==32");
    constexpr int LDAP = BM + 4, LDBP = BN + 4;
    __shared__ float sa[BKK * LDAP];
    __shared__ float sb[BKK * LDBP];
    const int tid = threadIdx.x;
    const int tx = tid % TX, ty = tid / TX;
    const int m0 = blockIdx.x * BM, n0 = blockIdx.y * BN;
    float acc[4][4] = {};
    constexpr int AF4 = BM * BKK / 4;
    constexpr int BF4 = BN * BKK / 4;
    for (int k0 = 0; k0 < K; k0 += BKK) {
        #pragma unroll
        for (int t = 0; t < (AF4 + 255) / 256; ++t) {
            int fa = tid + t * 256;
            if ((AF4 % 256 == 0) || (fa < AF4)) {
                int row = fa >> 2, kq = fa & 3;
                int mg = m0 + row; if (mg > M - 1) mg = M - 1;
                int kg = k0 + kq * 4;
                const float* src = (kg < kSplitA) ? (a1 + (size_t)mg * lda1 + kg)
                                                  : (a2 + (size_t)mg * lda2 + (kg - kSplitA));
                float4 v = *(const float4*)src;
                int kb = kq * 4;
                sa[(kb + 0) * LDAP + row] = v.x;
                sa[(kb + 1) * LDAP + row] = v.y;
                sa[(kb + 2) * LDAP + row] = v.z;
                sa[(kb + 3) * LDAP + row] = v.w;
            }
        }
        #pragma unroll
        for (int t = 0; t < (BF4 + 255) / 256; ++t) {
            int fb = tid + t * 256;
            if ((BF4 % 256 == 0) || (fb < BF4)) {
                int n = fb >> 2, kq = fb & 3;
                int ng = n0 + n;
                int kg = k0 + kq * 4;
                const float* src = (kg < kSplitB) ? (b1 + (size_t)ng * ldb1 + kg)
                                                  : (b2 + (size_t)ng * ldb2 + (kg - kSplitB));
                float4 v = *(const float4*)src;
                int kb = kq * 4;
                sb[(kb + 0) * LDBP + n] = v.x;
                sb[(kb + 1) * LDBP + n] = v.y;
                sb[(kb + 2) * LDBP + n] = v.z;
                sb[(kb + 3) * LDBP + n] = v.w;
            }
        }
        __syncthreads();
        #pragma unroll
        for (int kk = 0; kk < BKK; ++kk) {
            float4 av = *(const float4*)&sa[kk * LDAP + ty * 4];
            float4 bv = *(const float4*)&sb[kk * LDBP + tx * 4];
            float ar[4] = {av.x, av.y, av.z, av.w};
            float br[4] = {bv.x, bv.y, bv.z, bv.w};
            #pragma unroll
            for (int i = 0; i < 4; ++i)
                #pragma unroll
                for (int j = 0; j < 4; ++j)
                    acc[i][j] += ar[i] * br[j];
        }
        __syncthreads();
    }
    const int nb = n0 + tx * 4;
    if constexpr (EPI == 2) {
        float v[4][4]; float ssq[4] = {0.f, 0.f, 0.f, 0.f};
        #pragma unroll
        for (int i = 0; i < 4; ++i)
            #pragma unroll
            for (int j = 0; j < 4; ++j) {
                float t = acc[i][j] + bias1[nb + j];
                t = fmaxf(t, 0.f);
                v[i][j] = t; ssq[i] += t * t;
            }
        #pragma unroll
        for (int msk = 1; msk < 32; msk <<= 1) {
            #pragma unroll
            for (int i = 0; i < 4; ++i) ssq[i] += __shfl_xor(ssq[i], msk);
        }
        #pragma unroll
        for (int i = 0; i < 4; ++i) {
            int m = m0 + ty * 4 + i;
            if (m < M) {
                float sc = 1.0f / fmaxf(sqrtf(ssq[i]), 1e-12f);
                float4 o;
                o.x = v[i][0] * sc; o.y = v[i][1] * sc;
                o.z = v[i][2] * sc; o.w = v[i][3] * sc;
                *(float4*)&out[(size_t)m * ldo + nb] = o;
            }
        }
    } else {
        float bvv[4];
        #pragma unroll
        for (int j = 0; j < 4; ++j) {
            float bb = bias1[nb + j];
            if constexpr (EPI == 3) bb += bias2[nb + j];
            bvv[j] = bb;
        }
        float scv[4], shv[4];
        if constexpr (EPI == 1) {
            #pragma unroll
            for (int j = 0; j < 4; ++j) {
                float sc = bng[nb + j] / sqrtf(bnrv[nb + j] + BN_EPS);
                scv[j] = sc;
                shv[j] = bnb[nb + j] - bnrm[nb + j] * sc;
            }
        }
        #pragma unroll
        for (int i = 0; i < 4; ++i) {
            int m = m0 + ty * 4 + i;
            if (m < M) {
                float o[4];
                #pragma unroll
                for (int j = 0; j < 4; ++j) {
                    float t = acc[i][j] + bvv[j];
                    if constexpr (EPI == 1) {
                        t = t * scv[j] + shv[j];
                        t = t > 0.f ? t : expm1f(t);
                    }
                    o[j] = t;
                }
                float4 ov; ov.x = o[0]; ov.y = o[1]; ov.z = o[2]; ov.w = o[3];
                *(float4*)&out[(size_t)m * ldo + nb] = ov;
            }
        }
    }
}

// ---------------------------------------------------------------------------
// LSTM gate kernel: z [N,512] (i,f,g,o), c_prev -> h_out, c_out
// ---------------------------------------------------------------------------
__global__ __launch_bounds__(256) void lstm_gate_kernel(const float* __restrict__ z,
                                                        const float* __restrict__ cprev,
                                                        float* __restrict__ hout,
                                                        float* __restrict__ cout)
{
    int idx = blockIdx.x * 256 + threadIdx.x;            // float4 index
    if (idx >= N_NODES * NH / 4) return;
    int m = idx >> 5, c4 = (idx & 31) * 4;
    const float* zr = z + (size_t)m * 512 + c4;
    float4 zi = *(const float4*)(zr);
    float4 zf = *(const float4*)(zr + 128);
    float4 zg = *(const float4*)(zr + 256);
    float4 zo = *(const float4*)(zr + 384);
    float4 cp = *(const float4*)(cprev + (size_t)m * NH + c4);
    float zia[4] = {zi.x, zi.y, zi.z, zi.w};
    float zfa[4] = {zf.x, zf.y, zf.z, zf.w};
    float zga[4] = {zg.x, zg.y, zg.z, zg.w};
    float zoa[4] = {zo.x, zo.y, zo.z, zo.w};
    float cpa[4] = {cp.x, cp.y, cp.z, cp.w};
    float ho[4], co[4];
    #pragma unroll
    for (int j = 0; j < 4; ++j) {
        float ig = sigm(zia[j]);
        float fg = sigm(zfa[j]);
        float gg = tanhf(zga[j]);
        float og = sigm(zoa[j]);
        float cn = fg * cpa[j] + ig * gg;
        co[j] = cn;
        ho[j] = og * tanhf(cn);
    }
    float4 hv; hv.x = ho[0]; hv.y = ho[1]; hv.z = ho[2]; hv.w = ho[3];
    float4 cv; cv.x = co[0]; cv.y = co[1]; cv.z = co[2]; cv.w = co[3];
    *(float4*)(hout + (size_t)m * NH + c4) = hv;
    *(float4*)(cout + (size_t)m * NH + c4) = cv;
}

// ---------------------------------------------------------------------------
// hpost = elu(bn_in(0.5*(a+b)))  elementwise over [N, NH]
// ---------------------------------------------------------------------------
__global__ __launch_bounds__(256) void jkmean_bnelu_kernel(const float* __restrict__ a,
                                                           const float* __restrict__ b,
                                                           const float* __restrict__ g,
                                                           const float* __restrict__ bb,
                                                           const float* __restrict__ rm,
                                                           const float* __restrict__ rv,
                                                           float* __restrict__ out)
{
    int idx = blockIdx.x * 256 + threadIdx.x;            // float4 index
    if (idx >= N_NODES * NH / 4) return;
    int c4 = (idx & 31) * 4;
    float4 va = *(const float4*)(a + (size_t)idx * 4);
    float4 vb = *(const float4*)(b + (size_t)idx * 4);
    float av[4] = {va.x, va.y, va.z, va.w};
    float bv[4] = {vb.x, vb.y, vb.z, vb.w};
    float o[4];
    #pragma unroll
    for (int j = 0; j < 4; ++j) {
        int c = c4 + j;
        float t = 0.5f * (av[j] + bv[j]);
        float sc = g[c] / sqrtf(rv[c] + BN_EPS);
        t = (t - rm[c]) * sc + bb[c];
        o[j] = t > 0.f ? t : expm1f(t);
    }
    float4 ov; ov.x = o[0]; ov.y = o[1]; ov.z = o[2]; ov.w = o[3];
    *(float4*)(out + (size_t)idx * 4) = ov;
}

// ---------------------------------------------------------------------------
// out = log_softmax(hfc @ W_out.T + b_out).  One wave per row (4 rows/block).
// ---------------------------------------------------------------------------
__global__ __launch_bounds__(256) void out_kernel(const float* __restrict__ hfc,
                                                  const float* __restrict__ W_out,
                                                  const float* __restrict__ b_out,
                                                  float* __restrict__ out)
{
    __shared__ float wl[NOUT * 193];   // padded to kill bank conflicts
    __shared__ float rl[4][DCAT];
    const int tid = threadIdx.x;
    for (int i = tid; i < NOUT * DCAT; i += 256)
        wl[(i / DCAT) * 193 + (i % DCAT)] = W_out[i];
    const int w = tid >> 6, lane = tid & 63;
    const int r = blockIdx.x * 4 + w;
    for (int k = lane; k < DCAT; k += 64) rl[w][k] = hfc[(size_t)r * DCAT + k];
    __syncthreads();
    const int c = lane;
    float acc = -INFINITY;
    if (c < NOUT) {
        acc = b_out[c];
        #pragma unroll 4
        for (int k = 0; k < DCAT; ++k) acc += rl[w][k] * wl[c * 193 + k];
    }
    float mx = acc;
    #pragma unroll
    for (int msk = 16; msk >= 1; msk >>= 1) mx = fmaxf(mx, __shfl_xor(mx, msk));
    float ex = (c < NOUT) ? expf(acc - mx) : 0.f;
    float sm = ex;
    #pragma unroll
    for (int msk = 16; msk >= 1; msk >>= 1) sm += __shfl_xor(sm, msk);
    if (c < NOUT) out[(size_t)r * NOUT + c] = acc - mx - logf(sm);
}

// ---------------------------------------------------------------------------
extern "C" void kernel_launch(void* const* d_in, const int* in_sizes, int n_in,
                              void* d_out, int out_size, void* d_ws, size_t ws_size,
                              hipStream_t stream)
{
    const float* x       = (const float*)d_in[0];
    const float* embed   = (const float*)d_in[1];
    const float* adj     = (const float*)d_in[2];
    const float* W_in    = (const float*)d_in[3];
    const float* b_in    = (const float*)d_in[4];
    const float* bn_in_g = (const float*)d_in[5];
    const float* bn_in_b = (const float*)d_in[6];
    const float* bn_in_rm= (const float*)d_in[7];
    const float* bn_in_rv= (const float*)d_in[8];
    const float* W_gs    = (const float*)d_in[9];
    const float* b_gs    = (const float*)d_in[10];
    const float* Wih0    = (const float*)d_in[11];
    const float* Whh0    = (const float*)d_in[12];
    const float* bih0    = (const float*)d_in[13];
    const float* bhh0    = (const float*)d_in[14];
    const float* Wih1    = (const float*)d_in[15];
    const float* Whh1    = (const float*)d_in[16];
    const float* bih1    = (const float*)d_in[17];
    const float* bhh1    = (const float*)d_in[18];
    const float* W_emb   = (const float*)d_in[19];
    const float* b_emb   = (const float*)d_in[20];
    const float* bn_e_g  = (const float*)d_in[21];
    const float* bn_e_b  = (const float*)d_in[22];
    const float* bn_e_rm = (const float*)d_in[23];
    const float* bn_e_rv = (const float*)d_in[24];
    const float* W_fc    = (const float*)d_in[25];
    const float* b_fc    = (const float*)d_in[26];
    const float* bn_f_g  = (const float*)d_in[27];
    const float* bn_f_b  = (const float*)d_in[28];
    const float* bn_f_rm = (const float*)d_in[29];
    const float* bn_f_rv = (const float*)d_in[30];
    const float* W_out   = (const float*)d_in[31];
    const float* b_out   = (const float*)d_in[32];
    float* outp = (float*)d_out;

    // ---- workspace carve (1KB-aligned chunks) ----
    const size_t HB = (size_t)N_NODES * NH * sizeof(float);      // 5,120,000
    char* wp = (char*)d_ws;
    auto carve = [&](size_t bytes) {
        void* p = (void*)wp;
        wp += (bytes + 1023) & ~(size_t)1023;
        return p;
    };
    float* s     = (float*)carve(N_NODES * sizeof(float));
    float* h_in  = (float*)carve(HB);
    float* neigh = (float*)carve(HB);
    float* jk0   = (float*)carve(HB);
    float* jk1   = (float*)carve(HB);
    float* zero  = (float*)carve(HB);
    float* h1_0  = (float*)carve(HB);
    float* h1_1  = (float*)carve(HB);
    float* c1    = (float*)carve(HB);
    float* h2_0  = (float*)carve(HB);
    float* h2_1  = (float*)carve(HB);
    float* c2    = (float*)carve(HB);
    float* hpost = (float*)carve(HB);
    float* z     = (float*)carve((size_t)N_NODES * 512 * sizeof(float));
    float* e     = (float*)carve((size_t)N_NODES * NHE * sizeof(float));
    float* hfc   = (float*)carve((size_t)N_NODES * DCAT * sizeof(float));
    unsigned short* adjb = (unsigned short*)carve((size_t)N_NODES * KP * 2);        // 200.3 MB
    unsigned short* hT   = (unsigned short*)carve((size_t)NH * KP * 2);             // 2.6 MB
    float* part  = (float*)carve((size_t)NSPLIT * (MT * 64) * NH * sizeof(float));  // 41.2 MB
    if ((size_t)(wp - (char*)d_ws) > ws_size) return;            // loud failure

    const dim3 blk(256);
    hipMemsetAsync(zero, 0, HB, stream);

    // 1. adj -> bf16 (+ fused rowsum)
    adj_conv_kernel<<<N_NODES, blk, 0, stream>>>(adj, adjb, s);

    // 2. h = elu(bn_in(x @ W_in.T + b_in))
    wgemm_kernel<32, 128, 1><<<dim3(313, 1), blk, 0, stream>>>(
        N_NODES, NFEAT, NFEAT, x, NFEAT, nullptr, 0,
        NFEAT, W_in, NFEAT, nullptr, 0,
        h_in, NH, b_in, nullptr, bn_in_g, bn_in_b, bn_in_rm, bn_in_rv);

    // 3. layer 0: neigh = adj_norm @ h ; jk0 = normalize(relu([h|neigh]@Wgs0.T+b))
    htrans_kernel<<<dim3(KSTEPS, 4), blk, 0, stream>>>(h_in, hT);
    adjmm_mfma_kernel<<<dim3(MT, NSPLIT), blk, 0, stream>>>(adjb, hT, part);
    nreduce_kernel<<<1250, blk, 0, stream>>>(part, s, neigh);
    wgemm_kernel<32, 128, 2><<<dim3(313, 1), blk, 0, stream>>>(
        N_NODES, 2 * NH, NH, h_in, NH, neigh, NH,
        2 * NH, W_gs, 2 * NH, nullptr, 0,
        jk0, NH, b_gs, nullptr, nullptr, nullptr, nullptr, nullptr);

    // 4. layer 1
    htrans_kernel<<<dim3(KSTEPS, 4), blk, 0, stream>>>(jk0, hT);
    adjmm_mfma_kernel<<<dim3(MT, NSPLIT), blk, 0, stream>>>(adjb, hT, part);
    nreduce_kernel<<<1250, blk, 0, stream>>>(part, s, neigh);
    wgemm_kernel<32, 128, 2><<<dim3(313, 1), blk, 0, stream>>>(
        N_NODES, 2 * NH, NH, jk0, NH, neigh, NH,
        2 * NH, W_gs + 128 * 256, 2 * NH, nullptr, 0,
        jk1, NH, b_gs + 128, nullptr, nullptr, nullptr, nullptr, nullptr);

    // 5. LSTM jumping-knowledge (2 layers x 2 steps)
    auto lstm_step = [&](const float* xt, const float* hp,
                         const float* Wih, const float* Whh,
                         const float* bih, const float* bhh,
                         const float* cp, float* hn, float* cn) {
        wgemm_kernel<32, 128, 3><<<dim3(313, 4), blk, 0, stream>>>(
            N_NODES, 2 * NH, NH, xt, NH, hp, NH,
            NH, Wih, NH, Whh, NH,
            z, 4 * NH, bih, bhh, nullptr, nullptr, nullptr, nullptr);
        lstm_gate_kernel<<<1250, blk, 0, stream>>>(z, cp, hn, cn);
    };
    lstm_step(jk0,  zero, Wih0, Whh0, bih0, bhh0, zero, h1_0, c1);
    lstm_step(jk1,  h1_0, Wih0, Whh0, bih0, bhh0, c1,   h1_1, c1);
    lstm_step(h1_0, zero, Wih1, Whh1, bih1, bhh1, zero, h2_0, c2);
    lstm_step(h1_1, h2_0, Wih1, Whh1, bih1, bhh1, c2,   h2_1, c2);

    // 6. JK mean + bn_in + elu
    jkmean_bnelu_kernel<<<1250, blk, 0, stream>>>(h2_0, h2_1, bn_in_g, bn_in_b,
                                                  bn_in_rm, bn_in_rv, hpost);

    // 7. e = elu(bn_emb(embed @ W_emb.T + b_emb))
    wgemm_kernel<64, 64, 1><<<dim3(157, 1), blk, 0, stream>>>(
        N_NODES, NFE, NFE, embed, NFE, nullptr, 0,
        NFE, W_emb, NFE, nullptr, 0,
        e, NHE, b_emb, nullptr, bn_e_g, bn_e_b, bn_e_rm, bn_e_rv);

    // 8-9. hfc = elu(bn_fc([hpost|e] @ W_fc.T + b_fc))
    wgemm_kernel<64, 64, 1><<<dim3(157, 3), blk, 0, stream>>>(
        N_NODES, DCAT, NH, hpost, NH, e, NHE,
        DCAT, W_fc, DCAT, nullptr, 0,
        hfc, DCAT, b_fc, nullptr, bn_f_g, bn_f_b, bn_f_rm, bn_f_rv);

    // 10. logits + log_softmax
    out_kernel<<<2500, blk, 0, stream>>>(hfc, W_out, b_out, outp);
}

// Round 4
// 521.667 us; speedup vs baseline: 4.1325x; 1.5287x over previous
//
#include <hip/hip_runtime.h>
#include <hip/hip_bf16.h>
#include <math.h>

#define N_NODES 10000
#define NFEAT   2000
#define NFE     256
#define NH      128
#define NHE     64
#define NOUT    20
#define DCAT    192   // NH + NHE
#define BN_EPS  1e-5f

#define KP      10016        // N_NODES padded to multiple of 32 (hT K-dim)
#define KSTEPS  313          // ceil(N_NODES/32)
#define MT      157          // ceil(N_NODES / 64) m-tiles
#define NSPLIT  8
#define KC      40           // ceil(KSTEPS / NSPLIT)
#define MPAD    10048        // MT*64

typedef __attribute__((ext_vector_type(8))) short  bf16x8;
typedef __attribute__((ext_vector_type(4))) float  f32x4;

__device__ __forceinline__ float sigm(float x) { return 1.0f / (1.0f + expf(-x)); }

__device__ __forceinline__ unsigned short f2bf(float x) {
    union { __hip_bfloat16 h; unsigned short u; } c;
    c.h = __float2bfloat16(x);
    return c.u;
}

__device__ __forceinline__ bf16x8 cvt8(const float* v) {
    bf16x8 r;
    #pragma unroll
    for (int i = 0; i < 8; ++i) r[i] = (short)f2bf(v[i]);
    return r;
}

// ---------------------------------------------------------------------------
// h [N_NODES][NH] f32 -> hT [NH][KP] bf16 (transposed, K-pad zeroed)
// ---------------------------------------------------------------------------
__global__ __launch_bounds__(256) void htrans_kernel(const float* __restrict__ h,
                                                     unsigned short* __restrict__ hT)
{
    __shared__ float t[32][36];
    const int k0 = blockIdx.x * 32, c0 = blockIdx.y * 32;
    {
        int r = threadIdx.x >> 3, ci = threadIdx.x & 7;
        int kg = k0 + r;
        float4 v = {0.f, 0.f, 0.f, 0.f};
        if (kg < N_NODES) v = *(const float4*)(h + (size_t)kg * NH + c0 + ci * 4);
        t[r][ci * 4 + 0] = v.x; t[r][ci * 4 + 1] = v.y;
        t[r][ci * 4 + 2] = v.z; t[r][ci * 4 + 3] = v.w;
    }
    __syncthreads();
    {
        int c = threadIdx.x >> 3, ki = threadIdx.x & 7;
        ushort4 o;
        o.x = f2bf(t[ki * 4 + 0][c]); o.y = f2bf(t[ki * 4 + 1][c]);
        o.z = f2bf(t[ki * 4 + 2][c]); o.w = f2bf(t[ki * 4 + 3][c]);
        *(ushort4*)(hT + (size_t)(c0 + c) * KP + k0 + ki * 4) = o;
    }
}

// ---------------------------------------------------------------------------
// adjmm split-K: part[chunk] = adj(f32, converted inline) @ hT^T, and
// part_s[chunk][m] = partial row-sum of adj over this chunk's K-slice.
// grid (MT, NSPLIT), 256 thr = 4 waves, wave tile 32x64 of the 64x128 block.
// ---------------------------------------------------------------------------
__global__ __launch_bounds__(256) void adjmm_kernel(const float* __restrict__ adj,
                                                    const unsigned short* __restrict__ hT,
                                                    float* __restrict__ part,
                                                    float* __restrict__ part_s)
{
    __shared__ unsigned short sa[64 * 32];
    __shared__ unsigned short sb[128 * 32];
    const int tid  = threadIdx.x;
    const int lane = tid & 63, w = tid >> 6;
    const int m0   = blockIdx.x * 64;
    const int ks0  = blockIdx.y * KC;
    const int ks1  = min(ks0 + KC, KSTEPS);
    const int r0   = (w & 1) * 32;
    const int c0   = (w >> 1) * 64;

    const int arow = tid >> 2, agrp = tid & 3;
    const size_t abase = (size_t)min(m0 + arow, N_NODES - 1) * N_NODES;
    const int bcol = tid >> 1, bg0 = (tid & 1) * 2;

    float rs = 0.f;
    f32x4 acc[2][4];
    #pragma unroll
    for (int i = 0; i < 2; ++i)
        #pragma unroll
        for (int j = 0; j < 4; ++j) acc[i][j] = (f32x4){0.f, 0.f, 0.f, 0.f};

    for (int ks = ks0; ks < ks1; ++ks) {
        const int k0 = ks * 32;
        const int kg = k0 + agrp * 8;
        float av8[8];
        if (kg + 8 <= N_NODES) {
            float4 u0 = *(const float4*)(adj + abase + kg);
            float4 u1 = *(const float4*)(adj + abase + kg + 4);
            av8[0] = u0.x; av8[1] = u0.y; av8[2] = u0.z; av8[3] = u0.w;
            av8[4] = u1.x; av8[5] = u1.y; av8[6] = u1.z; av8[7] = u1.w;
        } else {
            #pragma unroll
            for (int i = 0; i < 8; ++i) av8[i] = 0.f;
        }
        #pragma unroll
        for (int i = 0; i < 8; ++i) rs += av8[i];
        bf16x8 vb0 = *(const bf16x8*)(hT + (size_t)bcol * KP + k0 + bg0 * 8);
        bf16x8 vb1 = *(const bf16x8*)(hT + (size_t)bcol * KP + k0 + (bg0 + 1) * 8);
        __syncthreads();
        *(bf16x8*)(sa + arow * 32 + ((agrp ^ (arow & 3)) << 3)) = cvt8(av8);
        *(bf16x8*)(sb + bcol * 32 + (((bg0 + 0) ^ (bcol & 3)) << 3)) = vb0;
        *(bf16x8*)(sb + bcol * 32 + (((bg0 + 1) ^ (bcol & 3)) << 3)) = vb1;
        __syncthreads();
        bf16x8 av[2], bv[4];
        #pragma unroll
        for (int rb = 0; rb < 2; ++rb) {
            int row = r0 + rb * 16 + (lane & 15);
            int g   = lane >> 4;
            av[rb] = *(const bf16x8*)(sa + row * 32 + ((g ^ (row & 3)) << 3));
        }
        #pragma unroll
        for (int cb = 0; cb < 4; ++cb) {
            int col = c0 + cb * 16 + (lane & 15);
            int g   = lane >> 4;
            bv[cb] = *(const bf16x8*)(sb + col * 32 + ((g ^ (col & 3)) << 3));
        }
        #pragma unroll
        for (int rb = 0; rb < 2; ++rb)
            #pragma unroll
            for (int cb = 0; cb < 4; ++cb)
                acc[rb][cb] = __builtin_amdgcn_mfma_f32_16x16x32_bf16(av[rb], bv[cb],
                                                                      acc[rb][cb], 0, 0, 0);
    }

    // row-sum partial: 4 threads per row (tid&3 = granule)
    rs += __shfl_xor(rs, 1);
    rs += __shfl_xor(rs, 2);
    if ((tid & 3) == 0) part_s[(size_t)blockIdx.y * MPAD + m0 + arow] = rs;

    float* pout = part + (size_t)blockIdx.y * MPAD * NH;
    #pragma unroll
    for (int rb = 0; rb < 2; ++rb) {
        #pragma unroll
        for (int cb = 0; cb < 4; ++cb) {
            int rowb = m0 + r0 + rb * 16 + (lane >> 4) * 4;
            int col  = c0 + cb * 16 + (lane & 15);
            #pragma unroll
            for (int reg = 0; reg < 4; ++reg)
                pout[(size_t)(rowb + reg) * NH + col] = acc[rb][cb][reg];
        }
    }
}

// ---------------------------------------------------------------------------
// sinv[m] = 1 / sum_chunks part_s[c][m]
// ---------------------------------------------------------------------------
__global__ __launch_bounds__(256) void sinv_kernel(const float* __restrict__ part_s,
                                                   float* __restrict__ sinv)
{
    int m = blockIdx.x * 256 + threadIdx.x;
    if (m >= N_NODES) return;
    float a = 0.f;
    #pragma unroll
    for (int c = 0; c < NSPLIT; ++c) a += part_s[(size_t)c * MPAD + m];
    sinv[m] = 1.0f / a;
}

// ---------------------------------------------------------------------------
// neigh[m][c] = (sum over chunks of part) * sinv[m]
// ---------------------------------------------------------------------------
__global__ __launch_bounds__(256) void nreduce_kernel(const float* __restrict__ part,
                                                      const float* __restrict__ sinv,
                                                      float* __restrict__ neigh)
{
    int idx = blockIdx.x * 256 + threadIdx.x;   // float4 index over [N_NODES][NH]
    if (idx >= N_NODES * NH / 4) return;
    const int m = idx >> 5;
    const size_t ch = (size_t)MPAD * NH / 4;
    const float4* p = (const float4*)part;
    float a0 = 0.f, a1 = 0.f, a2 = 0.f, a3 = 0.f;
    #pragma unroll
    for (int c = 0; c < NSPLIT; ++c) {
        float4 v = p[c * ch + idx];
        a0 += v.x; a1 += v.y; a2 += v.z; a3 += v.w;
    }
    const float inv = sinv[m];
    float4 o; o.x = a0 * inv; o.y = a1 * inv; o.z = a2 * inv; o.w = a3 * inv;
    *(float4*)(neigh + (size_t)idx * 4) = o;
}

// ---------------------------------------------------------------------------
// x @ W_in.T with split-K (K=2000). bf16 MFMA, f32 inputs converted inline.
// grid (MT, 8). Writes f32 partials; reduce kernel applies bias+BN+ELU.
// ---------------------------------------------------------------------------
__global__ __launch_bounds__(256) void xw_mfma_kernel(const float* __restrict__ x,
                                                      const float* __restrict__ Wn,
                                                      float* __restrict__ part)
{
    __shared__ unsigned short sa[64 * 32];
    __shared__ unsigned short sb[128 * 32];
    const int tid  = threadIdx.x;
    const int lane = tid & 63, w = tid >> 6;
    const int m0   = blockIdx.x * 64;
    const int TOT  = (NFEAT + 31) / 32;                 // 63
    const int s0   = blockIdx.y * 8;
    const int s1   = min(s0 + 8, TOT);
    const int r0   = (w & 1) * 32;
    const int c0   = (w >> 1) * 64;

    const int arow = tid >> 2, agrp = tid & 3;
    const size_t abase = (size_t)min(m0 + arow, N_NODES - 1) * NFEAT;

    f32x4 acc[2][4];
    #pragma unroll
    for (int i = 0; i < 2; ++i)
        #pragma unroll
        for (int j = 0; j < 4; ++j) acc[i][j] = (f32x4){0.f, 0.f, 0.f, 0.f};

    for (int ks = s0; ks < s1; ++ks) {
        const int k0 = ks * 32;
        float av8[8], bv8[2][8];
        {
            const int kg = k0 + agrp * 8;
            if (kg + 8 <= NFEAT) {
                float4 u0 = *(const float4*)(x + abase + kg);
                float4 u1 = *(const float4*)(x + abase + kg + 4);
                av8[0]=u0.x; av8[1]=u0.y; av8[2]=u0.z; av8[3]=u0.w;
                av8[4]=u1.x; av8[5]=u1.y; av8[6]=u1.z; av8[7]=u1.w;
            } else {
                #pragma unroll
                for (int i = 0; i < 8; ++i) av8[i] = 0.f;
            }
        }
        #pragma unroll
        for (int t = 0; t < 2; ++t) {
            int g = tid + t * 256;
            int n = g >> 2, grp = g & 3;
            int kg = k0 + grp * 8;
            if (kg + 8 <= NFEAT) {
                float4 u0 = *(const float4*)(Wn + (size_t)n * NFEAT + kg);
                float4 u1 = *(const float4*)(Wn + (size_t)n * NFEAT + kg + 4);
                bv8[t][0]=u0.x; bv8[t][1]=u0.y; bv8[t][2]=u0.z; bv8[t][3]=u0.w;
                bv8[t][4]=u1.x; bv8[t][5]=u1.y; bv8[t][6]=u1.z; bv8[t][7]=u1.w;
            } else {
                #pragma unroll
                for (int i = 0; i < 8; ++i) bv8[t][i] = 0.f;
            }
        }
        __syncthreads();
        *(bf16x8*)(sa + arow * 32 + ((agrp ^ (arow & 3)) << 3)) = cvt8(av8);
        #pragma unroll
        for (int t = 0; t < 2; ++t) {
            int g = tid + t * 256;
            int n = g >> 2, grp = g & 3;
            *(bf16x8*)(sb + n * 32 + ((grp ^ (n & 3)) << 3)) = cvt8(bv8[t]);
        }
        __syncthreads();
        bf16x8 av[2], bv[4];
        #pragma unroll
        for (int rb = 0; rb < 2; ++rb) {
            int row = r0 + rb * 16 + (lane & 15);
            int g   = lane >> 4;
            av[rb] = *(const bf16x8*)(sa + row * 32 + ((g ^ (row & 3)) << 3));
        }
        #pragma unroll
        for (int cb = 0; cb < 4; ++cb) {
            int col = c0 + cb * 16 + (lane & 15);
            int g   = lane >> 4;
            bv[cb] = *(const bf16x8*)(sb + col * 32 + ((g ^ (col & 3)) << 3));
        }
        #pragma unroll
        for (int rb = 0; rb < 2; ++rb)
            #pragma unroll
            for (int cb = 0; cb < 4; ++cb)
                acc[rb][cb] = __builtin_amdgcn_mfma_f32_16x16x32_bf16(av[rb], bv[cb],
                                                                      acc[rb][cb], 0, 0, 0);
    }
    float* pout = part + (size_t)blockIdx.y * MPAD * NH;
    #pragma unroll
    for (int rb = 0; rb < 2; ++rb)
        #pragma unroll
        for (int cb = 0; cb < 4; ++cb) {
            int rowb = m0 + r0 + rb * 16 + (lane >> 4) * 4;
            int col  = c0 + cb * 16 + (lane & 15);
            #pragma unroll
            for (int reg = 0; reg < 4; ++reg)
                pout[(size_t)(rowb + reg) * NH + col] = acc[rb][cb][reg];
        }
}

// ---------------------------------------------------------------------------
// h_in = elu(bn_in(sum_chunks part + b_in))
// ---------------------------------------------------------------------------
__global__ __launch_bounds__(256) void xw_reduce_kernel(const float* __restrict__ part,
                                                        const float* __restrict__ bias,
                                                        const float* __restrict__ g,
                                                        const float* __restrict__ bb,
                                                        const float* __restrict__ rm,
                                                        const float* __restrict__ rv,
                                                        float* __restrict__ h)
{
    int idx = blockIdx.x * 256 + threadIdx.x;
    if (idx >= N_NODES * NH / 4) return;
    const int c4 = (idx & 31) * 4;
    const size_t ch = (size_t)MPAD * NH / 4;
    const float4* p = (const float4*)part;
    float a[4] = {0.f, 0.f, 0.f, 0.f};
    #pragma unroll
    for (int c = 0; c < NSPLIT; ++c) {
        float4 v = p[c * ch + idx];
        a[0] += v.x; a[1] += v.y; a[2] += v.z; a[3] += v.w;
    }
    float o[4];
    #pragma unroll
    for (int j = 0; j < 4; ++j) {
        int c = c4 + j;
        float sc = g[c] / sqrtf(rv[c] + BN_EPS);
        float t = (a[j] + bias[c] - rm[c]) * sc + bb[c];
        o[j] = t > 0.f ? t : expm1f(t);
    }
    float4 ov; ov.x = o[0]; ov.y = o[1]; ov.z = o[2]; ov.w = o[3];
    *(float4*)(h + (size_t)idx * 4) = ov;
}

// ---------------------------------------------------------------------------
// Generic MFMA weight GEMM: out[m, n0+n] = sum_k A[m,k]*B[n,k] (+epilogue)
// A,B f32 (virtual concats), converted to bf16 inline. 256 thr = 4 waves.
// Wave tile 32x64; WR=BM/32 row-groups x WC=BN/64 col-groups, WR*WC=4.
// EPI: 0 = +bias1+bias2 (LSTM z)   1 = +bias, BN, ELU   2 = +bias, ReLU
// ---------------------------------------------------------------------------
template<int BM, int BN, int EPI>
__global__ __launch_bounds__(256) void wgemm_mfma_kernel(
    int M, int K, int kSplitA,
    const float* __restrict__ a1, int lda1,
    const float* __restrict__ a2, int lda2,
    int kSplitB,
    const float* __restrict__ b1, int ldb1,
    const float* __restrict__ b2, int ldb2,
    float* __restrict__ out, int ldo,
    const float* __restrict__ bias1, const float* __restrict__ bias2,
    const float* __restrict__ bng, const float* __restrict__ bnb,
    const float* __restrict__ bnrm, const float* __restrict__ bnrv)
{
    constexpr int WC = BN / 64;
    constexpr int WR = 4 / WC;
    static_assert(WR * WC == 4 && BM == WR * 32, "geometry");
    constexpr int NGA = BM * 4 / 256;   // A granules per thread (1 or 2)
    constexpr int NGB = BN * 4 / 256;   // B granules per thread (1 or 2)
    __shared__ unsigned short sa[BM * 32];
    __shared__ unsigned short sb[BN * 32];
    const int tid  = threadIdx.x;
    const int lane = tid & 63, w = tid >> 6;
    const int m0   = blockIdx.x * BM, n0 = blockIdx.y * BN;
    const int r0   = (w % WR) * 32, c0 = (w / WR) * 64;

    f32x4 acc[2][4];
    #pragma unroll
    for (int i = 0; i < 2; ++i)
        #pragma unroll
        for (int j = 0; j < 4; ++j) acc[i][j] = (f32x4){0.f, 0.f, 0.f, 0.f};

    for (int k0 = 0; k0 < K; k0 += 32) {
        float ar[NGA][8], br[NGB][8];
        #pragma unroll
        for (int t = 0; t < NGA; ++t) {
            int gidx = tid + t * 256;
            int row = gidx >> 2, grp = gidx & 3;
            int mg = min(m0 + row, M - 1);
            int kg = k0 + grp * 8;
            const float* src = (kg < kSplitA) ? (a1 + (size_t)mg * lda1 + kg)
                                              : (a2 + (size_t)mg * lda2 + (kg - kSplitA));
            float4 u0 = *(const float4*)src;
            float4 u1 = *(const float4*)(src + 4);
            ar[t][0]=u0.x; ar[t][1]=u0.y; ar[t][2]=u0.z; ar[t][3]=u0.w;
            ar[t][4]=u1.x; ar[t][5]=u1.y; ar[t][6]=u1.z; ar[t][7]=u1.w;
        }
        #pragma unroll
        for (int t = 0; t < NGB; ++t) {
            int gidx = tid + t * 256;
            int n = gidx >> 2, grp = gidx & 3;
            int ng = n0 + n;
            int kg = k0 + grp * 8;
            const float* src = (kg < kSplitB) ? (b1 + (size_t)ng * ldb1 + kg)
                                              : (b2 + (size_t)ng * ldb2 + (kg - kSplitB));
            float4 u0 = *(const float4*)src;
            float4 u1 = *(const float4*)(src + 4);
            br[t][0]=u0.x; br[t][1]=u0.y; br[t][2]=u0.z; br[t][3]=u0.w;
            br[t][4]=u1.x; br[t][5]=u1.y; br[t][6]=u1.z; br[t][7]=u1.w;
        }
        __syncthreads();
        #pragma unroll
        for (int t = 0; t < NGA; ++t) {
            int gidx = tid + t * 256;
            int row = gidx >> 2, grp = gidx & 3;
            *(bf16x8*)(sa + row * 32 + ((grp ^ (row & 3)) << 3)) = cvt8(ar[t]);
        }
        #pragma unroll
        for (int t = 0; t < NGB; ++t) {
            int gidx = tid + t * 256;
            int n = gidx >> 2, grp = gidx & 3;
            *(bf16x8*)(sb + n * 32 + ((grp ^ (n & 3)) << 3)) = cvt8(br[t]);
        }
        __syncthreads();
        bf16x8 av[2], bv[4];
        #pragma unroll
        for (int rb = 0; rb < 2; ++rb) {
            int row = r0 + rb * 16 + (lane & 15);
            int g   = lane >> 4;
            av[rb] = *(const bf16x8*)(sa + row * 32 + ((g ^ (row & 3)) << 3));
        }
        #pragma unroll
        for (int cb = 0; cb < 4; ++cb) {
            int col = c0 + cb * 16 + (lane & 15);
            int g   = lane >> 4;
            bv[cb] = *(const bf16x8*)(sb + col * 32 + ((g ^ (col & 3)) << 3));
        }
        #pragma unroll
        for (int rb = 0; rb < 2; ++rb)
            #pragma unroll
            for (int cb = 0; cb < 4; ++cb)
                acc[rb][cb] = __builtin_amdgcn_mfma_f32_16x16x32_bf16(av[rb], bv[cb],
                                                                      acc[rb][cb], 0, 0, 0);
    }

    #pragma unroll
    for (int cb = 0; cb < 4; ++cb) {
        const int colg = n0 + c0 + cb * 16 + (lane & 15);
        float badd = bias1[colg];
        if constexpr (EPI == 0) badd += bias2[colg];
        float sc = 0.f, sh = 0.f;
        if constexpr (EPI == 1) {
            sc = bng[colg] / sqrtf(bnrv[colg] + BN_EPS);
            sh = bnb[colg] - bnrm[colg] * sc;
        }
        #pragma unroll
        for (int rb = 0; rb < 2; ++rb) {
            int rowb = m0 + r0 + rb * 16 + (lane >> 4) * 4;
            #pragma unroll
            for (int reg = 0; reg < 4; ++reg) {
                int m = rowb + reg;
                if (m < M) {
                    float t = acc[rb][cb][reg] + badd;
                    if constexpr (EPI == 1) {
                        t = t * sc + sh;
                        t = t > 0.f ? t : expm1f(t);
                    }
                    if constexpr (EPI == 2) t = fmaxf(t, 0.f);
                    out[(size_t)m * ldo + colg] = t;
                }
            }
        }
    }
}

// ---------------------------------------------------------------------------
// row-normalize: out[r] = in[r] / max(||in[r]||, 1e-12).  One wave per row.
// ---------------------------------------------------------------------------
__global__ __launch_bounds__(256) void rownorm_kernel(const float* __restrict__ in,
                                                      float* __restrict__ out)
{
    const int w = threadIdx.x >> 6, lane = threadIdx.x & 63;
    const int r = blockIdx.x * 4 + w;
    float2 v = ((const float2*)(in + (size_t)r * NH))[lane];
    float ss = v.x * v.x + v.y * v.y;
    #pragma unroll
    for (int msk = 32; msk >= 1; msk >>= 1) ss += __shfl_xor(ss, msk);
    float sc = 1.0f / fmaxf(sqrtf(ss), 1e-12f);
    float2 o; o.x = v.x * sc; o.y = v.y * sc;
    ((float2*)(out + (size_t)r * NH))[lane] = o;
}

// ---------------------------------------------------------------------------
// LSTM gate kernel: z [N,512] (i,f,g,o), c_prev -> h_out, c_out
// ---------------------------------------------------------------------------
template<bool HASC>
__global__ __launch_bounds__(256) void lstm_gate_kernel(const float* __restrict__ z,
                                                        const float* __restrict__ cprev,
                                                        float* __restrict__ hout,
                                                        float* __restrict__ cout)
{
    int idx = blockIdx.x * 256 + threadIdx.x;            // float4 index
    if (idx >= N_NODES * NH / 4) return;
    int m = idx >> 5, c4 = (idx & 31) * 4;
    const float* zr = z + (size_t)m * 512 + c4;
    float4 zi = *(const float4*)(zr);
    float4 zf = *(const float4*)(zr + 128);
    float4 zg = *(const float4*)(zr + 256);
    float4 zo = *(const float4*)(zr + 384);
    float4 cp = {0.f, 0.f, 0.f, 0.f};
    if (HASC) cp = *(const float4*)(cprev + (size_t)m * NH + c4);
    float zia[4] = {zi.x, zi.y, zi.z, zi.w};
    float zfa[4] = {zf.x, zf.y, zf.z, zf.w};
    float zga[4] = {zg.x, zg.y, zg.z, zg.w};
    float zoa[4] = {zo.x, zo.y, zo.z, zo.w};
    float cpa[4] = {cp.x, cp.y, cp.z, cp.w};
    float ho[4], co[4];
    #pragma unroll
    for (int j = 0; j < 4; ++j) {
        float ig = sigm(zia[j]);
        float gg = tanhf(zga[j]);
        float cn = ig * gg;
        if (HASC) cn += sigm(zfa[j]) * cpa[j];
        co[j] = cn;
        ho[j] = sigm(zoa[j]) * tanhf(cn);
    }
    float4 hv; hv.x = ho[0]; hv.y = ho[1]; hv.z = ho[2]; hv.w = ho[3];
    float4 cv; cv.x = co[0]; cv.y = co[1]; cv.z = co[2]; cv.w = co[3];
    *(float4*)(hout + (size_t)m * NH + c4) = hv;
    *(float4*)(cout + (size_t)m * NH + c4) = cv;
}

// ---------------------------------------------------------------------------
// hpost = elu(bn_in(0.5*(a+b)))
// ---------------------------------------------------------------------------
__global__ __launch_bounds__(256) void jkmean_bnelu_kernel(const float* __restrict__ a,
                                                           const float* __restrict__ b,
                                                           const float* __restrict__ g,
                                                           const float* __restrict__ bb,
                                                           const float* __restrict__ rm,
                                                           const float* __restrict__ rv,
                                                           float* __restrict__ out)
{
    int idx = blockIdx.x * 256 + threadIdx.x;
    if (idx >= N_NODES * NH / 4) return;
    int c4 = (idx & 31) * 4;
    float4 va = *(const float4*)(a + (size_t)idx * 4);
    float4 vb = *(const float4*)(b + (size_t)idx * 4);
    float av[4] = {va.x, va.y, va.z, va.w};
    float bv[4] = {vb.x, vb.y, vb.z, vb.w};
    float o[4];
    #pragma unroll
    for (int j = 0; j < 4; ++j) {
        int c = c4 + j;
        float t = 0.5f * (av[j] + bv[j]);
        float sc = g[c] / sqrtf(rv[c] + BN_EPS);
        t = (t - rm[c]) * sc + bb[c];
        o[j] = t > 0.f ? t : expm1f(t);
    }
    float4 ov; ov.x = o[0]; ov.y = o[1]; ov.z = o[2]; ov.w = o[3];
    *(float4*)(out + (size_t)idx * 4) = ov;
}

// ---------------------------------------------------------------------------
// out = log_softmax(hfc @ W_out.T + b_out).  One wave per row.
// ---------------------------------------------------------------------------
__global__ __launch_bounds__(256) void out_kernel(const float* __restrict__ hfc,
                                                  const float* __restrict__ W_out,
                                                  const float* __restrict__ b_out,
                                                  float* __restrict__ out)
{
    __shared__ float wl[NOUT * 193];
    __shared__ float rl[4][DCAT];
    const int tid = threadIdx.x;
    for (int i = tid; i < NOUT * DCAT; i += 256)
        wl[(i / DCAT) * 193 + (i % DCAT)] = W_out[i];
    const int w = tid >> 6, lane = tid & 63;
    const int r = blockIdx.x * 4 + w;
    for (int k = lane; k < DCAT; k += 64) rl[w][k] = hfc[(size_t)r * DCAT + k];
    __syncthreads();
    const int c = lane;
    float acc = -INFINITY;
    if (c < NOUT) {
        acc = b_out[c];
        #pragma unroll 4
        for (int k = 0; k < DCAT; ++k) acc += rl[w][k] * wl[c * 193 + k];
    }
    float mx = acc;
    #pragma unroll
    for (int msk = 16; msk >= 1; msk >>= 1) mx = fmaxf(mx, __shfl_xor(mx, msk));
    float ex = (c < NOUT) ? expf(acc - mx) : 0.f;
    float sm = ex;
    #pragma unroll
    for (int msk = 16; msk >= 1; msk >>= 1) sm += __shfl_xor(sm, msk);
    if (c < NOUT) out[(size_t)r * NOUT + c] = acc - mx - logf(sm);
}

// ---------------------------------------------------------------------------
extern "C" void kernel_launch(void* const* d_in, const int* in_sizes, int n_in,
                              void* d_out, int out_size, void* d_ws, size_t ws_size,
                              hipStream_t stream)
{
    const float* x       = (const float*)d_in[0];
    const float* embed   = (const float*)d_in[1];
    const float* adj     = (const float*)d_in[2];
    const float* W_in    = (const float*)d_in[3];
    const float* b_in    = (const float*)d_in[4];
    const float* bn_in_g = (const float*)d_in[5];
    const float* bn_in_b = (const float*)d_in[6];
    const float* bn_in_rm= (const float*)d_in[7];
    const float* bn_in_rv= (const float*)d_in[8];
    const float* W_gs    = (const float*)d_in[9];
    const float* b_gs    = (const float*)d_in[10];
    const float* Wih0    = (const float*)d_in[11];
    const float* Whh0    = (const float*)d_in[12];
    const float* bih0    = (const float*)d_in[13];
    const float* bhh0    = (const float*)d_in[14];
    const float* Wih1    = (const float*)d_in[15];
    const float* Whh1    = (const float*)d_in[16];
    const float* bih1    = (const float*)d_in[17];
    const float* bhh1    = (const float*)d_in[18];
    const float* W_emb   = (const float*)d_in[19];
    const float* b_emb   = (const float*)d_in[20];
    const float* bn_e_g  = (const float*)d_in[21];
    const float* bn_e_b  = (const float*)d_in[22];
    const float* bn_e_rm = (const float*)d_in[23];
    const float* bn_e_rv = (const float*)d_in[24];
    const float* W_fc    = (const float*)d_in[25];
    const float* b_fc    = (const float*)d_in[26];
    const float* bn_f_g  = (const float*)d_in[27];
    const float* bn_f_b  = (const float*)d_in[28];
    const float* bn_f_rm = (const float*)d_in[29];
    const float* bn_f_rv = (const float*)d_in[30];
    const float* W_out   = (const float*)d_in[31];
    const float* b_out   = (const float*)d_in[32];
    float* outp = (float*)d_out;

    const size_t HB = (size_t)N_NODES * NH * sizeof(float);
    char* wp = (char*)d_ws;
    auto carve = [&](size_t bytes) {
        void* p = (void*)wp;
        wp += (bytes + 1023) & ~(size_t)1023;
        return p;
    };
    float* part  = (float*)carve((size_t)NSPLIT * MPAD * NH * sizeof(float)); // 41.2 MB
    float* part_s= (float*)carve((size_t)NSPLIT * MPAD * sizeof(float));
    float* sinv  = (float*)carve(N_NODES * sizeof(float));
    float* h_in  = (float*)carve(HB);
    float* neigh = (float*)carve(HB);
    float* jkraw = (float*)carve(HB);
    float* jk0   = (float*)carve(HB);
    float* jk1   = (float*)carve(HB);
    float* h1_0  = (float*)carve(HB);
    float* h1_1  = (float*)carve(HB);
    float* c1    = (float*)carve(HB);
    float* h2_0  = (float*)carve(HB);
    float* h2_1  = (float*)carve(HB);
    float* c2    = (float*)carve(HB);
    float* hpost = (float*)carve(HB);
    float* z     = (float*)carve((size_t)N_NODES * 512 * sizeof(float));
    float* e     = (float*)carve((size_t)N_NODES * NHE * sizeof(float));
    float* hfc   = (float*)carve((size_t)N_NODES * DCAT * sizeof(float));
    unsigned short* hT = (unsigned short*)carve((size_t)NH * KP * 2);
    if ((size_t)(wp - (char*)d_ws) > ws_size) return;

    const dim3 blk(256);

    // 1. h_in = elu(bn_in(x @ W_in.T + b_in))   [split-K MFMA]
    xw_mfma_kernel<<<dim3(MT, 8), blk, 0, stream>>>(x, W_in, part);
    xw_reduce_kernel<<<1250, blk, 0, stream>>>(part, b_in, bn_in_g, bn_in_b,
                                               bn_in_rm, bn_in_rv, h_in);

    // 2. GraphSAGE layer 0
    htrans_kernel<<<dim3(KSTEPS, 4), blk, 0, stream>>>(h_in, hT);
    adjmm_kernel<<<dim3(MT, NSPLIT), blk, 0, stream>>>(adj, hT, part, part_s);
    sinv_kernel<<<40, blk, 0, stream>>>(part_s, sinv);
    nreduce_kernel<<<1250, blk, 0, stream>>>(part, sinv, neigh);
    wgemm_mfma_kernel<64, 128, 2><<<dim3(MT, 1), blk, 0, stream>>>(
        N_NODES, 2 * NH, NH, h_in, NH, neigh, NH,
        2 * NH, W_gs, 2 * NH, nullptr, 0,
        jkraw, NH, b_gs, nullptr, nullptr, nullptr, nullptr, nullptr);
    rownorm_kernel<<<2500, blk, 0, stream>>>(jkraw, jk0);

    // 3. GraphSAGE layer 1
    htrans_kernel<<<dim3(KSTEPS, 4), blk, 0, stream>>>(jk0, hT);
    adjmm_kernel<<<dim3(MT, NSPLIT), blk, 0, stream>>>(adj, hT, part, part_s);
    sinv_kernel<<<40, blk, 0, stream>>>(part_s, sinv);
    nreduce_kernel<<<1250, blk, 0, stream>>>(part, sinv, neigh);
    wgemm_mfma_kernel<64, 128, 2><<<dim3(MT, 1), blk, 0, stream>>>(
        N_NODES, 2 * NH, NH, jk0, NH, neigh, NH,
        2 * NH, W_gs + 128 * 256, 2 * NH, nullptr, 0,
        jkraw, NH, b_gs + 128, nullptr, nullptr, nullptr, nullptr, nullptr);
    rownorm_kernel<<<2500, blk, 0, stream>>>(jkraw, jk1);

    // 4. LSTM jumping-knowledge (2 layers x 2 steps)
    // layer 1, t=0 (h=c=0): K=128, only Wih
    wgemm_mfma_kernel<64, 128, 0><<<dim3(MT, 4), blk, 0, stream>>>(
        N_NODES, NH, NH, jk0, NH, nullptr, 0,
        NH, Wih0, NH, nullptr, 0,
        z, 4 * NH, bih0, bhh0, nullptr, nullptr, nullptr, nullptr);
    lstm_gate_kernel<false><<<1250, blk, 0, stream>>>(z, nullptr, h1_0, c1);
    // layer 1, t=1
    wgemm_mfma_kernel<64, 128, 0><<<dim3(MT, 4), blk, 0, stream>>>(
        N_NODES, 2 * NH, NH, jk1, NH, h1_0, NH,
        NH, Wih0, NH, Whh0, NH,
        z, 4 * NH, bih0, bhh0, nullptr, nullptr, nullptr, nullptr);
    lstm_gate_kernel<true><<<1250, blk, 0, stream>>>(z, c1, h1_1, c1);
    // layer 2, t=0
    wgemm_mfma_kernel<64, 128, 0><<<dim3(MT, 4), blk, 0, stream>>>(
        N_NODES, NH, NH, h1_0, NH, nullptr, 0,
        NH, Wih1, NH, nullptr, 0,
        z, 4 * NH, bih1, bhh1, nullptr, nullptr, nullptr, nullptr);
    lstm_gate_kernel<false><<<1250, blk, 0, stream>>>(z, nullptr, h2_0, c2);
    // layer 2, t=1
    wgemm_mfma_kernel<64, 128, 0><<<dim3(MT, 4), blk, 0, stream>>>(
        N_NODES, 2 * NH, NH, h1_1, NH, h2_0, NH,
        NH, Wih1, NH, Whh1, NH,
        z, 4 * NH, bih1, bhh1, nullptr, nullptr, nullptr, nullptr);
    lstm_gate_kernel<true><<<1250, blk, 0, stream>>>(z, c2, h2_1, c2);

    // 5. JK mean + bn_in + elu
    jkmean_bnelu_kernel<<<1250, blk, 0, stream>>>(h2_0, h2_1, bn_in_g, bn_in_b,
                                                  bn_in_rm, bn_in_rv, hpost);

    // 6. e = elu(bn_emb(embed @ W_emb.T + b_emb))
    wgemm_mfma_kernel<128, 64, 1><<<dim3(79, 1), blk, 0, stream>>>(
        N_NODES, NFE, NFE, embed, NFE, nullptr, 0,
        NFE, W_emb, NFE, nullptr, 0,
        e, NHE, b_emb, nullptr, bn_e_g, bn_e_b, bn_e_rm, bn_e_rv);

    // 7. hfc = elu(bn_fc([hpost|e] @ W_fc.T + b_fc))
    wgemm_mfma_kernel<128, 64, 1><<<dim3(79, 3), blk, 0, stream>>>(
        N_NODES, DCAT, NH, hpost, NH, e, NHE,
        DCAT, W_fc, DCAT, nullptr, 0,
        hfc, DCAT, b_fc, nullptr, bn_f_g, bn_f_b, bn_f_rm, bn_f_rv);

    // 8. logits + log_softmax
    out_kernel<<<2500, blk, 0, stream>>>(hfc, W_out, b_out, outp);
}

// Round 5
// 486.168 us; speedup vs baseline: 4.4343x; 1.0730x over previous
//
#include <hip/hip_runtime.h>
#include <hip/hip_bf16.h>
#include <math.h>

#define N_NODES 10000
#define NFEAT   2000
#define NFE     256
#define NH      128
#define NHE     64
#define NOUT    20
#define DCAT    192
#define BN_EPS  1e-5f

#define KP      10016        // padded K for transposed activations
#define KSTEPS  313
#define MT      157          // 64-row m-tiles
#define NSPLIT  8            // adjmm split-K
#define KC      40
#define NSPLX   4            // xw split-K
#define MPAD    10048

typedef __attribute__((ext_vector_type(8))) short  bf16x8;
typedef __attribute__((ext_vector_type(4))) float  f32x4;

__device__ __forceinline__ float sigm(float x) { return 1.0f / (1.0f + expf(-x)); }

__device__ __forceinline__ unsigned short f2bf(float x) {
    union { __hip_bfloat16 h; unsigned short u; } c;
    c.h = __float2bfloat16(x);
    return c.u;
}

__device__ __forceinline__ bf16x8 cvt8(const float* v) {
    bf16x8 r;
    #pragma unroll
    for (int i = 0; i < 8; ++i) r[i] = (short)f2bf(v[i]);
    return r;
}

// ---------------------------------------------------------------------------
// pack weights to bf16: wl[l][512][256] = [Wih_l | Whh_l]; wgb = bf16(W_gs)
// ---------------------------------------------------------------------------
__global__ __launch_bounds__(256) void wconv_kernel(const float* __restrict__ Wih0,
                                                    const float* __restrict__ Whh0,
                                                    const float* __restrict__ Wih1,
                                                    const float* __restrict__ Whh1,
                                                    const float* __restrict__ Wgs,
                                                    unsigned short* __restrict__ wl,
                                                    unsigned short* __restrict__ wgb)
{
    const int total = 262144 + 65536;
    for (int i = blockIdx.x * 256 + threadIdx.x; i < total; i += gridDim.x * 256) {
        if (i < 262144) {
            int l = i >> 17, rem = i & 131071;
            int n = rem >> 8, k = rem & 255;
            const float* src;
            if (l == 0) src = (k < 128) ? (Wih0 + n * 128 + k) : (Whh0 + n * 128 + (k - 128));
            else        src = (k < 128) ? (Wih1 + n * 128 + k) : (Whh1 + n * 128 + (k - 128));
            wl[i] = f2bf(*src);
        } else {
            int j = i - 262144;
            wgb[j] = f2bf(Wgs[j]);
        }
    }
}

// ---------------------------------------------------------------------------
// adjmm split-K: part[chunk] = adj(f32->bf16 inline) @ hT^T ; part_s rowsums
// ---------------------------------------------------------------------------
__global__ __launch_bounds__(256) void adjmm_kernel(const float* __restrict__ adj,
                                                    const unsigned short* __restrict__ hT,
                                                    float* __restrict__ part,
                                                    float* __restrict__ part_s)
{
    __shared__ unsigned short sa[64 * 32];
    __shared__ unsigned short sb[128 * 32];
    const int tid  = threadIdx.x;
    const int lane = tid & 63, w = tid >> 6;
    const int m0   = blockIdx.x * 64;
    const int ks0  = blockIdx.y * KC;
    const int ks1  = min(ks0 + KC, KSTEPS);
    const int r0   = (w & 1) * 32;
    const int c0   = (w >> 1) * 64;

    const int arow = tid >> 2, agrp = tid & 3;
    const size_t abase = (size_t)min(m0 + arow, N_NODES - 1) * N_NODES;
    const int bcol = tid >> 1, bg0 = (tid & 1) * 2;

    float rs = 0.f;
    f32x4 acc[2][4];
    #pragma unroll
    for (int i = 0; i < 2; ++i)
        #pragma unroll
        for (int j = 0; j < 4; ++j) acc[i][j] = (f32x4){0.f, 0.f, 0.f, 0.f};

    for (int ks = ks0; ks < ks1; ++ks) {
        const int k0 = ks * 32;
        const int kg = k0 + agrp * 8;
        float av8[8];
        if (kg + 8 <= N_NODES) {
            float4 u0 = *(const float4*)(adj + abase + kg);
            float4 u1 = *(const float4*)(adj + abase + kg + 4);
            av8[0] = u0.x; av8[1] = u0.y; av8[2] = u0.z; av8[3] = u0.w;
            av8[4] = u1.x; av8[5] = u1.y; av8[6] = u1.z; av8[7] = u1.w;
        } else {
            #pragma unroll
            for (int i = 0; i < 8; ++i) av8[i] = 0.f;
        }
        #pragma unroll
        for (int i = 0; i < 8; ++i) rs += av8[i];
        bf16x8 vb0 = *(const bf16x8*)(hT + (size_t)bcol * KP + k0 + bg0 * 8);
        bf16x8 vb1 = *(const bf16x8*)(hT + (size_t)bcol * KP + k0 + (bg0 + 1) * 8);
        __syncthreads();
        *(bf16x8*)(sa + arow * 32 + ((agrp ^ (arow & 3)) << 3)) = cvt8(av8);
        *(bf16x8*)(sb + bcol * 32 + (((bg0 + 0) ^ (bcol & 3)) << 3)) = vb0;
        *(bf16x8*)(sb + bcol * 32 + (((bg0 + 1) ^ (bcol & 3)) << 3)) = vb1;
        __syncthreads();
        bf16x8 av[2], bv[4];
        #pragma unroll
        for (int rb = 0; rb < 2; ++rb) {
            int row = r0 + rb * 16 + (lane & 15);
            int g   = lane >> 4;
            av[rb] = *(const bf16x8*)(sa + row * 32 + ((g ^ (row & 3)) << 3));
        }
        #pragma unroll
        for (int cb = 0; cb < 4; ++cb) {
            int col = c0 + cb * 16 + (lane & 15);
            int g   = lane >> 4;
            bv[cb] = *(const bf16x8*)(sb + col * 32 + ((g ^ (col & 3)) << 3));
        }
        #pragma unroll
        for (int rb = 0; rb < 2; ++rb)
            #pragma unroll
            for (int cb = 0; cb < 4; ++cb)
                acc[rb][cb] = __builtin_amdgcn_mfma_f32_16x16x32_bf16(av[rb], bv[cb],
                                                                      acc[rb][cb], 0, 0, 0);
    }

    rs += __shfl_xor(rs, 1);
    rs += __shfl_xor(rs, 2);
    if ((tid & 3) == 0) part_s[(size_t)blockIdx.y * MPAD + m0 + arow] = rs;

    float* pout = part + (size_t)blockIdx.y * MPAD * NH;
    #pragma unroll
    for (int rb = 0; rb < 2; ++rb)
        #pragma unroll
        for (int cb = 0; cb < 4; ++cb) {
            int rowb = m0 + r0 + rb * 16 + (lane >> 4) * 4;
            int col  = c0 + cb * 16 + (lane & 15);
            #pragma unroll
            for (int reg = 0; reg < 4; ++reg)
                pout[(size_t)(rowb + reg) * NH + col] = acc[rb][cb][reg];
        }
}

// ---------------------------------------------------------------------------
// neigh[m][c] = (sum_chunks part) / (sum_chunks part_s[m])   [sinv fused]
// ---------------------------------------------------------------------------
__global__ __launch_bounds__(256) void nreduce_kernel(const float* __restrict__ part,
                                                      const float* __restrict__ part_s,
                                                      float* __restrict__ neigh)
{
    int idx = blockIdx.x * 256 + threadIdx.x;
    if (idx >= N_NODES * NH / 4) return;
    const int m = idx >> 5;
    const int lane = threadIdx.x & 63;
    float inv = 0.f;
    if ((lane & 31) == 0) {
        float a = 0.f;
        #pragma unroll
        for (int c = 0; c < NSPLIT; ++c) a += part_s[(size_t)c * MPAD + m];
        inv = 1.0f / a;
    }
    inv = __shfl(inv, lane & 32);
    const size_t ch = (size_t)MPAD * NH / 4;
    const float4* p = (const float4*)part;
    float a0 = 0.f, a1 = 0.f, a2 = 0.f, a3 = 0.f;
    #pragma unroll
    for (int c = 0; c < NSPLIT; ++c) {
        float4 v = p[c * ch + idx];
        a0 += v.x; a1 += v.y; a2 += v.z; a3 += v.w;
    }
    float4 o; o.x = a0 * inv; o.y = a1 * inv; o.z = a2 * inv; o.w = a3 * inv;
    *(float4*)(neigh + (size_t)idx * 4) = o;
}

// ---------------------------------------------------------------------------
// x @ W_in.T split-K (4 chunks of 16 K-steps)
// ---------------------------------------------------------------------------
__global__ __launch_bounds__(256) void xw_mfma_kernel(const float* __restrict__ x,
                                                      const float* __restrict__ Wn,
                                                      float* __restrict__ part)
{
    __shared__ unsigned short sa[64 * 32];
    __shared__ unsigned short sb[128 * 32];
    const int tid  = threadIdx.x;
    const int lane = tid & 63, w = tid >> 6;
    const int m0   = blockIdx.x * 64;
    const int TOT  = (NFEAT + 31) / 32;                 // 63
    const int s0   = blockIdx.y * 16;
    const int s1   = min(s0 + 16, TOT);
    const int r0   = (w & 1) * 32;
    const int c0   = (w >> 1) * 64;

    const int arow = tid >> 2, agrp = tid & 3;
    const size_t abase = (size_t)min(m0 + arow, N_NODES - 1) * NFEAT;

    f32x4 acc[2][4];
    #pragma unroll
    for (int i = 0; i < 2; ++i)
        #pragma unroll
        for (int j = 0; j < 4; ++j) acc[i][j] = (f32x4){0.f, 0.f, 0.f, 0.f};

    for (int ks = s0; ks < s1; ++ks) {
        const int k0 = ks * 32;
        float av8[8], bv8[2][8];
        {
            const int kg = k0 + agrp * 8;
            if (kg + 8 <= NFEAT) {
                float4 u0 = *(const float4*)(x + abase + kg);
                float4 u1 = *(const float4*)(x + abase + kg + 4);
                av8[0]=u0.x; av8[1]=u0.y; av8[2]=u0.z; av8[3]=u0.w;
                av8[4]=u1.x; av8[5]=u1.y; av8[6]=u1.z; av8[7]=u1.w;
            } else {
                #pragma unroll
                for (int i = 0; i < 8; ++i) av8[i] = 0.f;
            }
        }
        #pragma unroll
        for (int t = 0; t < 2; ++t) {
            int g = tid + t * 256;
            int n = g >> 2, grp = g & 3;
            int kg = k0 + grp * 8;
            if (kg + 8 <= NFEAT) {
                float4 u0 = *(const float4*)(Wn + (size_t)n * NFEAT + kg);
                float4 u1 = *(const float4*)(Wn + (size_t)n * NFEAT + kg + 4);
                bv8[t][0]=u0.x; bv8[t][1]=u0.y; bv8[t][2]=u0.z; bv8[t][3]=u0.w;
                bv8[t][4]=u1.x; bv8[t][5]=u1.y; bv8[t][6]=u1.z; bv8[t][7]=u1.w;
            } else {
                #pragma unroll
                for (int i = 0; i < 8; ++i) bv8[t][i] = 0.f;
            }
        }
        __syncthreads();
        *(bf16x8*)(sa + arow * 32 + ((agrp ^ (arow & 3)) << 3)) = cvt8(av8);
        #pragma unroll
        for (int t = 0; t < 2; ++t) {
            int g = tid + t * 256;
            int n = g >> 2, grp = g & 3;
            *(bf16x8*)(sb + n * 32 + ((grp ^ (n & 3)) << 3)) = cvt8(bv8[t]);
        }
        __syncthreads();
        bf16x8 av[2], bv[4];
        #pragma unroll
        for (int rb = 0; rb < 2; ++rb) {
            int row = r0 + rb * 16 + (lane & 15);
            int g   = lane >> 4;
            av[rb] = *(const bf16x8*)(sa + row * 32 + ((g ^ (row & 3)) << 3));
        }
        #pragma unroll
        for (int cb = 0; cb < 4; ++cb) {
            int col = c0 + cb * 16 + (lane & 15);
            int g   = lane >> 4;
            bv[cb] = *(const bf16x8*)(sb + col * 32 + ((g ^ (col & 3)) << 3));
        }
        #pragma unroll
        for (int rb = 0; rb < 2; ++rb)
            #pragma unroll
            for (int cb = 0; cb < 4; ++cb)
                acc[rb][cb] = __builtin_amdgcn_mfma_f32_16x16x32_bf16(av[rb], bv[cb],
                                                                      acc[rb][cb], 0, 0, 0);
    }
    float* pout = part + (size_t)blockIdx.y * MPAD * NH;
    #pragma unroll
    for (int rb = 0; rb < 2; ++rb)
        #pragma unroll
        for (int cb = 0; cb < 4; ++cb) {
            int rowb = m0 + r0 + rb * 16 + (lane >> 4) * 4;
            int col  = c0 + cb * 16 + (lane & 15);
            #pragma unroll
            for (int reg = 0; reg < 4; ++reg)
                pout[(size_t)(rowb + reg) * NH + col] = acc[rb][cb][reg];
        }
}

// ---------------------------------------------------------------------------
// h_in = elu(bn_in(sum part + b_in)); also writes h_inT bf16 [128][KP] + pad
// ---------------------------------------------------------------------------
__global__ __launch_bounds__(256) void xw_reduce_kernel(const float* __restrict__ part,
                                                        const float* __restrict__ bias,
                                                        const float* __restrict__ g,
                                                        const float* __restrict__ bb,
                                                        const float* __restrict__ rm,
                                                        const float* __restrict__ rv,
                                                        float* __restrict__ h,
                                                        unsigned short* __restrict__ hT)
{
    __shared__ unsigned short tb[128][8];
    const int tid = threadIdx.x;
    int idx = blockIdx.x * 256 + tid;
    const int c4 = (tid & 31) * 4;
    const int lr = tid >> 5;                       // 0..7
    const int m0g = blockIdx.x * 8;
    const size_t ch = (size_t)MPAD * NH / 4;
    const float4* p = (const float4*)part;
    float a[4] = {0.f, 0.f, 0.f, 0.f};
    #pragma unroll
    for (int c = 0; c < NSPLX; ++c) {
        float4 v = p[c * ch + idx];
        a[0] += v.x; a[1] += v.y; a[2] += v.z; a[3] += v.w;
    }
    float o[4];
    #pragma unroll
    for (int j = 0; j < 4; ++j) {
        int c = c4 + j;
        float sc = g[c] / sqrtf(rv[c] + BN_EPS);
        float t = (a[j] + bias[c] - rm[c]) * sc + bb[c];
        o[j] = t > 0.f ? t : expm1f(t);
        tb[c][lr] = f2bf(o[j]);
    }
    float4 ov; ov.x = o[0]; ov.y = o[1]; ov.z = o[2]; ov.w = o[3];
    *(float4*)(h + (size_t)idx * 4) = ov;
    __syncthreads();
    if (tid < 128) {
        ushort4 v0, v1;
        v0.x = tb[tid][0]; v0.y = tb[tid][1]; v0.z = tb[tid][2]; v0.w = tb[tid][3];
        v1.x = tb[tid][4]; v1.y = tb[tid][5]; v1.z = tb[tid][6]; v1.w = tb[tid][7];
        *(ushort4*)(hT + (size_t)tid * KP + m0g)     = v0;
        *(ushort4*)(hT + (size_t)tid * KP + m0g + 4) = v1;
        if (blockIdx.x == 0) {                     // zero the K-pad [10000,10016)
            ushort4 zz; zz.x = zz.y = zz.z = zz.w = 0;
            #pragma unroll
            for (int q = 0; q < 4; ++q)
                *(ushort4*)(hT + (size_t)tid * KP + 10000 + q * 4) = zz;
        }
    }
}

// ---------------------------------------------------------------------------
// GraphSAGE fused: jk = rownorm(relu([h|neigh]@Wg^T + bg)); opt. jkT bf16
// BM=64, BN=128 (full width), K=256, grid MT. Wg is pre-packed bf16 [128][256].
// ---------------------------------------------------------------------------
template<bool WRITE_T>
__global__ __launch_bounds__(256) void gs_fused_kernel(const float* __restrict__ h,
                                                       const float* __restrict__ neigh,
                                                       const unsigned short* __restrict__ Wg,
                                                       const float* __restrict__ bg,
                                                       float* __restrict__ jk,
                                                       unsigned short* __restrict__ jkT)
{
    __shared__ unsigned short sa[64 * 32];
    __shared__ unsigned short sb[128 * 32];
    __shared__ float ssq_l[64][2];
    __shared__ unsigned short tb[WRITE_T ? 128 * 64 : 1];
    const int tid  = threadIdx.x;
    const int lane = tid & 63, w = tid >> 6;
    const int m0   = blockIdx.x * 64;
    const int r0   = (w & 1) * 32;
    const int c0   = (w >> 1) * 64;
    const int arow = tid >> 2, agrp = tid & 3;
    const int mg   = min(m0 + arow, N_NODES - 1);

    f32x4 acc[2][4];
    #pragma unroll
    for (int i = 0; i < 2; ++i)
        #pragma unroll
        for (int j = 0; j < 4; ++j) acc[i][j] = (f32x4){0.f, 0.f, 0.f, 0.f};

    for (int k0 = 0; k0 < 256; k0 += 32) {
        const int kg = k0 + agrp * 8;
        const float* asrc = (kg < 128) ? (h + (size_t)mg * NH + kg)
                                       : (neigh + (size_t)mg * NH + (kg - 128));
        float4 u0 = *(const float4*)asrc;
        float4 u1 = *(const float4*)(asrc + 4);
        float a8[8] = {u0.x, u0.y, u0.z, u0.w, u1.x, u1.y, u1.z, u1.w};
        bf16x8 b8[2];
        #pragma unroll
        for (int t = 0; t < 2; ++t) {
            int gi = tid + t * 256;
            int n = gi >> 2, grp = gi & 3;
            b8[t] = *(const bf16x8*)(Wg + (size_t)n * 256 + k0 + grp * 8);
        }
        __syncthreads();
        *(bf16x8*)(sa + arow * 32 + ((agrp ^ (arow & 3)) << 3)) = cvt8(a8);
        #pragma unroll
        for (int t = 0; t < 2; ++t) {
            int gi = tid + t * 256;
            int n = gi >> 2, grp = gi & 3;
            *(bf16x8*)(sb + n * 32 + ((grp ^ (n & 3)) << 3)) = b8[t];
        }
        __syncthreads();
        bf16x8 av[2], bv[4];
        #pragma unroll
        for (int rb = 0; rb < 2; ++rb) {
            int row = r0 + rb * 16 + (lane & 15);
            int g   = lane >> 4;
            av[rb] = *(const bf16x8*)(sa + row * 32 + ((g ^ (row & 3)) << 3));
        }
        #pragma unroll
        for (int cb = 0; cb < 4; ++cb) {
            int col = c0 + cb * 16 + (lane & 15);
            int g   = lane >> 4;
            bv[cb] = *(const bf16x8*)(sb + col * 32 + ((g ^ (col & 3)) << 3));
        }
        #pragma unroll
        for (int rb = 0; rb < 2; ++rb)
            #pragma unroll
            for (int cb = 0; cb < 4; ++cb)
                acc[rb][cb] = __builtin_amdgcn_mfma_f32_16x16x32_bf16(av[rb], bv[cb],
                                                                      acc[rb][cb], 0, 0, 0);
    }

    // bias + relu + per-row ssq
    float vv[2][4][4];
    float ps[2][4] = {};
    #pragma unroll
    for (int rb = 0; rb < 2; ++rb)
        #pragma unroll
        for (int cb = 0; cb < 4; ++cb) {
            int colg = c0 + cb * 16 + (lane & 15);
            float b = bg[colg];
            #pragma unroll
            for (int reg = 0; reg < 4; ++reg) {
                float t = fmaxf(acc[rb][cb][reg] + b, 0.f);
                vv[rb][cb][reg] = t;
                ps[rb][reg] += t * t;
            }
        }
    #pragma unroll
    for (int msk = 1; msk < 16; msk <<= 1)
        #pragma unroll
        for (int rb = 0; rb < 2; ++rb)
            #pragma unroll
            for (int reg = 0; reg < 4; ++reg)
                ps[rb][reg] += __shfl_xor(ps[rb][reg], msk);
    if ((lane & 15) == 0) {
        #pragma unroll
        for (int rb = 0; rb < 2; ++rb)
            #pragma unroll
            for (int reg = 0; reg < 4; ++reg)
                ssq_l[r0 + rb * 16 + (lane >> 4) * 4 + reg][w >> 1] = ps[rb][reg];
    }
    __syncthreads();
    #pragma unroll
    for (int rb = 0; rb < 2; ++rb)
        #pragma unroll
        for (int reg = 0; reg < 4; ++reg) {
            int lr = r0 + rb * 16 + (lane >> 4) * 4 + reg;
            float s = ssq_l[lr][0] + ssq_l[lr][1];
            float sc = 1.0f / fmaxf(sqrtf(s), 1e-12f);
            int m = m0 + lr;
            #pragma unroll
            for (int cb = 0; cb < 4; ++cb) {
                int colg = c0 + cb * 16 + (lane & 15);
                float o = vv[rb][cb][reg] * sc;
                if (m < N_NODES) jk[(size_t)m * NH + colg] = o;
                if constexpr (WRITE_T) tb[colg * 64 + lr] = f2bf(o);
            }
        }
    if constexpr (WRITE_T) {
        __syncthreads();
        #pragma unroll
        for (int p = 0; p < 4; ++p) {
            int flat = (tid + p * 256) * 8;
            int c = flat >> 6, mo = flat & 63;
            int kglob = m0 + mo;
            if (kglob < KP) {
                unsigned short tmp[8];
                #pragma unroll
                for (int i = 0; i < 8; ++i)
                    tmp[i] = (kglob + i < N_NODES) ? tb[c * 64 + mo + i] : (unsigned short)0;
                ushort4 v0, v1;
                v0.x = tmp[0]; v0.y = tmp[1]; v0.z = tmp[2]; v0.w = tmp[3];
                v1.x = tmp[4]; v1.y = tmp[5]; v1.z = tmp[6]; v1.w = tmp[7];
                *(ushort4*)(jkT + (size_t)c * KP + kglob)     = v0;
                *(ushort4*)(jkT + (size_t)c * KP + kglob + 4) = v1;
            }
        }
    }
}

// ---------------------------------------------------------------------------
// LSTM step fused: z = [xt|h]@[Wih|Whh]^T + biases; gates in-register.
// BM=32, all 512 cols; wave w owns col-slice w*32 of each gate.
// wl: pre-packed bf16 [512][256]. FINAL: fuse JK-mean + bn_in + elu -> hpost.
// ---------------------------------------------------------------------------
template<bool HASC, bool FINAL>
__global__ __launch_bounds__(256) void lstm_fused_kernel(
    int K, const float* __restrict__ a1, const float* __restrict__ a2,
    const unsigned short* __restrict__ wl,
    const float* __restrict__ bih, const float* __restrict__ bhh,
    const float* __restrict__ cprev,
    float* __restrict__ hout, float* __restrict__ cout,
    const float* __restrict__ hmean, const float* __restrict__ bng,
    const float* __restrict__ bnb, const float* __restrict__ bnrm,
    const float* __restrict__ bnrv, float* __restrict__ hpost)
{
    __shared__ unsigned short sa[32 * 32];
    __shared__ unsigned short sb[512 * 32];
    const int tid  = threadIdx.x;
    const int lane = tid & 63, w = tid >> 6;
    const int m0   = blockIdx.x * 32;
    const int arow = tid >> 2, agrp = tid & 3;      // active for tid<128
    const int mg   = min(m0 + arow, N_NODES - 1);

    f32x4 acc[2][8];
    #pragma unroll
    for (int i = 0; i < 2; ++i)
        #pragma unroll
        for (int j = 0; j < 8; ++j) acc[i][j] = (f32x4){0.f, 0.f, 0.f, 0.f};

    for (int k0 = 0; k0 < K; k0 += 32) {
        float a8[8];
        if (tid < 128) {
            int kg = k0 + agrp * 8;
            const float* asrc = (kg < 128) ? (a1 + (size_t)mg * NH + kg)
                                           : (a2 + (size_t)mg * NH + (kg - 128));
            float4 u0 = *(const float4*)asrc;
            float4 u1 = *(const float4*)(asrc + 4);
            a8[0]=u0.x; a8[1]=u0.y; a8[2]=u0.z; a8[3]=u0.w;
            a8[4]=u1.x; a8[5]=u1.y; a8[6]=u1.z; a8[7]=u1.w;
        }
        bf16x8 b8[8];
        #pragma unroll
        for (int t = 0; t < 8; ++t) {
            int gi = tid + t * 256;
            int n = gi >> 2, grp = gi & 3;
            b8[t] = *(const bf16x8*)(wl + (size_t)n * 256 + k0 + grp * 8);
        }
        __syncthreads();
        if (tid < 128)
            *(bf16x8*)(sa + arow * 32 + ((agrp ^ (arow & 3)) << 3)) = cvt8(a8);
        #pragma unroll
        for (int t = 0; t < 8; ++t) {
            int gi = tid + t * 256;
            int n = gi >> 2, grp = gi & 3;
            *(bf16x8*)(sb + n * 32 + ((grp ^ (n & 3)) << 3)) = b8[t];
        }
        __syncthreads();
        bf16x8 av[2];
        #pragma unroll
        for (int rb = 0; rb < 2; ++rb) {
            int row = rb * 16 + (lane & 15);
            int g   = lane >> 4;
            av[rb] = *(const bf16x8*)(sa + row * 32 + ((g ^ (row & 3)) << 3));
        }
        #pragma unroll
        for (int gate = 0; gate < 4; ++gate)
            #pragma unroll
            for (int cb = 0; cb < 2; ++cb) {
                int col = gate * 128 + w * 32 + cb * 16 + (lane & 15);
                int g   = lane >> 4;
                bf16x8 bv = *(const bf16x8*)(sb + col * 32 + ((g ^ (col & 3)) << 3));
                #pragma unroll
                for (int rb = 0; rb < 2; ++rb)
                    acc[rb][gate * 2 + cb] =
                        __builtin_amdgcn_mfma_f32_16x16x32_bf16(av[rb], bv,
                                                                acc[rb][gate * 2 + cb], 0, 0, 0);
            }
    }

    #pragma unroll
    for (int cb = 0; cb < 2; ++cb) {
        const int cg = w * 32 + cb * 16 + (lane & 15);
        const float bi = bih[0 * 128 + cg] + bhh[0 * 128 + cg];
        const float bf = bih[1 * 128 + cg] + bhh[1 * 128 + cg];
        const float bgg= bih[2 * 128 + cg] + bhh[2 * 128 + cg];
        const float bo = bih[3 * 128 + cg] + bhh[3 * 128 + cg];
        float sc = 0.f, sh = 0.f;
        if constexpr (FINAL) {
            sc = bng[cg] / sqrtf(bnrv[cg] + BN_EPS);
            sh = bnb[cg] - bnrm[cg] * sc;
        }
        #pragma unroll
        for (int rb = 0; rb < 2; ++rb) {
            #pragma unroll
            for (int reg = 0; reg < 4; ++reg) {
                int m = m0 + rb * 16 + (lane >> 4) * 4 + reg;
                if (m < N_NODES) {
                    float zi = acc[rb][0 + cb][reg] + bi;
                    float zf = acc[rb][2 + cb][reg] + bf;
                    float zg = acc[rb][4 + cb][reg] + bgg;
                    float zo = acc[rb][6 + cb][reg] + bo;
                    float cn = sigm(zi) * tanhf(zg);
                    if constexpr (HASC) cn += sigm(zf) * cprev[(size_t)m * NH + cg];
                    float hv = sigm(zo) * tanhf(cn);
                    if constexpr (FINAL) {
                        float t = 0.5f * (hmean[(size_t)m * NH + cg] + hv);
                        t = t * sc + sh;
                        hpost[(size_t)m * NH + cg] = t > 0.f ? t : expm1f(t);
                    } else {
                        hout[(size_t)m * NH + cg] = hv;
                        cout[(size_t)m * NH + cg] = cn;
                    }
                }
            }
        }
    }
}

// ---------------------------------------------------------------------------
// Generic MFMA GEMM + bias + BN + ELU (emb / fc). B f32, col-count clamped.
// ---------------------------------------------------------------------------
template<int BM, int BN>
__global__ __launch_bounds__(256) void wgemm_bnelu_kernel(
    int M, int K, int kSplitA,
    const float* __restrict__ a1, int lda1,
    const float* __restrict__ a2, int lda2,
    const float* __restrict__ B, int ldb, int ncol,
    float* __restrict__ out, int ldo,
    const float* __restrict__ bias,
    const float* __restrict__ bng, const float* __restrict__ bnb,
    const float* __restrict__ bnrm, const float* __restrict__ bnrv)
{
    constexpr int WC = BN / 64;
    constexpr int WR = 4 / WC;
    static_assert(WR * WC == 4 && BM == WR * 32, "geometry");
    constexpr int NGA = BM * 4 / 256;
    constexpr int NGB = BN * 4 / 256;
    __shared__ unsigned short sa[BM * 32];
    __shared__ unsigned short sb[BN * 32];
    const int tid  = threadIdx.x;
    const int lane = tid & 63, w = tid >> 6;
    const int m0   = blockIdx.x * BM, n0 = blockIdx.y * BN;
    const int r0   = (w % WR) * 32, c0 = (w / WR) * 64;

    f32x4 acc[2][4];
    #pragma unroll
    for (int i = 0; i < 2; ++i)
        #pragma unroll
        for (int j = 0; j < 4; ++j) acc[i][j] = (f32x4){0.f, 0.f, 0.f, 0.f};

    for (int k0 = 0; k0 < K; k0 += 32) {
        float ar[NGA][8], br[NGB][8];
        #pragma unroll
        for (int t = 0; t < NGA; ++t) {
            int gi = tid + t * 256;
            int row = gi >> 2, grp = gi & 3;
            int mg = min(m0 + row, M - 1);
            int kg = k0 + grp * 8;
            const float* src = (kg < kSplitA) ? (a1 + (size_t)mg * lda1 + kg)
                                              : (a2 + (size_t)mg * lda2 + (kg - kSplitA));
            float4 u0 = *(const float4*)src;
            float4 u1 = *(const float4*)(src + 4);
            ar[t][0]=u0.x; ar[t][1]=u0.y; ar[t][2]=u0.z; ar[t][3]=u0.w;
            ar[t][4]=u1.x; ar[t][5]=u1.y; ar[t][6]=u1.z; ar[t][7]=u1.w;
        }
        #pragma unroll
        for (int t = 0; t < NGB; ++t) {
            int gi = tid + t * 256;
            int n = gi >> 2, grp = gi & 3;
            int ng = min(n0 + n, ncol - 1);
            int kg = k0 + grp * 8;
            const float* src = B + (size_t)ng * ldb + kg;
            float4 u0 = *(const float4*)src;
            float4 u1 = *(const float4*)(src + 4);
            br[t][0]=u0.x; br[t][1]=u0.y; br[t][2]=u0.z; br[t][3]=u0.w;
            br[t][4]=u1.x; br[t][5]=u1.y; br[t][6]=u1.z; br[t][7]=u1.w;
        }
        __syncthreads();
        #pragma unroll
        for (int t = 0; t < NGA; ++t) {
            int gi = tid + t * 256;
            int row = gi >> 2, grp = gi & 3;
            *(bf16x8*)(sa + row * 32 + ((grp ^ (row & 3)) << 3)) = cvt8(ar[t]);
        }
        #pragma unroll
        for (int t = 0; t < NGB; ++t) {
            int gi = tid + t * 256;
            int n = gi >> 2, grp = gi & 3;
            *(bf16x8*)(sb + n * 32 + ((grp ^ (n & 3)) << 3)) = cvt8(br[t]);
        }
        __syncthreads();
        bf16x8 av[2], bv[4];
        #pragma unroll
        for (int rb = 0; rb < 2; ++rb) {
            int row = r0 + rb * 16 + (lane & 15);
            int g   = lane >> 4;
            av[rb] = *(const bf16x8*)(sa + row * 32 + ((g ^ (row & 3)) << 3));
        }
        #pragma unroll
        for (int cb = 0; cb < 4; ++cb) {
            int col = c0 + cb * 16 + (lane & 15);
            int g   = lane >> 4;
            bv[cb] = *(const bf16x8*)(sb + col * 32 + ((g ^ (col & 3)) << 3));
        }
        #pragma unroll
        for (int rb = 0; rb < 2; ++rb)
            #pragma unroll
            for (int cb = 0; cb < 4; ++cb)
                acc[rb][cb] = __builtin_amdgcn_mfma_f32_16x16x32_bf16(av[rb], bv[cb],
                                                                      acc[rb][cb], 0, 0, 0);
    }

    #pragma unroll
    for (int cb = 0; cb < 4; ++cb) {
        const int colg = n0 + c0 + cb * 16 + (lane & 15);
        const int cc = min(colg, ncol - 1);
        float badd = bias[cc];
        float sc = bng[cc] / sqrtf(bnrv[cc] + BN_EPS);
        float sh = bnb[cc] - bnrm[cc] * sc;
        #pragma unroll
        for (int rb = 0; rb < 2; ++rb) {
            int rowb = m0 + r0 + rb * 16 + (lane >> 4) * 4;
            #pragma unroll
            for (int reg = 0; reg < 4; ++reg) {
                int m = rowb + reg;
                if (m < M && colg < ncol) {
                    float t = (acc[rb][cb][reg] + badd) * sc + sh;
                    out[(size_t)m * ldo + colg] = t > 0.f ? t : expm1f(t);
                }
            }
        }
    }
}

// ---------------------------------------------------------------------------
// out = log_softmax(hfc @ W_out.T + b_out)
// ---------------------------------------------------------------------------
__global__ __launch_bounds__(256) void out_kernel(const float* __restrict__ hfc,
                                                  const float* __restrict__ W_out,
                                                  const float* __restrict__ b_out,
                                                  float* __restrict__ out)
{
    __shared__ float wl[NOUT * 193];
    __shared__ float rl[4][DCAT];
    const int tid = threadIdx.x;
    for (int i = tid; i < NOUT * DCAT; i += 256)
        wl[(i / DCAT) * 193 + (i % DCAT)] = W_out[i];
    const int w = tid >> 6, lane = tid & 63;
    const int r = blockIdx.x * 4 + w;
    for (int k = lane; k < DCAT; k += 64) rl[w][k] = hfc[(size_t)r * DCAT + k];
    __syncthreads();
    const int c = lane;
    float acc = -INFINITY;
    if (c < NOUT) {
        acc = b_out[c];
        #pragma unroll 4
        for (int k = 0; k < DCAT; ++k) acc += rl[w][k] * wl[c * 193 + k];
    }
    float mx = acc;
    #pragma unroll
    for (int msk = 16; msk >= 1; msk >>= 1) mx = fmaxf(mx, __shfl_xor(mx, msk));
    float ex = (c < NOUT) ? expf(acc - mx) : 0.f;
    float sm = ex;
    #pragma unroll
    for (int msk = 16; msk >= 1; msk >>= 1) sm += __shfl_xor(sm, msk);
    if (c < NOUT) out[(size_t)r * NOUT + c] = acc - mx - logf(sm);
}

// ---------------------------------------------------------------------------
extern "C" void kernel_launch(void* const* d_in, const int* in_sizes, int n_in,
                              void* d_out, int out_size, void* d_ws, size_t ws_size,
                              hipStream_t stream)
{
    const float* x       = (const float*)d_in[0];
    const float* embed   = (const float*)d_in[1];
    const float* adj     = (const float*)d_in[2];
    const float* W_in    = (const float*)d_in[3];
    const float* b_in    = (const float*)d_in[4];
    const float* bn_in_g = (const float*)d_in[5];
    const float* bn_in_b = (const float*)d_in[6];
    const float* bn_in_rm= (const float*)d_in[7];
    const float* bn_in_rv= (const float*)d_in[8];
    const float* W_gs    = (const float*)d_in[9];
    const float* b_gs    = (const float*)d_in[10];
    const float* Wih0    = (const float*)d_in[11];
    const float* Whh0    = (const float*)d_in[12];
    const float* bih0    = (const float*)d_in[13];
    const float* bhh0    = (const float*)d_in[14];
    const float* Wih1    = (const float*)d_in[15];
    const float* Whh1    = (const float*)d_in[16];
    const float* bih1    = (const float*)d_in[17];
    const float* bhh1    = (const float*)d_in[18];
    const float* W_emb   = (const float*)d_in[19];
    const float* b_emb   = (const float*)d_in[20];
    const float* bn_e_g  = (const float*)d_in[21];
    const float* bn_e_b  = (const float*)d_in[22];
    const float* bn_e_rm = (const float*)d_in[23];
    const float* bn_e_rv = (const float*)d_in[24];
    const float* W_fc    = (const float*)d_in[25];
    const float* b_fc    = (const float*)d_in[26];
    const float* bn_f_g  = (const float*)d_in[27];
    const float* bn_f_b  = (const float*)d_in[28];
    const float* bn_f_rm = (const float*)d_in[29];
    const float* bn_f_rv = (const float*)d_in[30];
    const float* W_out   = (const float*)d_in[31];
    const float* b_out   = (const float*)d_in[32];
    float* outp = (float*)d_out;

    const size_t HB = (size_t)N_NODES * NH * sizeof(float);
    char* wp = (char*)d_ws;
    auto carve = [&](size_t bytes) {
        void* p = (void*)wp;
        wp += (bytes + 1023) & ~(size_t)1023;
        return p;
    };
    float* part  = (float*)carve((size_t)NSPLIT * MPAD * NH * sizeof(float)); // 41.2 MB
    float* part_s= (float*)carve((size_t)NSPLIT * MPAD * sizeof(float));
    float* h_in  = (float*)carve(HB);
    float* neigh = (float*)carve(HB);
    float* jk0   = (float*)carve(HB);
    float* jk1   = (float*)carve(HB);
    float* h1_0  = (float*)carve(HB);
    float* h1_1  = (float*)carve(HB);
    float* c1    = (float*)carve(HB);
    float* h2_0  = (float*)carve(HB);
    float* c2    = (float*)carve(HB);
    float* hpost = (float*)carve(HB);
    float* e     = (float*)carve((size_t)N_NODES * NHE * sizeof(float));
    float* hfc   = (float*)carve((size_t)N_NODES * DCAT * sizeof(float));
    unsigned short* hT  = (unsigned short*)carve((size_t)NH * KP * 2);
    unsigned short* wl  = (unsigned short*)carve((size_t)2 * 512 * 256 * 2);
    unsigned short* wgb = (unsigned short*)carve((size_t)2 * 128 * 256 * 2);
    if ((size_t)(wp - (char*)d_ws) > ws_size) return;

    const dim3 blk(256);

    // 0. pack weights to bf16
    wconv_kernel<<<320, blk, 0, stream>>>(Wih0, Whh0, Wih1, Whh1, W_gs, wl, wgb);

    // 1. h_in = elu(bn_in(x @ W_in.T + b_in)); also h_inT (bf16, padded)
    xw_mfma_kernel<<<dim3(MT, NSPLX), blk, 0, stream>>>(x, W_in, part);
    xw_reduce_kernel<<<1250, blk, 0, stream>>>(part, b_in, bn_in_g, bn_in_b,
                                               bn_in_rm, bn_in_rv, h_in, hT);

    // 2. GraphSAGE layer 0
    adjmm_kernel<<<dim3(MT, NSPLIT), blk, 0, stream>>>(adj, hT, part, part_s);
    nreduce_kernel<<<1250, blk, 0, stream>>>(part, part_s, neigh);
    gs_fused_kernel<true><<<MT, blk, 0, stream>>>(h_in, neigh, wgb, b_gs, jk0, hT);

    // 3. GraphSAGE layer 1
    adjmm_kernel<<<dim3(MT, NSPLIT), blk, 0, stream>>>(adj, hT, part, part_s);
    nreduce_kernel<<<1250, blk, 0, stream>>>(part, part_s, neigh);
    gs_fused_kernel<false><<<MT, blk, 0, stream>>>(jk0, neigh, wgb + 128 * 256, b_gs + 128,
                                                   jk1, nullptr);

    // 4. LSTM jumping-knowledge (fused gates, no z buffer)
    lstm_fused_kernel<false, false><<<313, blk, 0, stream>>>(
        128, jk0, jk0, wl, bih0, bhh0, nullptr, h1_0, c1,
        nullptr, nullptr, nullptr, nullptr, nullptr, nullptr);
    lstm_fused_kernel<true, false><<<313, blk, 0, stream>>>(
        256, jk1, h1_0, wl, bih0, bhh0, c1, h1_1, c1,
        nullptr, nullptr, nullptr, nullptr, nullptr, nullptr);
    lstm_fused_kernel<false, false><<<313, blk, 0, stream>>>(
        128, h1_0, h1_0, wl + 512 * 256, bih1, bhh1, nullptr, h2_0, c2,
        nullptr, nullptr, nullptr, nullptr, nullptr, nullptr);
    lstm_fused_kernel<true, true><<<313, blk, 0, stream>>>(
        256, h1_1, h2_0, wl + 512 * 256, bih1, bhh1, c2, nullptr, nullptr,
        h2_0, bn_in_g, bn_in_b, bn_in_rm, bn_in_rv, hpost);

    // 5. e = elu(bn_emb(embed @ W_emb.T + b_emb))
    wgemm_bnelu_kernel<64, 128><<<dim3(MT, 1), blk, 0, stream>>>(
        N_NODES, NFE, NFE, embed, NFE, nullptr, 0,
        W_emb, NFE, NHE, e, NHE,
        b_emb, bn_e_g, bn_e_b, bn_e_rm, bn_e_rv);

    // 6. hfc = elu(bn_fc([hpost|e] @ W_fc.T + b_fc))
    wgemm_bnelu_kernel<64, 128><<<dim3(MT, 2), blk, 0, stream>>>(
        N_NODES, DCAT, NH, hpost, NH, e, NHE,
        W_fc, DCAT, DCAT, hfc, DCAT,
        b_fc, bn_f_g, bn_f_b, bn_f_rm, bn_f_rv);

    // 7. logits + log_softmax
    out_kernel<<<2500, blk, 0, stream>>>(hfc, W_out, b_out, outp);
}

// Round 6
// 476.862 us; speedup vs baseline: 4.5208x; 1.0195x over previous
//
#include <hip/hip_runtime.h>
#include <hip/hip_bf16.h>
#include <math.h>

#define N_NODES 10000
#define NFEAT   2000
#define NFE     256
#define NH      128
#define NHE     64
#define NOUT    20
#define DCAT    192
#define BN_EPS  1e-5f

#define KP      10016        // padded K for transposed activations
#define KSTEPS  313
#define MT      157          // 64-row m-tiles
#define NSPLIT  8            // adjmm split-K
#define KC      40
#define NSPLX   4            // xw split-K
#define MPAD    10048

typedef __attribute__((ext_vector_type(8))) short  bf16x8;
typedef __attribute__((ext_vector_type(4))) float  f32x4;

__device__ __forceinline__ float sigm(float x) { return 1.0f / (1.0f + expf(-x)); }

__device__ __forceinline__ unsigned short f2bf(float x) {
    union { __hip_bfloat16 h; unsigned short u; } c;
    c.h = __float2bfloat16(x);
    return c.u;
}

__device__ __forceinline__ bf16x8 cvt8(const float* v) {
    bf16x8 r;
    #pragma unroll
    for (int i = 0; i < 8; ++i) r[i] = (short)f2bf(v[i]);
    return r;
}

// ---------------------------------------------------------------------------
// pack weights to bf16: wl[l][512][256] = [Wih_l | Whh_l]; wgb = bf16(W_gs)
// ---------------------------------------------------------------------------
__global__ __launch_bounds__(256) void wconv_kernel(const float* __restrict__ Wih0,
                                                    const float* __restrict__ Whh0,
                                                    const float* __restrict__ Wih1,
                                                    const float* __restrict__ Whh1,
                                                    const float* __restrict__ Wgs,
                                                    unsigned short* __restrict__ wl,
                                                    unsigned short* __restrict__ wgb)
{
    const int total = 262144 + 65536;
    for (int i = blockIdx.x * 256 + threadIdx.x; i < total; i += gridDim.x * 256) {
        if (i < 262144) {
            int l = i >> 17, rem = i & 131071;
            int n = rem >> 8, k = rem & 255;
            const float* src;
            if (l == 0) src = (k < 128) ? (Wih0 + n * 128 + k) : (Whh0 + n * 128 + (k - 128));
            else        src = (k < 128) ? (Wih1 + n * 128 + k) : (Whh1 + n * 128 + (k - 128));
            wl[i] = f2bf(*src);
        } else {
            int j = i - 262144;
            wgb[j] = f2bf(Wgs[j]);
        }
    }
}

// ---------------------------------------------------------------------------
// adjmm split-K, software-pipelined ping-pong LDS (1 barrier/step).
// part[chunk] = adj(f32->bf16 inline) @ hT^T ; part_s rowsum partials.
// ---------------------------------------------------------------------------
__global__ __launch_bounds__(256) void adjmm_kernel(const float* __restrict__ adj,
                                                    const unsigned short* __restrict__ hT,
                                                    float* __restrict__ part,
                                                    float* __restrict__ part_s)
{
    __shared__ unsigned short sa[2][64 * 32];
    __shared__ unsigned short sb[2][128 * 32];
    const int tid  = threadIdx.x;
    const int lane = tid & 63, w = tid >> 6;
    const int m0   = blockIdx.x * 64;
    const int ks0  = blockIdx.y * KC;
    const int ks1  = min(ks0 + KC, KSTEPS);
    const int r0   = (w & 1) * 32;
    const int c0   = (w >> 1) * 64;

    const int arow = tid >> 2, agrp = tid & 3;
    const size_t abase = (size_t)min(m0 + arow, N_NODES - 1) * N_NODES;
    const int bcol = tid >> 1, bg0 = (tid & 1) * 2;

    const int asoff  = arow * 32 + ((agrp ^ (arow & 3)) << 3);
    const int bsoff0 = bcol * 32 + (((bg0 + 0) ^ (bcol & 3)) << 3);
    const int bsoff1 = bcol * 32 + (((bg0 + 1) ^ (bcol & 3)) << 3);

    float rs = 0.f;
    f32x4 acc[2][4];
    #pragma unroll
    for (int i = 0; i < 2; ++i)
        #pragma unroll
        for (int j = 0; j < 4; ++j) acc[i][j] = (f32x4){0.f, 0.f, 0.f, 0.f};

    float av8[8];
    bf16x8 vb0, vb1;
    auto load_step = [&](int ks) {
        const int k0 = ks * 32;
        const int kg = k0 + agrp * 8;
        if (kg + 8 <= N_NODES) {
            float4 u0 = *(const float4*)(adj + abase + kg);
            float4 u1 = *(const float4*)(adj + abase + kg + 4);
            av8[0] = u0.x; av8[1] = u0.y; av8[2] = u0.z; av8[3] = u0.w;
            av8[4] = u1.x; av8[5] = u1.y; av8[6] = u1.z; av8[7] = u1.w;
        } else {
            #pragma unroll
            for (int i = 0; i < 8; ++i) av8[i] = 0.f;
        }
        #pragma unroll
        for (int i = 0; i < 8; ++i) rs += av8[i];
        vb0 = *(const bf16x8*)(hT + (size_t)bcol * KP + k0 + bg0 * 8);
        vb1 = *(const bf16x8*)(hT + (size_t)bcol * KP + k0 + (bg0 + 1) * 8);
    };
    auto write_step = [&](int p) {
        *(bf16x8*)(sa[p] + asoff)  = cvt8(av8);
        *(bf16x8*)(sb[p] + bsoff0) = vb0;
        *(bf16x8*)(sb[p] + bsoff1) = vb1;
    };

    load_step(ks0);
    write_step(0);

    for (int ks = ks0; ks < ks1; ++ks) {
        const int p = (ks - ks0) & 1;
        const bool more = (ks + 1 < ks1);
        if (more) load_step(ks + 1);        // prefetch next step (latency hidden)
        __syncthreads();                    // buf[p] ready; buf[p^1] reads done
        bf16x8 av[2], bv[4];
        #pragma unroll
        for (int rb = 0; rb < 2; ++rb) {
            int row = r0 + rb * 16 + (lane & 15);
            int g   = lane >> 4;
            av[rb] = *(const bf16x8*)(sa[p] + row * 32 + ((g ^ (row & 3)) << 3));
        }
        #pragma unroll
        for (int cb = 0; cb < 4; ++cb) {
            int col = c0 + cb * 16 + (lane & 15);
            int g   = lane >> 4;
            bv[cb] = *(const bf16x8*)(sb[p] + col * 32 + ((g ^ (col & 3)) << 3));
        }
        #pragma unroll
        for (int rb = 0; rb < 2; ++rb)
            #pragma unroll
            for (int cb = 0; cb < 4; ++cb)
                acc[rb][cb] = __builtin_amdgcn_mfma_f32_16x16x32_bf16(av[rb], bv[cb],
                                                                      acc[rb][cb], 0, 0, 0);
        if (more) write_step(p ^ 1);
    }

    rs += __shfl_xor(rs, 1);
    rs += __shfl_xor(rs, 2);
    if ((tid & 3) == 0) part_s[(size_t)blockIdx.y * MPAD + m0 + arow] = rs;

    float* pout = part + (size_t)blockIdx.y * MPAD * NH;
    #pragma unroll
    for (int rb = 0; rb < 2; ++rb)
        #pragma unroll
        for (int cb = 0; cb < 4; ++cb) {
            int rowb = m0 + r0 + rb * 16 + (lane >> 4) * 4;
            int col  = c0 + cb * 16 + (lane & 15);
            #pragma unroll
            for (int reg = 0; reg < 4; ++reg)
                pout[(size_t)(rowb + reg) * NH + col] = acc[rb][cb][reg];
        }
}

// ---------------------------------------------------------------------------
// x @ W_in.T split-K (4 chunks of 16 K-steps), pipelined ping-pong.
// ---------------------------------------------------------------------------
__global__ __launch_bounds__(256) void xw_mfma_kernel(const float* __restrict__ x,
                                                      const float* __restrict__ Wn,
                                                      float* __restrict__ part)
{
    __shared__ unsigned short sa[2][64 * 32];
    __shared__ unsigned short sb[2][128 * 32];
    const int tid  = threadIdx.x;
    const int lane = tid & 63, w = tid >> 6;
    const int m0   = blockIdx.x * 64;
    const int TOT  = (NFEAT + 31) / 32;                 // 63
    const int s0   = blockIdx.y * 16;
    const int s1   = min(s0 + 16, TOT);
    const int r0   = (w & 1) * 32;
    const int c0   = (w >> 1) * 64;

    const int arow = tid >> 2, agrp = tid & 3;
    const size_t abase = (size_t)min(m0 + arow, N_NODES - 1) * NFEAT;
    const int asoff = arow * 32 + ((agrp ^ (arow & 3)) << 3);
    const int bn0 = tid >> 2;            // reuse same decomposition for B (2 granule sets)
    // B granule t: gi = tid + t*256 -> n = gi>>2, grp = gi&3
    int bn_[2], bgrp_[2], bsoff_[2];
    #pragma unroll
    for (int t = 0; t < 2; ++t) {
        int gi = tid + t * 256;
        bn_[t] = gi >> 2; bgrp_[t] = gi & 3;
        bsoff_[t] = bn_[t] * 32 + ((bgrp_[t] ^ (bn_[t] & 3)) << 3);
    }

    f32x4 acc[2][4];
    #pragma unroll
    for (int i = 0; i < 2; ++i)
        #pragma unroll
        for (int j = 0; j < 4; ++j) acc[i][j] = (f32x4){0.f, 0.f, 0.f, 0.f};

    float av8[8], bv8[2][8];
    auto load_step = [&](int ks) {
        const int k0 = ks * 32;
        {
            const int kg = k0 + agrp * 8;
            if (kg + 8 <= NFEAT) {
                float4 u0 = *(const float4*)(x + abase + kg);
                float4 u1 = *(const float4*)(x + abase + kg + 4);
                av8[0]=u0.x; av8[1]=u0.y; av8[2]=u0.z; av8[3]=u0.w;
                av8[4]=u1.x; av8[5]=u1.y; av8[6]=u1.z; av8[7]=u1.w;
            } else {
                #pragma unroll
                for (int i = 0; i < 8; ++i) av8[i] = 0.f;
            }
        }
        #pragma unroll
        for (int t = 0; t < 2; ++t) {
            int kg = k0 + bgrp_[t] * 8;
            if (kg + 8 <= NFEAT) {
                float4 u0 = *(const float4*)(Wn + (size_t)bn_[t] * NFEAT + kg);
                float4 u1 = *(const float4*)(Wn + (size_t)bn_[t] * NFEAT + kg + 4);
                bv8[t][0]=u0.x; bv8[t][1]=u0.y; bv8[t][2]=u0.z; bv8[t][3]=u0.w;
                bv8[t][4]=u1.x; bv8[t][5]=u1.y; bv8[t][6]=u1.z; bv8[t][7]=u1.w;
            } else {
                #pragma unroll
                for (int i = 0; i < 8; ++i) bv8[t][i] = 0.f;
            }
        }
    };
    auto write_step = [&](int p) {
        *(bf16x8*)(sa[p] + asoff) = cvt8(av8);
        #pragma unroll
        for (int t = 0; t < 2; ++t)
            *(bf16x8*)(sb[p] + bsoff_[t]) = cvt8(bv8[t]);
    };

    load_step(s0);
    write_step(0);

    for (int ks = s0; ks < s1; ++ks) {
        const int p = (ks - s0) & 1;
        const bool more = (ks + 1 < s1);
        if (more) load_step(ks + 1);
        __syncthreads();
        bf16x8 av[2], bv[4];
        #pragma unroll
        for (int rb = 0; rb < 2; ++rb) {
            int row = r0 + rb * 16 + (lane & 15);
            int g   = lane >> 4;
            av[rb] = *(const bf16x8*)(sa[p] + row * 32 + ((g ^ (row & 3)) << 3));
        }
        #pragma unroll
        for (int cb = 0; cb < 4; ++cb) {
            int col = c0 + cb * 16 + (lane & 15);
            int g   = lane >> 4;
            bv[cb] = *(const bf16x8*)(sb[p] + col * 32 + ((g ^ (col & 3)) << 3));
        }
        #pragma unroll
        for (int rb = 0; rb < 2; ++rb)
            #pragma unroll
            for (int cb = 0; cb < 4; ++cb)
                acc[rb][cb] = __builtin_amdgcn_mfma_f32_16x16x32_bf16(av[rb], bv[cb],
                                                                      acc[rb][cb], 0, 0, 0);
        if (more) write_step(p ^ 1);
    }
    float* pout = part + (size_t)blockIdx.y * MPAD * NH;
    #pragma unroll
    for (int rb = 0; rb < 2; ++rb)
        #pragma unroll
        for (int cb = 0; cb < 4; ++cb) {
            int rowb = m0 + r0 + rb * 16 + (lane >> 4) * 4;
            int col  = c0 + cb * 16 + (lane & 15);
            #pragma unroll
            for (int reg = 0; reg < 4; ++reg)
                pout[(size_t)(rowb + reg) * NH + col] = acc[rb][cb][reg];
        }
}

// ---------------------------------------------------------------------------
// h_in = elu(bn_in(sum part + b_in)); also writes h_inT bf16 [128][KP] + pad
// ---------------------------------------------------------------------------
__global__ __launch_bounds__(256) void xw_reduce_kernel(const float* __restrict__ part,
                                                        const float* __restrict__ bias,
                                                        const float* __restrict__ g,
                                                        const float* __restrict__ bb,
                                                        const float* __restrict__ rm,
                                                        const float* __restrict__ rv,
                                                        float* __restrict__ h,
                                                        unsigned short* __restrict__ hT)
{
    __shared__ unsigned short tb[128][8];
    const int tid = threadIdx.x;
    int idx = blockIdx.x * 256 + tid;
    const int c4 = (tid & 31) * 4;
    const int lr = tid >> 5;                       // 0..7
    const int m0g = blockIdx.x * 8;
    const size_t ch = (size_t)MPAD * NH / 4;
    const float4* p = (const float4*)part;
    float a[4] = {0.f, 0.f, 0.f, 0.f};
    #pragma unroll
    for (int c = 0; c < NSPLX; ++c) {
        float4 v = p[c * ch + idx];
        a[0] += v.x; a[1] += v.y; a[2] += v.z; a[3] += v.w;
    }
    float o[4];
    #pragma unroll
    for (int j = 0; j < 4; ++j) {
        int c = c4 + j;
        float sc = g[c] / sqrtf(rv[c] + BN_EPS);
        float t = (a[j] + bias[c] - rm[c]) * sc + bb[c];
        o[j] = t > 0.f ? t : expm1f(t);
        tb[c][lr] = f2bf(o[j]);
    }
    float4 ov; ov.x = o[0]; ov.y = o[1]; ov.z = o[2]; ov.w = o[3];
    *(float4*)(h + (size_t)idx * 4) = ov;
    __syncthreads();
    if (tid < 128) {
        ushort4 v0, v1;
        v0.x = tb[tid][0]; v0.y = tb[tid][1]; v0.z = tb[tid][2]; v0.w = tb[tid][3];
        v1.x = tb[tid][4]; v1.y = tb[tid][5]; v1.z = tb[tid][6]; v1.w = tb[tid][7];
        *(ushort4*)(hT + (size_t)tid * KP + m0g)     = v0;
        *(ushort4*)(hT + (size_t)tid * KP + m0g + 4) = v1;
        if (blockIdx.x == 0) {                     // zero the K-pad [10000,10016)
            ushort4 zz; zz.x = zz.y = zz.z = zz.w = 0;
            #pragma unroll
            for (int q = 0; q < 4; ++q)
                *(ushort4*)(hT + (size_t)tid * KP + 10000 + q * 4) = zz;
        }
    }
}

// ---------------------------------------------------------------------------
// GraphSAGE fused (+nreduce): A = [h | (sum_c part)/rowsum]; jk = rownorm(
// relu(A@Wg^T + bg)); opt. jkT bf16. BM=64, K=256, grid MT.
// ---------------------------------------------------------------------------
template<bool WRITE_T>
__global__ __launch_bounds__(256) void gs_fused_kernel(const float* __restrict__ h,
                                                       const float* __restrict__ part,
                                                       const float* __restrict__ part_s,
                                                       const unsigned short* __restrict__ Wg,
                                                       const float* __restrict__ bg,
                                                       float* __restrict__ jk,
                                                       unsigned short* __restrict__ jkT)
{
    __shared__ unsigned short sa[64 * 32];
    __shared__ unsigned short sb[128 * 32];
    __shared__ float ssq_l[64][2];
    __shared__ unsigned short tb[WRITE_T ? 128 * 64 : 1];
    const int tid  = threadIdx.x;
    const int lane = tid & 63, w = tid >> 6;
    const int m0   = blockIdx.x * 64;
    const int r0   = (w & 1) * 32;
    const int c0   = (w >> 1) * 64;
    const int arow = tid >> 2, agrp = tid & 3;
    const int mg   = min(m0 + arow, N_NODES - 1);

    float inv;
    {
        float s = 0.f;
        #pragma unroll
        for (int c = 0; c < NSPLIT; ++c) s += part_s[(size_t)c * MPAD + mg];
        inv = 1.0f / s;
    }

    f32x4 acc[2][4];
    #pragma unroll
    for (int i = 0; i < 2; ++i)
        #pragma unroll
        for (int j = 0; j < 4; ++j) acc[i][j] = (f32x4){0.f, 0.f, 0.f, 0.f};

    for (int k0 = 0; k0 < 256; k0 += 32) {
        const int kg = k0 + agrp * 8;
        float a8[8];
        if (kg < 128) {
            const float* asrc = h + (size_t)mg * NH + kg;
            float4 u0 = *(const float4*)asrc;
            float4 u1 = *(const float4*)(asrc + 4);
            a8[0]=u0.x; a8[1]=u0.y; a8[2]=u0.z; a8[3]=u0.w;
            a8[4]=u1.x; a8[5]=u1.y; a8[6]=u1.z; a8[7]=u1.w;
        } else {
            const int cc = kg - 128;
            float s0x=0,s0y=0,s0z=0,s0w=0,s1x=0,s1y=0,s1z=0,s1w=0;
            #pragma unroll
            for (int c = 0; c < NSPLIT; ++c) {
                const float* pp = part + (size_t)c * MPAD * NH + (size_t)mg * NH + cc;
                float4 v0 = *(const float4*)pp;
                float4 v1 = *(const float4*)(pp + 4);
                s0x+=v0.x; s0y+=v0.y; s0z+=v0.z; s0w+=v0.w;
                s1x+=v1.x; s1y+=v1.y; s1z+=v1.z; s1w+=v1.w;
            }
            a8[0]=s0x*inv; a8[1]=s0y*inv; a8[2]=s0z*inv; a8[3]=s0w*inv;
            a8[4]=s1x*inv; a8[5]=s1y*inv; a8[6]=s1z*inv; a8[7]=s1w*inv;
        }
        bf16x8 b8[2];
        #pragma unroll
        for (int t = 0; t < 2; ++t) {
            int gi = tid + t * 256;
            int n = gi >> 2, grp = gi & 3;
            b8[t] = *(const bf16x8*)(Wg + (size_t)n * 256 + k0 + grp * 8);
        }
        __syncthreads();
        *(bf16x8*)(sa + arow * 32 + ((agrp ^ (arow & 3)) << 3)) = cvt8(a8);
        #pragma unroll
        for (int t = 0; t < 2; ++t) {
            int gi = tid + t * 256;
            int n = gi >> 2, grp = gi & 3;
            *(bf16x8*)(sb + n * 32 + ((grp ^ (n & 3)) << 3)) = b8[t];
        }
        __syncthreads();
        bf16x8 av[2], bv[4];
        #pragma unroll
        for (int rb = 0; rb < 2; ++rb) {
            int row = r0 + rb * 16 + (lane & 15);
            int g   = lane >> 4;
            av[rb] = *(const bf16x8*)(sa + row * 32 + ((g ^ (row & 3)) << 3));
        }
        #pragma unroll
        for (int cb = 0; cb < 4; ++cb) {
            int col = c0 + cb * 16 + (lane & 15);
            int g   = lane >> 4;
            bv[cb] = *(const bf16x8*)(sb + col * 32 + ((g ^ (col & 3)) << 3));
        }
        #pragma unroll
        for (int rb = 0; rb < 2; ++rb)
            #pragma unroll
            for (int cb = 0; cb < 4; ++cb)
                acc[rb][cb] = __builtin_amdgcn_mfma_f32_16x16x32_bf16(av[rb], bv[cb],
                                                                      acc[rb][cb], 0, 0, 0);
    }

    // bias + relu + per-row ssq
    float vv[2][4][4];
    float ps[2][4] = {};
    #pragma unroll
    for (int rb = 0; rb < 2; ++rb)
        #pragma unroll
        for (int cb = 0; cb < 4; ++cb) {
            int colg = c0 + cb * 16 + (lane & 15);
            float b = bg[colg];
            #pragma unroll
            for (int reg = 0; reg < 4; ++reg) {
                float t = fmaxf(acc[rb][cb][reg] + b, 0.f);
                vv[rb][cb][reg] = t;
                ps[rb][reg] += t * t;
            }
        }
    #pragma unroll
    for (int msk = 1; msk < 16; msk <<= 1)
        #pragma unroll
        for (int rb = 0; rb < 2; ++rb)
            #pragma unroll
            for (int reg = 0; reg < 4; ++reg)
                ps[rb][reg] += __shfl_xor(ps[rb][reg], msk);
    if ((lane & 15) == 0) {
        #pragma unroll
        for (int rb = 0; rb < 2; ++rb)
            #pragma unroll
            for (int reg = 0; reg < 4; ++reg)
                ssq_l[r0 + rb * 16 + (lane >> 4) * 4 + reg][w >> 1] = ps[rb][reg];
    }
    __syncthreads();
    #pragma unroll
    for (int rb = 0; rb < 2; ++rb)
        #pragma unroll
        for (int reg = 0; reg < 4; ++reg) {
            int lr = r0 + rb * 16 + (lane >> 4) * 4 + reg;
            float s = ssq_l[lr][0] + ssq_l[lr][1];
            float sc = 1.0f / fmaxf(sqrtf(s), 1e-12f);
            int m = m0 + lr;
            #pragma unroll
            for (int cb = 0; cb < 4; ++cb) {
                int colg = c0 + cb * 16 + (lane & 15);
                float o = vv[rb][cb][reg] * sc;
                if (m < N_NODES) jk[(size_t)m * NH + colg] = o;
                if constexpr (WRITE_T) tb[colg * 64 + lr] = f2bf(o);
            }
        }
    if constexpr (WRITE_T) {
        __syncthreads();
        #pragma unroll
        for (int p = 0; p < 4; ++p) {
            int flat = (tid + p * 256) * 8;
            int c = flat >> 6, mo = flat & 63;
            int kglob = m0 + mo;
            if (kglob < KP) {
                unsigned short tmp[8];
                #pragma unroll
                for (int i = 0; i < 8; ++i)
                    tmp[i] = (kglob + i < N_NODES) ? tb[c * 64 + mo + i] : (unsigned short)0;
                ushort4 v0, v1;
                v0.x = tmp[0]; v0.y = tmp[1]; v0.z = tmp[2]; v0.w = tmp[3];
                v1.x = tmp[4]; v1.y = tmp[5]; v1.z = tmp[6]; v1.w = tmp[7];
                *(ushort4*)(jkT + (size_t)c * KP + kglob)     = v0;
                *(ushort4*)(jkT + (size_t)c * KP + kglob + 4) = v1;
            }
        }
    }
}

// ---------------------------------------------------------------------------
// LSTM step fused: z = [xt|h]@[Wih|Whh]^T + biases; gates in-register.
// ---------------------------------------------------------------------------
template<bool HASC, bool FINAL>
__global__ __launch_bounds__(256) void lstm_fused_kernel(
    int K, const float* __restrict__ a1, const float* __restrict__ a2,
    const unsigned short* __restrict__ wl,
    const float* __restrict__ bih, const float* __restrict__ bhh,
    const float* __restrict__ cprev,
    float* __restrict__ hout, float* __restrict__ cout,
    const float* __restrict__ hmean, const float* __restrict__ bng,
    const float* __restrict__ bnb, const float* __restrict__ bnrm,
    const float* __restrict__ bnrv, float* __restrict__ hpost)
{
    __shared__ unsigned short sa[32 * 32];
    __shared__ unsigned short sb[512 * 32];
    const int tid  = threadIdx.x;
    const int lane = tid & 63, w = tid >> 6;
    const int m0   = blockIdx.x * 32;
    const int arow = tid >> 2, agrp = tid & 3;      // active for tid<128
    const int mg   = min(m0 + arow, N_NODES - 1);

    f32x4 acc[2][8];
    #pragma unroll
    for (int i = 0; i < 2; ++i)
        #pragma unroll
        for (int j = 0; j < 8; ++j) acc[i][j] = (f32x4){0.f, 0.f, 0.f, 0.f};

    for (int k0 = 0; k0 < K; k0 += 32) {
        float a8[8];
        if (tid < 128) {
            int kg = k0 + agrp * 8;
            const float* asrc = (kg < 128) ? (a1 + (size_t)mg * NH + kg)
                                           : (a2 + (size_t)mg * NH + (kg - 128));
            float4 u0 = *(const float4*)asrc;
            float4 u1 = *(const float4*)(asrc + 4);
            a8[0]=u0.x; a8[1]=u0.y; a8[2]=u0.z; a8[3]=u0.w;
            a8[4]=u1.x; a8[5]=u1.y; a8[6]=u1.z; a8[7]=u1.w;
        }
        bf16x8 b8[8];
        #pragma unroll
        for (int t = 0; t < 8; ++t) {
            int gi = tid + t * 256;
            int n = gi >> 2, grp = gi & 3;
            b8[t] = *(const bf16x8*)(wl + (size_t)n * 256 + k0 + grp * 8);
        }
        __syncthreads();
        if (tid < 128)
            *(bf16x8*)(sa + arow * 32 + ((agrp ^ (arow & 3)) << 3)) = cvt8(a8);
        #pragma unroll
        for (int t = 0; t < 8; ++t) {
            int gi = tid + t * 256;
            int n = gi >> 2, grp = gi & 3;
            *(bf16x8*)(sb + n * 32 + ((grp ^ (n & 3)) << 3)) = b8[t];
        }
        __syncthreads();
        bf16x8 av[2];
        #pragma unroll
        for (int rb = 0; rb < 2; ++rb) {
            int row = rb * 16 + (lane & 15);
            int g   = lane >> 4;
            av[rb] = *(const bf16x8*)(sa + row * 32 + ((g ^ (row & 3)) << 3));
        }
        #pragma unroll
        for (int gate = 0; gate < 4; ++gate)
            #pragma unroll
            for (int cb = 0; cb < 2; ++cb) {
                int col = gate * 128 + w * 32 + cb * 16 + (lane & 15);
                int g   = lane >> 4;
                bf16x8 bv = *(const bf16x8*)(sb + col * 32 + ((g ^ (col & 3)) << 3));
                #pragma unroll
                for (int rb = 0; rb < 2; ++rb)
                    acc[rb][gate * 2 + cb] =
                        __builtin_amdgcn_mfma_f32_16x16x32_bf16(av[rb], bv,
                                                                acc[rb][gate * 2 + cb], 0, 0, 0);
            }
    }

    #pragma unroll
    for (int cb = 0; cb < 2; ++cb) {
        const int cg = w * 32 + cb * 16 + (lane & 15);
        const float bi = bih[0 * 128 + cg] + bhh[0 * 128 + cg];
        const float bf = bih[1 * 128 + cg] + bhh[1 * 128 + cg];
        const float bgg= bih[2 * 128 + cg] + bhh[2 * 128 + cg];
        const float bo = bih[3 * 128 + cg] + bhh[3 * 128 + cg];
        float sc = 0.f, sh = 0.f;
        if constexpr (FINAL) {
            sc = bng[cg] / sqrtf(bnrv[cg] + BN_EPS);
            sh = bnb[cg] - bnrm[cg] * sc;
        }
        #pragma unroll
        for (int rb = 0; rb < 2; ++rb) {
            #pragma unroll
            for (int reg = 0; reg < 4; ++reg) {
                int m = m0 + rb * 16 + (lane >> 4) * 4 + reg;
                if (m < N_NODES) {
                    float zi = acc[rb][0 + cb][reg] + bi;
                    float zf = acc[rb][2 + cb][reg] + bf;
                    float zg = acc[rb][4 + cb][reg] + bgg;
                    float zo = acc[rb][6 + cb][reg] + bo;
                    float cn = sigm(zi) * tanhf(zg);
                    if constexpr (HASC) cn += sigm(zf) * cprev[(size_t)m * NH + cg];
                    float hv = sigm(zo) * tanhf(cn);
                    if constexpr (FINAL) {
                        float t = 0.5f * (hmean[(size_t)m * NH + cg] + hv);
                        t = t * sc + sh;
                        hpost[(size_t)m * NH + cg] = t > 0.f ? t : expm1f(t);
                    } else {
                        hout[(size_t)m * NH + cg] = hv;
                        cout[(size_t)m * NH + cg] = cn;
                    }
                }
            }
        }
    }
}

// ---------------------------------------------------------------------------
// Generic MFMA GEMM + bias + BN + ELU (emb / fc). B f32, col-count clamped.
// ---------------------------------------------------------------------------
template<int BM, int BN>
__global__ __launch_bounds__(256) void wgemm_bnelu_kernel(
    int M, int K, int kSplitA,
    const float* __restrict__ a1, int lda1,
    const float* __restrict__ a2, int lda2,
    const float* __restrict__ B, int ldb, int ncol,
    float* __restrict__ out, int ldo,
    const float* __restrict__ bias,
    const float* __restrict__ bng, const float* __restrict__ bnb,
    const float* __restrict__ bnrm, const float* __restrict__ bnrv)
{
    constexpr int WC = BN / 64;
    constexpr int WR = 4 / WC;
    static_assert(WR * WC == 4 && BM == WR * 32, "geometry");
    constexpr int NGA = BM * 4 / 256;
    constexpr int NGB = BN * 4 / 256;
    __shared__ unsigned short sa[BM * 32];
    __shared__ unsigned short sb[BN * 32];
    const int tid  = threadIdx.x;
    const int lane = tid & 63, w = tid >> 6;
    const int m0   = blockIdx.x * BM, n0 = blockIdx.y * BN;
    const int r0   = (w % WR) * 32, c0 = (w / WR) * 64;

    f32x4 acc[2][4];
    #pragma unroll
    for (int i = 0; i < 2; ++i)
        #pragma unroll
        for (int j = 0; j < 4; ++j) acc[i][j] = (f32x4){0.f, 0.f, 0.f, 0.f};

    for (int k0 = 0; k0 < K; k0 += 32) {
        float ar[NGA][8], br[NGB][8];
        #pragma unroll
        for (int t = 0; t < NGA; ++t) {
            int gi = tid + t * 256;
            int row = gi >> 2, grp = gi & 3;
            int mg = min(m0 + row, M - 1);
            int kg = k0 + grp * 8;
            const float* src = (kg < kSplitA) ? (a1 + (size_t)mg * lda1 + kg)
                                              : (a2 + (size_t)mg * lda2 + (kg - kSplitA));
            float4 u0 = *(const float4*)src;
            float4 u1 = *(const float4*)(src + 4);
            ar[t][0]=u0.x; ar[t][1]=u0.y; ar[t][2]=u0.z; ar[t][3]=u0.w;
            ar[t][4]=u1.x; ar[t][5]=u1.y; ar[t][6]=u1.z; ar[t][7]=u1.w;
        }
        #pragma unroll
        for (int t = 0; t < NGB; ++t) {
            int gi = tid + t * 256;
            int n = gi >> 2, grp = gi & 3;
            int ng = min(n0 + n, ncol - 1);
            int kg = k0 + grp * 8;
            const float* src = B + (size_t)ng * ldb + kg;
            float4 u0 = *(const float4*)src;
            float4 u1 = *(const float4*)(src + 4);
            br[t][0]=u0.x; br[t][1]=u0.y; br[t][2]=u0.z; br[t][3]=u0.w;
            br[t][4]=u1.x; br[t][5]=u1.y; br[t][6]=u1.z; br[t][7]=u1.w;
        }
        __syncthreads();
        #pragma unroll
        for (int t = 0; t < NGA; ++t) {
            int gi = tid + t * 256;
            int row = gi >> 2, grp = gi & 3;
            *(bf16x8*)(sa + row * 32 + ((grp ^ (row & 3)) << 3)) = cvt8(ar[t]);
        }
        #pragma unroll
        for (int t = 0; t < NGB; ++t) {
            int gi = tid + t * 256;
            int n = gi >> 2, grp = gi & 3;
            *(bf16x8*)(sb + n * 32 + ((grp ^ (n & 3)) << 3)) = cvt8(br[t]);
        }
        __syncthreads();
        bf16x8 av[2], bv[4];
        #pragma unroll
        for (int rb = 0; rb < 2; ++rb) {
            int row = r0 + rb * 16 + (lane & 15);
            int g   = lane >> 4;
            av[rb] = *(const bf16x8*)(sa + row * 32 + ((g ^ (row & 3)) << 3));
        }
        #pragma unroll
        for (int cb = 0; cb < 4; ++cb) {
            int col = c0 + cb * 16 + (lane & 15);
            int g   = lane >> 4;
            bv[cb] = *(const bf16x8*)(sb + col * 32 + ((g ^ (col & 3)) << 3));
        }
        #pragma unroll
        for (int rb = 0; rb < 2; ++rb)
            #pragma unroll
            for (int cb = 0; cb < 4; ++cb)
                acc[rb][cb] = __builtin_amdgcn_mfma_f32_16x16x32_bf16(av[rb], bv[cb],
                                                                      acc[rb][cb], 0, 0, 0);
    }

    #pragma unroll
    for (int cb = 0; cb < 4; ++cb) {
        const int colg = n0 + c0 + cb * 16 + (lane & 15);
        const int cc = min(colg, ncol - 1);
        float badd = bias[cc];
        float sc = bng[cc] / sqrtf(bnrv[cc] + BN_EPS);
        float sh = bnb[cc] - bnrm[cc] * sc;
        #pragma unroll
        for (int rb = 0; rb < 2; ++rb) {
            int rowb = m0 + r0 + rb * 16 + (lane >> 4) * 4;
            #pragma unroll
            for (int reg = 0; reg < 4; ++reg) {
                int m = rowb + reg;
                if (m < M && colg < ncol) {
                    float t = (acc[rb][cb][reg] + badd) * sc + sh;
                    out[(size_t)m * ldo + colg] = t > 0.f ? t : expm1f(t);
                }
            }
        }
    }
}

// ---------------------------------------------------------------------------
// out = log_softmax(hfc @ W_out.T + b_out)
// ---------------------------------------------------------------------------
__global__ __launch_bounds__(256) void out_kernel(const float* __restrict__ hfc,
                                                  const float* __restrict__ W_out,
                                                  const float* __restrict__ b_out,
                                                  float* __restrict__ out)
{
    __shared__ float wl[NOUT * 193];
    __shared__ float rl[4][DCAT];
    const int tid = threadIdx.x;
    for (int i = tid; i < NOUT * DCAT; i += 256)
        wl[(i / DCAT) * 193 + (i % DCAT)] = W_out[i];
    const int w = tid >> 6, lane = tid & 63;
    const int r = blockIdx.x * 4 + w;
    for (int k = lane; k < DCAT; k += 64) rl[w][k] = hfc[(size_t)r * DCAT + k];
    __syncthreads();
    const int c = lane;
    float acc = -INFINITY;
    if (c < NOUT) {
        acc = b_out[c];
        #pragma unroll 4
        for (int k = 0; k < DCAT; ++k) acc += rl[w][k] * wl[c * 193 + k];
    }
    float mx = acc;
    #pragma unroll
    for (int msk = 16; msk >= 1; msk >>= 1) mx = fmaxf(mx, __shfl_xor(mx, msk));
    float ex = (c < NOUT) ? expf(acc - mx) : 0.f;
    float sm = ex;
    #pragma unroll
    for (int msk = 16; msk >= 1; msk >>= 1) sm += __shfl_xor(sm, msk);
    if (c < NOUT) out[(size_t)r * NOUT + c] = acc - mx - logf(sm);
}

// ---------------------------------------------------------------------------
extern "C" void kernel_launch(void* const* d_in, const int* in_sizes, int n_in,
                              void* d_out, int out_size, void* d_ws, size_t ws_size,
                              hipStream_t stream)
{
    const float* x       = (const float*)d_in[0];
    const float* embed   = (const float*)d_in[1];
    const float* adj     = (const float*)d_in[2];
    const float* W_in    = (const float*)d_in[3];
    const float* b_in    = (const float*)d_in[4];
    const float* bn_in_g = (const float*)d_in[5];
    const float* bn_in_b = (const float*)d_in[6];
    const float* bn_in_rm= (const float*)d_in[7];
    const float* bn_in_rv= (const float*)d_in[8];
    const float* W_gs    = (const float*)d_in[9];
    const float* b_gs    = (const float*)d_in[10];
    const float* Wih0    = (const float*)d_in[11];
    const float* Whh0    = (const float*)d_in[12];
    const float* bih0    = (const float*)d_in[13];
    const float* bhh0    = (const float*)d_in[14];
    const float* Wih1    = (const float*)d_in[15];
    const float* Whh1    = (const float*)d_in[16];
    const float* bih1    = (const float*)d_in[17];
    const float* bhh1    = (const float*)d_in[18];
    const float* W_emb   = (const float*)d_in[19];
    const float* b_emb   = (const float*)d_in[20];
    const float* bn_e_g  = (const float*)d_in[21];
    const float* bn_e_b  = (const float*)d_in[22];
    const float* bn_e_rm = (const float*)d_in[23];
    const float* bn_e_rv = (const float*)d_in[24];
    const float* W_fc    = (const float*)d_in[25];
    const float* b_fc    = (const float*)d_in[26];
    const float* bn_f_g  = (const float*)d_in[27];
    const float* bn_f_b  = (const float*)d_in[28];
    const float* bn_f_rm = (const float*)d_in[29];
    const float* bn_f_rv = (const float*)d_in[30];
    const float* W_out   = (const float*)d_in[31];
    const float* b_out   = (const float*)d_in[32];
    float* outp = (float*)d_out;

    const size_t HB = (size_t)N_NODES * NH * sizeof(float);
    char* wp = (char*)d_ws;
    auto carve = [&](size_t bytes) {
        void* p = (void*)wp;
        wp += (bytes + 1023) & ~(size_t)1023;
        return p;
    };
    float* part  = (float*)carve((size_t)NSPLIT * MPAD * NH * sizeof(float)); // 41.2 MB
    float* part_s= (float*)carve((size_t)NSPLIT * MPAD * sizeof(float));
    float* h_in  = (float*)carve(HB);
    float* jk0   = (float*)carve(HB);
    float* jk1   = (float*)carve(HB);
    float* h1_0  = (float*)carve(HB);
    float* h1_1  = (float*)carve(HB);
    float* c1    = (float*)carve(HB);
    float* h2_0  = (float*)carve(HB);
    float* c2    = (float*)carve(HB);
    float* hpost = (float*)carve(HB);
    float* e     = (float*)carve((size_t)N_NODES * NHE * sizeof(float));
    float* hfc   = (float*)carve((size_t)N_NODES * DCAT * sizeof(float));
    unsigned short* hT  = (unsigned short*)carve((size_t)NH * KP * 2);
    unsigned short* wl  = (unsigned short*)carve((size_t)2 * 512 * 256 * 2);
    unsigned short* wgb = (unsigned short*)carve((size_t)2 * 128 * 256 * 2);
    if ((size_t)(wp - (char*)d_ws) > ws_size) return;

    const dim3 blk(256);

    // 0. pack weights to bf16
    wconv_kernel<<<320, blk, 0, stream>>>(Wih0, Whh0, Wih1, Whh1, W_gs, wl, wgb);

    // 1. h_in = elu(bn_in(x @ W_in.T + b_in)); also h_inT (bf16, padded)
    xw_mfma_kernel<<<dim3(MT, NSPLX), blk, 0, stream>>>(x, W_in, part);
    xw_reduce_kernel<<<1250, blk, 0, stream>>>(part, b_in, bn_in_g, bn_in_b,
                                               bn_in_rm, bn_in_rv, h_in, hT);

    // 2. GraphSAGE layer 0 (adjmm pipelined; nreduce fused into gs)
    adjmm_kernel<<<dim3(MT, NSPLIT), blk, 0, stream>>>(adj, hT, part, part_s);
    gs_fused_kernel<true><<<MT, blk, 0, stream>>>(h_in, part, part_s, wgb, b_gs, jk0, hT);

    // 3. GraphSAGE layer 1
    adjmm_kernel<<<dim3(MT, NSPLIT), blk, 0, stream>>>(adj, hT, part, part_s);
    gs_fused_kernel<false><<<MT, blk, 0, stream>>>(jk0, part, part_s, wgb + 128 * 256,
                                                   b_gs + 128, jk1, nullptr);

    // 4. LSTM jumping-knowledge (fused gates, no z buffer)
    lstm_fused_kernel<false, false><<<313, blk, 0, stream>>>(
        128, jk0, jk0, wl, bih0, bhh0, nullptr, h1_0, c1,
        nullptr, nullptr, nullptr, nullptr, nullptr, nullptr);
    lstm_fused_kernel<true, false><<<313, blk, 0, stream>>>(
        256, jk1, h1_0, wl, bih0, bhh0, c1, h1_1, c1,
        nullptr, nullptr, nullptr, nullptr, nullptr, nullptr);
    lstm_fused_kernel<false, false><<<313, blk, 0, stream>>>(
        128, h1_0, h1_0, wl + 512 * 256, bih1, bhh1, nullptr, h2_0, c2,
        nullptr, nullptr, nullptr, nullptr, nullptr, nullptr);
    lstm_fused_kernel<true, true><<<313, blk, 0, stream>>>(
        256, h1_1, h2_0, wl + 512 * 256, bih1, bhh1, c2, nullptr, nullptr,
        h2_0, bn_in_g, bn_in_b, bn_in_rm, bn_in_rv, hpost);

    // 5. e = elu(bn_emb(embed @ W_emb.T + b_emb))
    wgemm_bnelu_kernel<64, 128><<<dim3(MT, 1), blk, 0, stream>>>(
        N_NODES, NFE, NFE, embed, NFE, nullptr, 0,
        W_emb, NFE, NHE, e, NHE,
        b_emb, bn_e_g, bn_e_b, bn_e_rm, bn_e_rv);

    // 6. hfc = elu(bn_fc([hpost|e] @ W_fc.T + b_fc))
    wgemm_bnelu_kernel<64, 128><<<dim3(MT, 2), blk, 0, stream>>>(
        N_NODES, DCAT, NH, hpost, NH, e, NHE,
        W_fc, DCAT, DCAT, hfc, DCAT,
        b_fc, bn_f_g, bn_f_b, bn_f_rm, bn_f_rv);

    // 7. logits + log_softmax
    out_kernel<<<2500, blk, 0, stream>>>(hfc, W_out, b_out, outp);
}

// Round 7
// 475.423 us; speedup vs baseline: 4.5345x; 1.0030x over previous
//
#include <hip/hip_runtime.h>
#include <hip/hip_bf16.h>
#include <math.h>

#define N_NODES 10000
#define NFEAT   2000
#define NFE     256
#define NH      128
#define NHE     64
#define NOUT    20
#define DCAT    192
#define BN_EPS  1e-5f

#define KP      10016        // padded K for transposed activations
#define KSTEPS  313
#define MT      157          // 64-row m-tiles
#define NSPLIT  16           // adjmm split-K
#define KC      20
#define NSPLX   4            // xw split-K
#define MPAD    10048

typedef __attribute__((ext_vector_type(8))) short  bf16x8;
typedef __attribute__((ext_vector_type(4))) float  f32x4;

__device__ __forceinline__ float sigm(float x) { return 1.0f / (1.0f + expf(-x)); }

__device__ __forceinline__ unsigned short f2bf(float x) {
    union { __hip_bfloat16 h; unsigned short u; } c;
    c.h = __float2bfloat16(x);
    return c.u;
}

__device__ __forceinline__ float bf2f(unsigned short u) {
    union { float f; unsigned int i; } c;
    c.i = ((unsigned int)u) << 16;
    return c.f;
}

__device__ __forceinline__ bf16x8 cvt8(const float* v) {
    bf16x8 r;
    #pragma unroll
    for (int i = 0; i < 8; ++i) r[i] = (short)f2bf(v[i]);
    return r;
}

// ---------------------------------------------------------------------------
// pack weights to bf16: wl[l][512][256] = [Wih_l | Whh_l]; wgb = bf16(W_gs)
// ---------------------------------------------------------------------------
__global__ __launch_bounds__(256) void wconv_kernel(const float* __restrict__ Wih0,
                                                    const float* __restrict__ Whh0,
                                                    const float* __restrict__ Wih1,
                                                    const float* __restrict__ Whh1,
                                                    const float* __restrict__ Wgs,
                                                    unsigned short* __restrict__ wl,
                                                    unsigned short* __restrict__ wgb)
{
    const int total = 262144 + 65536;
    for (int i = blockIdx.x * 256 + threadIdx.x; i < total; i += gridDim.x * 256) {
        if (i < 262144) {
            int l = i >> 17, rem = i & 131071;
            int n = rem >> 8, k = rem & 255;
            const float* src;
            if (l == 0) src = (k < 128) ? (Wih0 + n * 128 + k) : (Whh0 + n * 128 + (k - 128));
            else        src = (k < 128) ? (Wih1 + n * 128 + k) : (Whh1 + n * 128 + (k - 128));
            wl[i] = f2bf(*src);
        } else {
            int j = i - 262144;
            wgb[j] = f2bf(Wgs[j]);
        }
    }
}

// ---------------------------------------------------------------------------
// adjmm split-K, ping-pong LDS, loads fully overlapped (rs after MFMA).
// part[chunk] (bf16) = adj @ hT^T ; part_s rowsum partials.
// ---------------------------------------------------------------------------
__global__ __launch_bounds__(256) void adjmm_kernel(const float* __restrict__ adj,
                                                    const unsigned short* __restrict__ hT,
                                                    unsigned short* __restrict__ part,
                                                    float* __restrict__ part_s)
{
    __shared__ unsigned short sa[2][64 * 32];
    __shared__ unsigned short sb[2][128 * 32];
    const int tid  = threadIdx.x;
    const int lane = tid & 63, w = tid >> 6;
    const int m0   = blockIdx.x * 64;
    const int ks0  = blockIdx.y * KC;
    const int ks1  = min(ks0 + KC, KSTEPS);
    const int r0   = (w & 1) * 32;
    const int c0   = (w >> 1) * 64;

    const int arow = tid >> 2, agrp = tid & 3;
    const size_t abase = (size_t)min(m0 + arow, N_NODES - 1) * N_NODES;
    const int bcol = tid >> 1, bg0 = (tid & 1) * 2;

    const int asoff  = arow * 32 + ((agrp ^ (arow & 3)) << 3);
    const int bsoff0 = bcol * 32 + (((bg0 + 0) ^ (bcol & 3)) << 3);
    const int bsoff1 = bcol * 32 + (((bg0 + 1) ^ (bcol & 3)) << 3);

    float rs = 0.f;
    f32x4 acc[2][4];
    #pragma unroll
    for (int i = 0; i < 2; ++i)
        #pragma unroll
        for (int j = 0; j < 4; ++j) acc[i][j] = (f32x4){0.f, 0.f, 0.f, 0.f};

    float av8[8];
    bf16x8 vb0, vb1;
    auto load_step = [&](int ks) {            // loads only — no VALU use
        const int k0 = ks * 32;
        const int kg = k0 + agrp * 8;
        if (kg + 8 <= N_NODES) {
            float4 u0 = *(const float4*)(adj + abase + kg);
            float4 u1 = *(const float4*)(adj + abase + kg + 4);
            av8[0] = u0.x; av8[1] = u0.y; av8[2] = u0.z; av8[3] = u0.w;
            av8[4] = u1.x; av8[5] = u1.y; av8[6] = u1.z; av8[7] = u1.w;
        } else {
            #pragma unroll
            for (int i = 0; i < 8; ++i) av8[i] = 0.f;
        }
        vb0 = *(const bf16x8*)(hT + (size_t)bcol * KP + k0 + bg0 * 8);
        vb1 = *(const bf16x8*)(hT + (size_t)bcol * KP + k0 + (bg0 + 1) * 8);
    };
    auto write_step = [&](int p) {            // first use of loads: after MFMA
        #pragma unroll
        for (int i = 0; i < 8; ++i) rs += av8[i];
        *(bf16x8*)(sa[p] + asoff)  = cvt8(av8);
        *(bf16x8*)(sb[p] + bsoff0) = vb0;
        *(bf16x8*)(sb[p] + bsoff1) = vb1;
    };

    load_step(ks0);
    write_step(0);

    for (int ks = ks0; ks < ks1; ++ks) {
        const int p = (ks - ks0) & 1;
        const bool more = (ks + 1 < ks1);
        if (more) load_step(ks + 1);
        __syncthreads();
        bf16x8 av[2], bv[4];
        #pragma unroll
        for (int rb = 0; rb < 2; ++rb) {
            int row = r0 + rb * 16 + (lane & 15);
            int g   = lane >> 4;
            av[rb] = *(const bf16x8*)(sa[p] + row * 32 + ((g ^ (row & 3)) << 3));
        }
        #pragma unroll
        for (int cb = 0; cb < 4; ++cb) {
            int col = c0 + cb * 16 + (lane & 15);
            int g   = lane >> 4;
            bv[cb] = *(const bf16x8*)(sb[p] + col * 32 + ((g ^ (col & 3)) << 3));
        }
        #pragma unroll
        for (int rb = 0; rb < 2; ++rb)
            #pragma unroll
            for (int cb = 0; cb < 4; ++cb)
                acc[rb][cb] = __builtin_amdgcn_mfma_f32_16x16x32_bf16(av[rb], bv[cb],
                                                                      acc[rb][cb], 0, 0, 0);
        if (more) write_step(p ^ 1);
    }

    rs += __shfl_xor(rs, 1);
    rs += __shfl_xor(rs, 2);
    if ((tid & 3) == 0) part_s[(size_t)blockIdx.y * MPAD + m0 + arow] = rs;

    unsigned short* pout = part + (size_t)blockIdx.y * MPAD * NH;
    #pragma unroll
    for (int rb = 0; rb < 2; ++rb)
        #pragma unroll
        for (int cb = 0; cb < 4; ++cb) {
            int rowb = m0 + r0 + rb * 16 + (lane >> 4) * 4;
            int col  = c0 + cb * 16 + (lane & 15);
            #pragma unroll
            for (int reg = 0; reg < 4; ++reg)
                pout[(size_t)(rowb + reg) * NH + col] = f2bf(acc[rb][cb][reg]);
        }
}

// ---------------------------------------------------------------------------
// x @ W_in.T split-K (4 chunks of 16 K-steps), pipelined ping-pong.
// ---------------------------------------------------------------------------
__global__ __launch_bounds__(256) void xw_mfma_kernel(const float* __restrict__ x,
                                                      const float* __restrict__ Wn,
                                                      float* __restrict__ part)
{
    __shared__ unsigned short sa[2][64 * 32];
    __shared__ unsigned short sb[2][128 * 32];
    const int tid  = threadIdx.x;
    const int lane = tid & 63, w = tid >> 6;
    const int m0   = blockIdx.x * 64;
    const int TOT  = (NFEAT + 31) / 32;                 // 63
    const int s0   = blockIdx.y * 16;
    const int s1   = min(s0 + 16, TOT);
    const int r0   = (w & 1) * 32;
    const int c0   = (w >> 1) * 64;

    const int arow = tid >> 2, agrp = tid & 3;
    const size_t abase = (size_t)min(m0 + arow, N_NODES - 1) * NFEAT;
    const int asoff = arow * 32 + ((agrp ^ (arow & 3)) << 3);
    int bn_[2], bgrp_[2], bsoff_[2];
    #pragma unroll
    for (int t = 0; t < 2; ++t) {
        int gi = tid + t * 256;
        bn_[t] = gi >> 2; bgrp_[t] = gi & 3;
        bsoff_[t] = bn_[t] * 32 + ((bgrp_[t] ^ (bn_[t] & 3)) << 3);
    }

    f32x4 acc[2][4];
    #pragma unroll
    for (int i = 0; i < 2; ++i)
        #pragma unroll
        for (int j = 0; j < 4; ++j) acc[i][j] = (f32x4){0.f, 0.f, 0.f, 0.f};

    float av8[8], bv8[2][8];
    auto load_step = [&](int ks) {
        const int k0 = ks * 32;
        {
            const int kg = k0 + agrp * 8;
            if (kg + 8 <= NFEAT) {
                float4 u0 = *(const float4*)(x + abase + kg);
                float4 u1 = *(const float4*)(x + abase + kg + 4);
                av8[0]=u0.x; av8[1]=u0.y; av8[2]=u0.z; av8[3]=u0.w;
                av8[4]=u1.x; av8[5]=u1.y; av8[6]=u1.z; av8[7]=u1.w;
            } else {
                #pragma unroll
                for (int i = 0; i < 8; ++i) av8[i] = 0.f;
            }
        }
        #pragma unroll
        for (int t = 0; t < 2; ++t) {
            int kg = k0 + bgrp_[t] * 8;
            if (kg + 8 <= NFEAT) {
                float4 u0 = *(const float4*)(Wn + (size_t)bn_[t] * NFEAT + kg);
                float4 u1 = *(const float4*)(Wn + (size_t)bn_[t] * NFEAT + kg + 4);
                bv8[t][0]=u0.x; bv8[t][1]=u0.y; bv8[t][2]=u0.z; bv8[t][3]=u0.w;
                bv8[t][4]=u1.x; bv8[t][5]=u1.y; bv8[t][6]=u1.z; bv8[t][7]=u1.w;
            } else {
                #pragma unroll
                for (int i = 0; i < 8; ++i) bv8[t][i] = 0.f;
            }
        }
    };
    auto write_step = [&](int p) {
        *(bf16x8*)(sa[p] + asoff) = cvt8(av8);
        #pragma unroll
        for (int t = 0; t < 2; ++t)
            *(bf16x8*)(sb[p] + bsoff_[t]) = cvt8(bv8[t]);
    };

    load_step(s0);
    write_step(0);

    for (int ks = s0; ks < s1; ++ks) {
        const int p = (ks - s0) & 1;
        const bool more = (ks + 1 < s1);
        if (more) load_step(ks + 1);
        __syncthreads();
        bf16x8 av[2], bv[4];
        #pragma unroll
        for (int rb = 0; rb < 2; ++rb) {
            int row = r0 + rb * 16 + (lane & 15);
            int g   = lane >> 4;
            av[rb] = *(const bf16x8*)(sa[p] + row * 32 + ((g ^ (row & 3)) << 3));
        }
        #pragma unroll
        for (int cb = 0; cb < 4; ++cb) {
            int col = c0 + cb * 16 + (lane & 15);
            int g   = lane >> 4;
            bv[cb] = *(const bf16x8*)(sb[p] + col * 32 + ((g ^ (col & 3)) << 3));
        }
        #pragma unroll
        for (int rb = 0; rb < 2; ++rb)
            #pragma unroll
            for (int cb = 0; cb < 4; ++cb)
                acc[rb][cb] = __builtin_amdgcn_mfma_f32_16x16x32_bf16(av[rb], bv[cb],
                                                                      acc[rb][cb], 0, 0, 0);
        if (more) write_step(p ^ 1);
    }
    float* pout = part + (size_t)blockIdx.y * MPAD * NH;
    #pragma unroll
    for (int rb = 0; rb < 2; ++rb)
        #pragma unroll
        for (int cb = 0; cb < 4; ++cb) {
            int rowb = m0 + r0 + rb * 16 + (lane >> 4) * 4;
            int col  = c0 + cb * 16 + (lane & 15);
            #pragma unroll
            for (int reg = 0; reg < 4; ++reg)
                pout[(size_t)(rowb + reg) * NH + col] = acc[rb][cb][reg];
        }
}

// ---------------------------------------------------------------------------
// h_in = elu(bn_in(sum part + b_in)); also writes h_inT bf16 [128][KP] + pad
// ---------------------------------------------------------------------------
__global__ __launch_bounds__(256) void xw_reduce_kernel(const float* __restrict__ part,
                                                        const float* __restrict__ bias,
                                                        const float* __restrict__ g,
                                                        const float* __restrict__ bb,
                                                        const float* __restrict__ rm,
                                                        const float* __restrict__ rv,
                                                        float* __restrict__ h,
                                                        unsigned short* __restrict__ hT)
{
    __shared__ unsigned short tb[128][8];
    const int tid = threadIdx.x;
    int idx = blockIdx.x * 256 + tid;
    const int c4 = (tid & 31) * 4;
    const int lr = tid >> 5;                       // 0..7
    const int m0g = blockIdx.x * 8;
    const size_t ch = (size_t)MPAD * NH / 4;
    const float4* p = (const float4*)part;
    float a[4] = {0.f, 0.f, 0.f, 0.f};
    #pragma unroll
    for (int c = 0; c < NSPLX; ++c) {
        float4 v = p[c * ch + idx];
        a[0] += v.x; a[1] += v.y; a[2] += v.z; a[3] += v.w;
    }
    float o[4];
    #pragma unroll
    for (int j = 0; j < 4; ++j) {
        int c = c4 + j;
        float sc = g[c] / sqrtf(rv[c] + BN_EPS);
        float t = (a[j] + bias[c] - rm[c]) * sc + bb[c];
        o[j] = t > 0.f ? t : expm1f(t);
        tb[c][lr] = f2bf(o[j]);
    }
    float4 ov; ov.x = o[0]; ov.y = o[1]; ov.z = o[2]; ov.w = o[3];
    *(float4*)(h + (size_t)idx * 4) = ov;
    __syncthreads();
    if (tid < 128) {
        ushort4 v0, v1;
        v0.x = tb[tid][0]; v0.y = tb[tid][1]; v0.z = tb[tid][2]; v0.w = tb[tid][3];
        v1.x = tb[tid][4]; v1.y = tb[tid][5]; v1.z = tb[tid][6]; v1.w = tb[tid][7];
        *(ushort4*)(hT + (size_t)tid * KP + m0g)     = v0;
        *(ushort4*)(hT + (size_t)tid * KP + m0g + 4) = v1;
        if (blockIdx.x == 0) {                     // zero the K-pad [10000,10016)
            ushort4 zz; zz.x = zz.y = zz.z = zz.w = 0;
            #pragma unroll
            for (int q = 0; q < 4; ++q)
                *(ushort4*)(hT + (size_t)tid * KP + 10000 + q * 4) = zz;
        }
    }
}

// ---------------------------------------------------------------------------
// GraphSAGE fused (+nreduce): A = [h | (sum_c bf16 part)/rowsum];
// jk = rownorm(relu(A@Wg^T + bg)); opt. jkT bf16. BM=64, K=256, grid MT.
// ---------------------------------------------------------------------------
template<bool WRITE_T>
__global__ __launch_bounds__(256) void gs_fused_kernel(const float* __restrict__ h,
                                                       const unsigned short* __restrict__ part,
                                                       const float* __restrict__ part_s,
                                                       const unsigned short* __restrict__ Wg,
                                                       const float* __restrict__ bg,
                                                       float* __restrict__ jk,
                                                       unsigned short* __restrict__ jkT)
{
    __shared__ unsigned short sa[64 * 32];
    __shared__ unsigned short sb[128 * 32];
    __shared__ float ssq_l[64][2];
    __shared__ unsigned short tb[WRITE_T ? 128 * 64 : 1];
    const int tid  = threadIdx.x;
    const int lane = tid & 63, w = tid >> 6;
    const int m0   = blockIdx.x * 64;
    const int r0   = (w & 1) * 32;
    const int c0   = (w >> 1) * 64;
    const int arow = tid >> 2, agrp = tid & 3;
    const int mg   = min(m0 + arow, N_NODES - 1);

    float inv;
    {
        float s = 0.f;
        #pragma unroll
        for (int c = 0; c < NSPLIT; ++c) s += part_s[(size_t)c * MPAD + mg];
        inv = 1.0f / s;
    }

    f32x4 acc[2][4];
    #pragma unroll
    for (int i = 0; i < 2; ++i)
        #pragma unroll
        for (int j = 0; j < 4; ++j) acc[i][j] = (f32x4){0.f, 0.f, 0.f, 0.f};

    for (int k0 = 0; k0 < 256; k0 += 32) {
        const int kg = k0 + agrp * 8;
        float a8[8];
        if (kg < 128) {
            const float* asrc = h + (size_t)mg * NH + kg;
            float4 u0 = *(const float4*)asrc;
            float4 u1 = *(const float4*)(asrc + 4);
            a8[0]=u0.x; a8[1]=u0.y; a8[2]=u0.z; a8[3]=u0.w;
            a8[4]=u1.x; a8[5]=u1.y; a8[6]=u1.z; a8[7]=u1.w;
        } else {
            const int cc = kg - 128;
            float s[8] = {0.f,0.f,0.f,0.f,0.f,0.f,0.f,0.f};
            #pragma unroll
            for (int c = 0; c < NSPLIT; ++c) {
                bf16x8 v = *(const bf16x8*)(part + (size_t)c * MPAD * NH + (size_t)mg * NH + cc);
                #pragma unroll
                for (int i = 0; i < 8; ++i) s[i] += bf2f((unsigned short)v[i]);
            }
            #pragma unroll
            for (int i = 0; i < 8; ++i) a8[i] = s[i] * inv;
        }
        bf16x8 b8[2];
        #pragma unroll
        for (int t = 0; t < 2; ++t) {
            int gi = tid + t * 256;
            int n = gi >> 2, grp = gi & 3;
            b8[t] = *(const bf16x8*)(Wg + (size_t)n * 256 + k0 + grp * 8);
        }
        __syncthreads();
        *(bf16x8*)(sa + arow * 32 + ((agrp ^ (arow & 3)) << 3)) = cvt8(a8);
        #pragma unroll
        for (int t = 0; t < 2; ++t) {
            int gi = tid + t * 256;
            int n = gi >> 2, grp = gi & 3;
            *(bf16x8*)(sb + n * 32 + ((grp ^ (n & 3)) << 3)) = b8[t];
        }
        __syncthreads();
        bf16x8 av[2], bv[4];
        #pragma unroll
        for (int rb = 0; rb < 2; ++rb) {
            int row = r0 + rb * 16 + (lane & 15);
            int g   = lane >> 4;
            av[rb] = *(const bf16x8*)(sa + row * 32 + ((g ^ (row & 3)) << 3));
        }
        #pragma unroll
        for (int cb = 0; cb < 4; ++cb) {
            int col = c0 + cb * 16 + (lane & 15);
            int g   = lane >> 4;
            bv[cb] = *(const bf16x8*)(sb + col * 32 + ((g ^ (col & 3)) << 3));
        }
        #pragma unroll
        for (int rb = 0; rb < 2; ++rb)
            #pragma unroll
            for (int cb = 0; cb < 4; ++cb)
                acc[rb][cb] = __builtin_amdgcn_mfma_f32_16x16x32_bf16(av[rb], bv[cb],
                                                                      acc[rb][cb], 0, 0, 0);
    }

    float vv[2][4][4];
    float ps[2][4] = {};
    #pragma unroll
    for (int rb = 0; rb < 2; ++rb)
        #pragma unroll
        for (int cb = 0; cb < 4; ++cb) {
            int colg = c0 + cb * 16 + (lane & 15);
            float b = bg[colg];
            #pragma unroll
            for (int reg = 0; reg < 4; ++reg) {
                float t = fmaxf(acc[rb][cb][reg] + b, 0.f);
                vv[rb][cb][reg] = t;
                ps[rb][reg] += t * t;
            }
        }
    #pragma unroll
    for (int msk = 1; msk < 16; msk <<= 1)
        #pragma unroll
        for (int rb = 0; rb < 2; ++rb)
            #pragma unroll
            for (int reg = 0; reg < 4; ++reg)
                ps[rb][reg] += __shfl_xor(ps[rb][reg], msk);
    if ((lane & 15) == 0) {
        #pragma unroll
        for (int rb = 0; rb < 2; ++rb)
            #pragma unroll
            for (int reg = 0; reg < 4; ++reg)
                ssq_l[r0 + rb * 16 + (lane >> 4) * 4 + reg][w >> 1] = ps[rb][reg];
    }
    __syncthreads();
    #pragma unroll
    for (int rb = 0; rb < 2; ++rb)
        #pragma unroll
        for (int reg = 0; reg < 4; ++reg) {
            int lr = r0 + rb * 16 + (lane >> 4) * 4 + reg;
            float s = ssq_l[lr][0] + ssq_l[lr][1];
            float sc = 1.0f / fmaxf(sqrtf(s), 1e-12f);
            int m = m0 + lr;
            #pragma unroll
            for (int cb = 0; cb < 4; ++cb) {
                int colg = c0 + cb * 16 + (lane & 15);
                float o = vv[rb][cb][reg] * sc;
                if (m < N_NODES) jk[(size_t)m * NH + colg] = o;
                if constexpr (WRITE_T) tb[colg * 64 + lr] = f2bf(o);
            }
        }
    if constexpr (WRITE_T) {
        __syncthreads();
        #pragma unroll
        for (int p = 0; p < 4; ++p) {
            int flat = (tid + p * 256) * 8;
            int c = flat >> 6, mo = flat & 63;
            int kglob = m0 + mo;
            if (kglob < KP) {
                unsigned short tmp[8];
                #pragma unroll
                for (int i = 0; i < 8; ++i)
                    tmp[i] = (kglob + i < N_NODES) ? tb[c * 64 + mo + i] : (unsigned short)0;
                ushort4 v0, v1;
                v0.x = tmp[0]; v0.y = tmp[1]; v0.z = tmp[2]; v0.w = tmp[3];
                v1.x = tmp[4]; v1.y = tmp[5]; v1.z = tmp[6]; v1.w = tmp[7];
                *(ushort4*)(jkT + (size_t)c * KP + kglob)     = v0;
                *(ushort4*)(jkT + (size_t)c * KP + kglob + 4) = v1;
            }
        }
    }
}

// ---------------------------------------------------------------------------
// Full LSTM JK chain in one kernel: 4 steps, h-states in LDS, c in registers.
// BM=32 rows/block, grid 313. Final step fuses JK-mean + bn_in + ELU -> hpost.
// ---------------------------------------------------------------------------
__global__ __launch_bounds__(256) void lstm4_kernel(
    const float* __restrict__ jk0, const float* __restrict__ jk1,
    const unsigned short* __restrict__ wl,   // [2][512][256] bf16
    const float* __restrict__ bih0, const float* __restrict__ bhh0,
    const float* __restrict__ bih1, const float* __restrict__ bhh1,
    const float* __restrict__ bng, const float* __restrict__ bnb,
    const float* __restrict__ bnrm, const float* __restrict__ bnrv,
    float* __restrict__ hpost)
{
    __shared__ unsigned short sa[32 * 32];
    __shared__ unsigned short sb[512 * 32];
    __shared__ unsigned short hb[2][32][136];   // +8 pad: 2-way banks on direct read
    const int tid = threadIdx.x, lane = tid & 63, w = tid >> 6;
    const int m0 = blockIdx.x * 32;
    const int arow = tid >> 2, agrp = tid & 3;  // A staging (tid<128)
    const int mg = min(m0 + arow, N_NODES - 1);

    f32x4 acc[2][8];
    float cst[2][2][4];

    auto zacc = [&] {
        #pragma unroll
        for (int i = 0; i < 2; ++i)
            #pragma unroll
            for (int j = 0; j < 8; ++j) acc[i][j] = (f32x4){0.f, 0.f, 0.f, 0.f};
    };
    auto stage_sb = [&](const unsigned short* wlayer, int k0) {
        #pragma unroll
        for (int t = 0; t < 8; ++t) {
            int gi = tid + t * 256, n = gi >> 2, grp = gi & 3;
            *(bf16x8*)(sb + n * 32 + ((grp ^ (n & 3)) << 3)) =
                *(const bf16x8*)(wlayer + (size_t)n * 256 + k0 + grp * 8);
        }
    };
    auto stage_sa = [&](const float* a, int k0) {
        if (tid < 128) {
            int kg = k0 + agrp * 8;
            const float* src = a + (size_t)mg * NH + kg;
            float4 u0 = *(const float4*)src, u1 = *(const float4*)(src + 4);
            float a8[8] = {u0.x, u0.y, u0.z, u0.w, u1.x, u1.y, u1.z, u1.w};
            *(bf16x8*)(sa + arow * 32 + ((agrp ^ (arow & 3)) << 3)) = cvt8(a8);
        }
    };
    auto av_sa = [&](int rb) {
        int row = rb * 16 + (lane & 15), g = lane >> 4;
        return *(const bf16x8*)(sa + row * 32 + ((g ^ (row & 3)) << 3));
    };
    auto av_hb = [&](int i, int rb, int kl) {
        int row = rb * 16 + (lane & 15), g = lane >> 4;
        return *(const bf16x8*)(&hb[i][row][kl + g * 8]);
    };
    auto mfma_all = [&](bf16x8 a0, bf16x8 a1) {
        #pragma unroll
        for (int gate = 0; gate < 4; ++gate)
            #pragma unroll
            for (int cb = 0; cb < 2; ++cb) {
                int col = gate * 128 + w * 32 + cb * 16 + (lane & 15);
                int g = lane >> 4;
                bf16x8 bv = *(const bf16x8*)(sb + col * 32 + ((g ^ (col & 3)) << 3));
                acc[0][gate * 2 + cb] =
                    __builtin_amdgcn_mfma_f32_16x16x32_bf16(a0, bv, acc[0][gate * 2 + cb], 0, 0, 0);
                acc[1][gate * 2 + cb] =
                    __builtin_amdgcn_mfma_f32_16x16x32_bf16(a1, bv, acc[1][gate * 2 + cb], 0, 0, 0);
            }
    };
    auto epi = [&](const float* bih, const float* bhh, bool hasc, int hdst, bool fin) {
        __syncthreads();    // all hb reads of this step done before overwrite
        #pragma unroll
        for (int cb = 0; cb < 2; ++cb) {
            int cg = w * 32 + cb * 16 + (lane & 15);
            float bi  = bih[cg]       + bhh[cg];
            float bf_ = bih[128 + cg] + bhh[128 + cg];
            float bgg = bih[256 + cg] + bhh[256 + cg];
            float bo  = bih[384 + cg] + bhh[384 + cg];
            float sc = 0.f, sh = 0.f;
            if (fin) {
                sc = bng[cg] / sqrtf(bnrv[cg] + BN_EPS);
                sh = bnb[cg] - bnrm[cg] * sc;
            }
            #pragma unroll
            for (int rb = 0; rb < 2; ++rb)
                #pragma unroll
                for (int reg = 0; reg < 4; ++reg) {
                    int lr = rb * 16 + (lane >> 4) * 4 + reg;
                    float zi = acc[rb][0 + cb][reg] + bi;
                    float zf = acc[rb][2 + cb][reg] + bf_;
                    float zg = acc[rb][4 + cb][reg] + bgg;
                    float zo = acc[rb][6 + cb][reg] + bo;
                    float cn = sigm(zi) * tanhf(zg);
                    if (hasc) cn += sigm(zf) * cst[rb][cb][reg];
                    cst[rb][cb][reg] = cn;
                    float hv = sigm(zo) * tanhf(cn);
                    if (fin) {
                        float hm = bf2f(hb[0][lr][cg]);     // h2_0
                        float t = 0.5f * (hm + hv);
                        t = t * sc + sh;
                        int m = m0 + lr;
                        if (m < N_NODES) hpost[(size_t)m * NH + cg] = t > 0.f ? t : expm1f(t);
                    } else {
                        hb[hdst][lr][cg] = f2bf(hv);
                    }
                }
        }
        __syncthreads();
    };

    // step0: L1 t0, A = jk0, K=128
    zacc();
    for (int k0 = 0; k0 < 128; k0 += 32) {
        __syncthreads();
        stage_sa(jk0, k0);
        stage_sb(wl, k0);
        __syncthreads();
        mfma_all(av_sa(0), av_sa(1));
    }
    epi(bih0, bhh0, false, 0, false);           // h1_0 -> hb0

    // step1: L1 t1, A = [jk1 | hb0], K=256
    zacc();
    for (int k0 = 0; k0 < 256; k0 += 32) {
        __syncthreads();
        if (k0 < 128) stage_sa(jk1, k0);
        stage_sb(wl, k0);
        __syncthreads();
        if (k0 < 128) mfma_all(av_sa(0), av_sa(1));
        else          mfma_all(av_hb(0, 0, k0 - 128), av_hb(0, 1, k0 - 128));
    }
    epi(bih0, bhh0, true, 1, false);            // h1_1 -> hb1

    // step2: L2 t0, A = hb0 (h1_0), K=128
    const unsigned short* wl1 = wl + 512 * 256;
    zacc();
    for (int k0 = 0; k0 < 128; k0 += 32) {
        __syncthreads();
        stage_sb(wl1, k0);
        __syncthreads();
        mfma_all(av_hb(0, 0, k0), av_hb(0, 1, k0));
    }
    epi(bih1, bhh1, false, 0, false);           // h2_0 -> hb0

    // step3: L2 t1, A = [hb1 | hb0] = [h1_1 | h2_0], K=256, FINAL
    zacc();
    for (int k0 = 0; k0 < 256; k0 += 32) {
        __syncthreads();
        stage_sb(wl1, k0);
        __syncthreads();
        if (k0 < 128) mfma_all(av_hb(1, 0, k0), av_hb(1, 1, k0));
        else          mfma_all(av_hb(0, 0, k0 - 128), av_hb(0, 1, k0 - 128));
    }
    epi(bih1, bhh1, true, -1, true);            // hpost out
}

// ---------------------------------------------------------------------------
// Epilogue: e=elu(bn(embed@W_emb^T)) -> LDS; hfc=elu(bn([hpost|e]@W_fc^T))
// -> LDS; out = log_softmax(hfc@W_out^T + b). BM=64, grid MT.
// ---------------------------------------------------------------------------
__global__ __launch_bounds__(256) void epilogue_kernel(
    const float* __restrict__ embed,
    const float* __restrict__ W_emb, const float* __restrict__ b_emb,
    const float* __restrict__ bn_e_g, const float* __restrict__ bn_e_b,
    const float* __restrict__ bn_e_rm, const float* __restrict__ bn_e_rv,
    const float* __restrict__ hpost,
    const float* __restrict__ W_fc, const float* __restrict__ b_fc,
    const float* __restrict__ bn_f_g, const float* __restrict__ bn_f_b,
    const float* __restrict__ bn_f_rm, const float* __restrict__ bn_f_rv,
    const float* __restrict__ W_out, const float* __restrict__ b_out,
    float* __restrict__ out)
{
    __shared__ unsigned short sa[64 * 32];
    __shared__ unsigned short sb[192 * 32];
    __shared__ unsigned short ebuf[64][72];
    __shared__ float fbuf[64][204];
    const int tid = threadIdx.x, lane = tid & 63, w = tid >> 6;
    const int m0 = blockIdx.x * 64;
    const int arow = tid >> 2, agrp = tid & 3;
    const int mg = min(m0 + arow, N_NODES - 1);
    const int g = lane >> 4;

    // ---- phase E ----
    f32x4 aE[4];
    #pragma unroll
    for (int j = 0; j < 4; ++j) aE[j] = (f32x4){0.f, 0.f, 0.f, 0.f};
    for (int k0 = 0; k0 < NFE; k0 += 32) {
        float a8[8], b8[8];
        {
            const float* s = embed + (size_t)mg * NFE + k0 + agrp * 8;
            float4 u0 = *(const float4*)s, u1 = *(const float4*)(s + 4);
            a8[0]=u0.x; a8[1]=u0.y; a8[2]=u0.z; a8[3]=u0.w;
            a8[4]=u1.x; a8[5]=u1.y; a8[6]=u1.z; a8[7]=u1.w;
        }
        {
            const float* s = W_emb + (size_t)arow * NFE + k0 + agrp * 8;  // arow<64=NHE
            float4 u0 = *(const float4*)s, u1 = *(const float4*)(s + 4);
            b8[0]=u0.x; b8[1]=u0.y; b8[2]=u0.z; b8[3]=u0.w;
            b8[4]=u1.x; b8[5]=u1.y; b8[6]=u1.z; b8[7]=u1.w;
        }
        __syncthreads();
        *(bf16x8*)(sa + arow * 32 + ((agrp ^ (arow & 3)) << 3)) = cvt8(a8);
        *(bf16x8*)(sb + arow * 32 + ((agrp ^ (arow & 3)) << 3)) = cvt8(b8);
        __syncthreads();
        bf16x8 av;
        { int row = w * 16 + (lane & 15);
          av = *(const bf16x8*)(sa + row * 32 + ((g ^ (row & 3)) << 3)); }
        #pragma unroll
        for (int cb = 0; cb < 4; ++cb) {
            int col = cb * 16 + (lane & 15);
            bf16x8 bv = *(const bf16x8*)(sb + col * 32 + ((g ^ (col & 3)) << 3));
            aE[cb] = __builtin_amdgcn_mfma_f32_16x16x32_bf16(av, bv, aE[cb], 0, 0, 0);
        }
    }
    #pragma unroll
    for (int cb = 0; cb < 4; ++cb) {
        int col = cb * 16 + (lane & 15);
        float sc = bn_e_g[col] / sqrtf(bn_e_rv[col] + BN_EPS);
        float sh = bn_e_b[col] - bn_e_rm[col] * sc;
        float bb = b_emb[col];
        #pragma unroll
        for (int reg = 0; reg < 4; ++reg) {
            int row = w * 16 + (lane >> 4) * 4 + reg;
            float t = (aE[cb][reg] + bb) * sc + sh;
            ebuf[row][col] = f2bf(t > 0.f ? t : expm1f(t));
        }
    }
    __syncthreads();

    // ---- phase F ----
    f32x4 aF[4][3];
    #pragma unroll
    for (int i = 0; i < 4; ++i)
        #pragma unroll
        for (int j = 0; j < 3; ++j) aF[i][j] = (f32x4){0.f, 0.f, 0.f, 0.f};
    for (int k0 = 0; k0 < DCAT; k0 += 32) {
        const bool gl = (k0 < 128);
        float b8[3][8];
        #pragma unroll
        for (int t = 0; t < 3; ++t) {
            int gi = tid + t * 256, n = gi >> 2, grp = gi & 3;
            const float* s = W_fc + (size_t)n * DCAT + k0 + grp * 8;
            float4 u0 = *(const float4*)s, u1 = *(const float4*)(s + 4);
            b8[t][0]=u0.x; b8[t][1]=u0.y; b8[t][2]=u0.z; b8[t][3]=u0.w;
            b8[t][4]=u1.x; b8[t][5]=u1.y; b8[t][6]=u1.z; b8[t][7]=u1.w;
        }
        float a8[8];
        if (gl) {
            const float* s = hpost + (size_t)mg * NH + k0 + agrp * 8;
            float4 u0 = *(const float4*)s, u1 = *(const float4*)(s + 4);
            a8[0]=u0.x; a8[1]=u0.y; a8[2]=u0.z; a8[3]=u0.w;
            a8[4]=u1.x; a8[5]=u1.y; a8[6]=u1.z; a8[7]=u1.w;
        }
        __syncthreads();
        if (gl) *(bf16x8*)(sa + arow * 32 + ((agrp ^ (arow & 3)) << 3)) = cvt8(a8);
        #pragma unroll
        for (int t = 0; t < 3; ++t) {
            int gi = tid + t * 256, n = gi >> 2, grp = gi & 3;
            *(bf16x8*)(sb + n * 32 + ((grp ^ (n & 3)) << 3)) = cvt8(b8[t]);
        }
        __syncthreads();
        #pragma unroll
        for (int rf = 0; rf < 4; ++rf) {
            int row = rf * 16 + (lane & 15);
            bf16x8 av = gl ? *(const bf16x8*)(sa + row * 32 + ((g ^ (row & 3)) << 3))
                           : *(const bf16x8*)(&ebuf[row][(k0 - 128) + g * 8]);
            #pragma unroll
            for (int cf = 0; cf < 3; ++cf) {
                int col = w * 48 + cf * 16 + (lane & 15);
                bf16x8 bv = *(const bf16x8*)(sb + col * 32 + ((g ^ (col & 3)) << 3));
                aF[rf][cf] = __builtin_amdgcn_mfma_f32_16x16x32_bf16(av, bv, aF[rf][cf], 0, 0, 0);
            }
        }
    }
    #pragma unroll
    for (int cf = 0; cf < 3; ++cf) {
        int col = w * 48 + cf * 16 + (lane & 15);
        float sc = bn_f_g[col] / sqrtf(bn_f_rv[col] + BN_EPS);
        float sh = bn_f_b[col] - bn_f_rm[col] * sc;
        float bb = b_fc[col];
        #pragma unroll
        for (int rf = 0; rf < 4; ++rf)
            #pragma unroll
            for (int reg = 0; reg < 4; ++reg) {
                int row = rf * 16 + (lane >> 4) * 4 + reg;
                float t = (aF[rf][cf][reg] + bb) * sc + sh;
                fbuf[row][col] = t > 0.f ? t : expm1f(t);
            }
    }
    __syncthreads();

    // ---- phase O ----
    f32x4 aO[2];
    aO[0] = (f32x4){0.f, 0.f, 0.f, 0.f};
    aO[1] = (f32x4){0.f, 0.f, 0.f, 0.f};
    for (int k0 = 0; k0 < DCAT; k0 += 32) {
        float b8[8];
        const bool act = tid < 128;                       // 32 out-cols x 4 granules
        if (act) {
            if (arow < NOUT) {
                const float* s = W_out + (size_t)arow * DCAT + k0 + agrp * 8;
                float4 u0 = *(const float4*)s, u1 = *(const float4*)(s + 4);
                b8[0]=u0.x; b8[1]=u0.y; b8[2]=u0.z; b8[3]=u0.w;
                b8[4]=u1.x; b8[5]=u1.y; b8[6]=u1.z; b8[7]=u1.w;
            } else {
                #pragma unroll
                for (int i = 0; i < 8; ++i) b8[i] = 0.f;
            }
        }
        __syncthreads();
        if (act) *(bf16x8*)(sb + arow * 32 + ((agrp ^ (arow & 3)) << 3)) = cvt8(b8);
        __syncthreads();
        int row = w * 16 + (lane & 15);
        float4 f0 = *(const float4*)(&fbuf[row][k0 + g * 8]);
        float4 f1 = *(const float4*)(&fbuf[row][k0 + g * 8 + 4]);
        float f8[8] = {f0.x, f0.y, f0.z, f0.w, f1.x, f1.y, f1.z, f1.w};
        bf16x8 av = cvt8(f8);
        #pragma unroll
        for (int cf = 0; cf < 2; ++cf) {
            int col = cf * 16 + (lane & 15);
            bf16x8 bv = *(const bf16x8*)(sb + col * 32 + ((g ^ (col & 3)) << 3));
            aO[cf] = __builtin_amdgcn_mfma_f32_16x16x32_bf16(av, bv, aO[cf], 0, 0, 0);
        }
    }
    const int c0i = lane & 15, c1i = 16 + (lane & 15);
    const bool v1 = c1i < NOUT;
    #pragma unroll
    for (int reg = 0; reg < 4; ++reg) {
        int row = w * 16 + (lane >> 4) * 4 + reg;
        int m = m0 + row;
        float l0 = aO[0][reg] + b_out[c0i];
        float l1 = v1 ? (aO[1][reg] + b_out[c1i]) : -INFINITY;
        float mx = fmaxf(l0, l1);
        #pragma unroll
        for (int msk = 1; msk < 16; msk <<= 1) mx = fmaxf(mx, __shfl_xor(mx, msk));
        float s = expf(l0 - mx) + (v1 ? expf(l1 - mx) : 0.f);
        #pragma unroll
        for (int msk = 1; msk < 16; msk <<= 1) s += __shfl_xor(s, msk);
        float lse = mx + logf(s);
        if (m < N_NODES) {
            out[(size_t)m * NOUT + c0i] = l0 - lse;
            if (v1) out[(size_t)m * NOUT + c1i] = l1 - lse;
        }
    }
}

// ---------------------------------------------------------------------------
extern "C" void kernel_launch(void* const* d_in, const int* in_sizes, int n_in,
                              void* d_out, int out_size, void* d_ws, size_t ws_size,
                              hipStream_t stream)
{
    const float* x       = (const float*)d_in[0];
    const float* embed   = (const float*)d_in[1];
    const float* adj     = (const float*)d_in[2];
    const float* W_in    = (const float*)d_in[3];
    const float* b_in    = (const float*)d_in[4];
    const float* bn_in_g = (const float*)d_in[5];
    const float* bn_in_b = (const float*)d_in[6];
    const float* bn_in_rm= (const float*)d_in[7];
    const float* bn_in_rv= (const float*)d_in[8];
    const float* W_gs    = (const float*)d_in[9];
    const float* b_gs    = (const float*)d_in[10];
    const float* Wih0    = (const float*)d_in[11];
    const float* Whh0    = (const float*)d_in[12];
    const float* bih0    = (const float*)d_in[13];
    const float* bhh0    = (const float*)d_in[14];
    const float* Wih1    = (const float*)d_in[15];
    const float* Whh1    = (const float*)d_in[16];
    const float* bih1    = (const float*)d_in[17];
    const float* bhh1    = (const float*)d_in[18];
    const float* W_emb   = (const float*)d_in[19];
    const float* b_emb   = (const float*)d_in[20];
    const float* bn_e_g  = (const float*)d_in[21];
    const float* bn_e_b  = (const float*)d_in[22];
    const float* bn_e_rm = (const float*)d_in[23];
    const float* bn_e_rv = (const float*)d_in[24];
    const float* W_fc    = (const float*)d_in[25];
    const float* b_fc    = (const float*)d_in[26];
    const float* bn_f_g  = (const float*)d_in[27];
    const float* bn_f_b  = (const float*)d_in[28];
    const float* bn_f_rm = (const float*)d_in[29];
    const float* bn_f_rv = (const float*)d_in[30];
    const float* W_out   = (const float*)d_in[31];
    const float* b_out   = (const float*)d_in[32];
    float* outp = (float*)d_out;

    const size_t HB = (size_t)N_NODES * NH * sizeof(float);
    char* wp = (char*)d_ws;
    auto carve = [&](size_t bytes) {
        void* p = (void*)wp;
        wp += (bytes + 1023) & ~(size_t)1023;
        return p;
    };
    void* partRaw = carve((size_t)NSPLIT * MPAD * NH * 2);     // 41.2 MB (bf16 view)
    unsigned short* partB = (unsigned short*)partRaw;
    float* partF = (float*)partRaw;                             // xw f32 view (4 chunks fit)
    float* part_s= (float*)carve((size_t)NSPLIT * MPAD * sizeof(float));
    float* h_in  = (float*)carve(HB);
    float* jk0   = (float*)carve(HB);
    float* jk1   = (float*)carve(HB);
    float* hpost = (float*)carve(HB);
    unsigned short* hT  = (unsigned short*)carve((size_t)NH * KP * 2);
    unsigned short* wl  = (unsigned short*)carve((size_t)2 * 512 * 256 * 2);
    unsigned short* wgb = (unsigned short*)carve((size_t)2 * 128 * 256 * 2);
    if ((size_t)(wp - (char*)d_ws) > ws_size) return;

    const dim3 blk(256);

    // 0. pack weights to bf16
    wconv_kernel<<<320, blk, 0, stream>>>(Wih0, Whh0, Wih1, Whh1, W_gs, wl, wgb);

    // 1. h_in = elu(bn_in(x @ W_in.T + b_in)); also h_inT (bf16, padded)
    xw_mfma_kernel<<<dim3(MT, NSPLX), blk, 0, stream>>>(x, W_in, partF);
    xw_reduce_kernel<<<1250, blk, 0, stream>>>(partF, b_in, bn_in_g, bn_in_b,
                                               bn_in_rm, bn_in_rv, h_in, hT);

    // 2. GraphSAGE layer 0
    adjmm_kernel<<<dim3(MT, NSPLIT), blk, 0, stream>>>(adj, hT, partB, part_s);
    gs_fused_kernel<true><<<MT, blk, 0, stream>>>(h_in, partB, part_s, wgb, b_gs, jk0, hT);

    // 3. GraphSAGE layer 1
    adjmm_kernel<<<dim3(MT, NSPLIT), blk, 0, stream>>>(adj, hT, partB, part_s);
    gs_fused_kernel<false><<<MT, blk, 0, stream>>>(jk0, partB, part_s, wgb + 128 * 256,
                                                   b_gs + 128, jk1, nullptr);

    // 4. LSTM JK chain (4 steps in one kernel) + JK-mean + bn + elu
    lstm4_kernel<<<313, blk, 0, stream>>>(jk0, jk1, wl, bih0, bhh0, bih1, bhh1,
                                          bn_in_g, bn_in_b, bn_in_rm, bn_in_rv, hpost);

    // 5. emb + fc + log_softmax fused epilogue
    epilogue_kernel<<<MT, blk, 0, stream>>>(embed, W_emb, b_emb,
                                            bn_e_g, bn_e_b, bn_e_rm, bn_e_rv,
                                            hpost, W_fc, b_fc,
                                            bn_f_g, bn_f_b, bn_f_rm, bn_f_rv,
                                            W_out, b_out, outp);
}

// Round 8
// 447.626 us; speedup vs baseline: 4.8161x; 1.0621x over previous
//
#include <hip/hip_runtime.h>
#include <hip/hip_bf16.h>
#include <math.h>

#define N_NODES 10000
#define NFEAT   2000
#define NFE     256
#define NH      128
#define NHE     64
#define NOUT    20
#define DCAT    192
#define BN_EPS  1e-5f

#define KP      10016        // padded K for transposed activations
#define KSTEPS  313
#define MT      157          // 64-row m-tiles
#define NSPLIT  16           // adjmm split-K
#define KC      20
#define NSPLX   4            // xw split-K
#define MPAD    10048

typedef __attribute__((ext_vector_type(8))) short  bf16x8;
typedef __attribute__((ext_vector_type(4))) float  f32x4;

__device__ __forceinline__ float sigm(float x) { return 1.0f / (1.0f + expf(-x)); }

__device__ __forceinline__ unsigned short f2bf(float x) {
    union { __hip_bfloat16 h; unsigned short u; } c;
    c.h = __float2bfloat16(x);
    return c.u;
}

__device__ __forceinline__ float bf2f(unsigned short u) {
    union { float f; unsigned int i; } c;
    c.i = ((unsigned int)u) << 16;
    return c.f;
}

__device__ __forceinline__ bf16x8 cvt8(const float* v) {
    bf16x8 r;
    #pragma unroll
    for (int i = 0; i < 8; ++i) r[i] = (short)f2bf(v[i]);
    return r;
}

// ---------------------------------------------------------------------------
// adjmm split-K, ping-pong LDS, loads fully overlapped.
// part[chunk] (bf16) = adj @ hT^T ; part_s rowsum partials.
// REV=1 reverses block->tile mapping so pass 2 starts on the L3-resident
// tail of adj left by pass 1 (LRU streaming reuse).
// Coalesced part store via LDS bounce (reuses sb after the K-loop).
// ---------------------------------------------------------------------------
template<int REV>
__global__ __launch_bounds__(256) void adjmm_kernel(const float* __restrict__ adj,
                                                    const unsigned short* __restrict__ hT,
                                                    unsigned short* __restrict__ part,
                                                    float* __restrict__ part_s)
{
    __shared__ unsigned short sa[2][64 * 32];
    __shared__ unsigned short sb[2][128 * 32];
    const int tid  = threadIdx.x;
    const int lane = tid & 63, w = tid >> 6;
    const int bx   = REV ? (int)gridDim.x - 1 - (int)blockIdx.x : (int)blockIdx.x;
    const int by   = REV ? (int)gridDim.y - 1 - (int)blockIdx.y : (int)blockIdx.y;
    const int m0   = bx * 64;
    const int ks0  = by * KC;
    const int ks1  = min(ks0 + KC, KSTEPS);
    const int r0   = (w & 1) * 32;
    const int c0   = (w >> 1) * 64;

    const int arow = tid >> 2, agrp = tid & 3;
    const size_t abase = (size_t)min(m0 + arow, N_NODES - 1) * N_NODES;
    const int bcol = tid >> 1, bg0 = (tid & 1) * 2;

    const int asoff  = arow * 32 + ((agrp ^ (arow & 3)) << 3);
    const int bsoff0 = bcol * 32 + (((bg0 + 0) ^ (bcol & 3)) << 3);
    const int bsoff1 = bcol * 32 + (((bg0 + 1) ^ (bcol & 3)) << 3);

    float rs = 0.f;
    f32x4 acc[2][4];
    #pragma unroll
    for (int i = 0; i < 2; ++i)
        #pragma unroll
        for (int j = 0; j < 4; ++j) acc[i][j] = (f32x4){0.f, 0.f, 0.f, 0.f};

    float av8[8];
    bf16x8 vb0, vb1;
    auto load_step = [&](int ks) {            // loads only — no VALU use
        const int k0 = ks * 32;
        const int kg = k0 + agrp * 8;
        if (kg + 8 <= N_NODES) {
            float4 u0 = *(const float4*)(adj + abase + kg);
            float4 u1 = *(const float4*)(adj + abase + kg + 4);
            av8[0] = u0.x; av8[1] = u0.y; av8[2] = u0.z; av8[3] = u0.w;
            av8[4] = u1.x; av8[5] = u1.y; av8[6] = u1.z; av8[7] = u1.w;
        } else {
            #pragma unroll
            for (int i = 0; i < 8; ++i) av8[i] = 0.f;
        }
        vb0 = *(const bf16x8*)(hT + (size_t)bcol * KP + k0 + bg0 * 8);
        vb1 = *(const bf16x8*)(hT + (size_t)bcol * KP + k0 + (bg0 + 1) * 8);
    };
    auto write_step = [&](int p) {            // first use of loads: after MFMA
        #pragma unroll
        for (int i = 0; i < 8; ++i) rs += av8[i];
        *(bf16x8*)(sa[p] + asoff)  = cvt8(av8);
        *(bf16x8*)(sb[p] + bsoff0) = vb0;
        *(bf16x8*)(sb[p] + bsoff1) = vb1;
    };

    load_step(ks0);
    write_step(0);

    for (int ks = ks0; ks < ks1; ++ks) {
        const int p = (ks - ks0) & 1;
        const bool more = (ks + 1 < ks1);
        if (more) load_step(ks + 1);
        __syncthreads();
        bf16x8 av[2], bv[4];
        #pragma unroll
        for (int rb = 0; rb < 2; ++rb) {
            int row = r0 + rb * 16 + (lane & 15);
            int g   = lane >> 4;
            av[rb] = *(const bf16x8*)(sa[p] + row * 32 + ((g ^ (row & 3)) << 3));
        }
        #pragma unroll
        for (int cb = 0; cb < 4; ++cb) {
            int col = c0 + cb * 16 + (lane & 15);
            int g   = lane >> 4;
            bv[cb] = *(const bf16x8*)(sb[p] + col * 32 + ((g ^ (col & 3)) << 3));
        }
        #pragma unroll
        for (int rb = 0; rb < 2; ++rb)
            #pragma unroll
            for (int cb = 0; cb < 4; ++cb)
                acc[rb][cb] = __builtin_amdgcn_mfma_f32_16x16x32_bf16(av[rb], bv[cb],
                                                                      acc[rb][cb], 0, 0, 0);
        if (more) write_step(p ^ 1);
    }

    rs += __shfl_xor(rs, 1);
    rs += __shfl_xor(rs, 2);
    if ((tid & 3) == 0) part_s[(size_t)by * MPAD + m0 + arow] = rs;

    // coalesced part store: acc -> LDS bounce (reuse sb: 2*128*32 = 64x128) -> 16B stores
    unsigned short* bounce = (unsigned short*)sb;
    __syncthreads();
    #pragma unroll
    for (int rb = 0; rb < 2; ++rb)
        #pragma unroll
        for (int cb = 0; cb < 4; ++cb) {
            int lrb = r0 + rb * 16 + (lane >> 4) * 4;
            int col = c0 + cb * 16 + (lane & 15);
            #pragma unroll
            for (int reg = 0; reg < 4; ++reg)
                bounce[(lrb + reg) * 128 + col] = f2bf(acc[rb][cb][reg]);
        }
    __syncthreads();
    unsigned short* pout = part + (size_t)by * MPAD * NH + (size_t)m0 * NH;
    #pragma unroll
    for (int t = 0; t < 4; ++t) {
        int flat = tid + t * 256;
        *(bf16x8*)(pout + flat * 8) = *(const bf16x8*)(bounce + flat * 8);
    }
}

// ---------------------------------------------------------------------------
// x @ W_in.T split-K (4 chunks of 16 K-steps), pipelined ping-pong.
// by==0 blocks additionally pack LSTM/GS weights to bf16 (wl, wgb) at the end.
// ---------------------------------------------------------------------------
__global__ __launch_bounds__(256) void xw_mfma_kernel(const float* __restrict__ x,
                                                      const float* __restrict__ Wn,
                                                      float* __restrict__ part,
                                                      const float* __restrict__ Wih0,
                                                      const float* __restrict__ Whh0,
                                                      const float* __restrict__ Wih1,
                                                      const float* __restrict__ Whh1,
                                                      const float* __restrict__ Wgs,
                                                      unsigned short* __restrict__ wl,
                                                      unsigned short* __restrict__ wgb)
{
    __shared__ unsigned short sa[2][64 * 32];
    __shared__ unsigned short sb[2][128 * 32];
    const int tid  = threadIdx.x;
    const int lane = tid & 63, w = tid >> 6;
    const int m0   = blockIdx.x * 64;
    const int TOT  = (NFEAT + 31) / 32;                 // 63
    const int s0   = blockIdx.y * 16;
    const int s1   = min(s0 + 16, TOT);
    const int r0   = (w & 1) * 32;
    const int c0   = (w >> 1) * 64;

    const int arow = tid >> 2, agrp = tid & 3;
    const size_t abase = (size_t)min(m0 + arow, N_NODES - 1) * NFEAT;
    const int asoff = arow * 32 + ((agrp ^ (arow & 3)) << 3);
    int bn_[2], bgrp_[2], bsoff_[2];
    #pragma unroll
    for (int t = 0; t < 2; ++t) {
        int gi = tid + t * 256;
        bn_[t] = gi >> 2; bgrp_[t] = gi & 3;
        bsoff_[t] = bn_[t] * 32 + ((bgrp_[t] ^ (bn_[t] & 3)) << 3);
    }

    f32x4 acc[2][4];
    #pragma unroll
    for (int i = 0; i < 2; ++i)
        #pragma unroll
        for (int j = 0; j < 4; ++j) acc[i][j] = (f32x4){0.f, 0.f, 0.f, 0.f};

    float av8[8], bv8[2][8];
    auto load_step = [&](int ks) {
        const int k0 = ks * 32;
        {
            const int kg = k0 + agrp * 8;
            if (kg + 8 <= NFEAT) {
                float4 u0 = *(const float4*)(x + abase + kg);
                float4 u1 = *(const float4*)(x + abase + kg + 4);
                av8[0]=u0.x; av8[1]=u0.y; av8[2]=u0.z; av8[3]=u0.w;
                av8[4]=u1.x; av8[5]=u1.y; av8[6]=u1.z; av8[7]=u1.w;
            } else {
                #pragma unroll
                for (int i = 0; i < 8; ++i) av8[i] = 0.f;
            }
        }
        #pragma unroll
        for (int t = 0; t < 2; ++t) {
            int kg = k0 + bgrp_[t] * 8;
            if (kg + 8 <= NFEAT) {
                float4 u0 = *(const float4*)(Wn + (size_t)bn_[t] * NFEAT + kg);
                float4 u1 = *(const float4*)(Wn + (size_t)bn_[t] * NFEAT + kg + 4);
                bv8[t][0]=u0.x; bv8[t][1]=u0.y; bv8[t][2]=u0.z; bv8[t][3]=u0.w;
                bv8[t][4]=u1.x; bv8[t][5]=u1.y; bv8[t][6]=u1.z; bv8[t][7]=u1.w;
            } else {
                #pragma unroll
                for (int i = 0; i < 8; ++i) bv8[t][i] = 0.f;
            }
        }
    };
    auto write_step = [&](int p) {
        *(bf16x8*)(sa[p] + asoff) = cvt8(av8);
        #pragma unroll
        for (int t = 0; t < 2; ++t)
            *(bf16x8*)(sb[p] + bsoff_[t]) = cvt8(bv8[t]);
    };

    load_step(s0);
    write_step(0);

    for (int ks = s0; ks < s1; ++ks) {
        const int p = (ks - s0) & 1;
        const bool more = (ks + 1 < s1);
        if (more) load_step(ks + 1);
        __syncthreads();
        bf16x8 av[2], bv[4];
        #pragma unroll
        for (int rb = 0; rb < 2; ++rb) {
            int row = r0 + rb * 16 + (lane & 15);
            int g   = lane >> 4;
            av[rb] = *(const bf16x8*)(sa[p] + row * 32 + ((g ^ (row & 3)) << 3));
        }
        #pragma unroll
        for (int cb = 0; cb < 4; ++cb) {
            int col = c0 + cb * 16 + (lane & 15);
            int g   = lane >> 4;
            bv[cb] = *(const bf16x8*)(sb[p] + col * 32 + ((g ^ (col & 3)) << 3));
        }
        #pragma unroll
        for (int rb = 0; rb < 2; ++rb)
            #pragma unroll
            for (int cb = 0; cb < 4; ++cb)
                acc[rb][cb] = __builtin_amdgcn_mfma_f32_16x16x32_bf16(av[rb], bv[cb],
                                                                      acc[rb][cb], 0, 0, 0);
        if (more) write_step(p ^ 1);
    }
    float* pout = part + (size_t)blockIdx.y * MPAD * NH;
    #pragma unroll
    for (int rb = 0; rb < 2; ++rb)
        #pragma unroll
        for (int cb = 0; cb < 4; ++cb) {
            int rowb = m0 + r0 + rb * 16 + (lane >> 4) * 4;
            int col  = c0 + cb * 16 + (lane & 15);
            #pragma unroll
            for (int reg = 0; reg < 4; ++reg)
                pout[(size_t)(rowb + reg) * NH + col] = acc[rb][cb][reg];
        }

    // fold-in: pack weights to bf16 (consumers run after adjmm0/gs0)
    if (blockIdx.y == 0) {
        const int total = 262144 + 65536;
        for (int i = blockIdx.x * 256 + tid; i < total; i += MT * 256) {
            if (i < 262144) {
                int l = i >> 17, rem = i & 131071;
                int n = rem >> 8, k = rem & 255;
                const float* src;
                if (l == 0) src = (k < 128) ? (Wih0 + n * 128 + k) : (Whh0 + n * 128 + (k - 128));
                else        src = (k < 128) ? (Wih1 + n * 128 + k) : (Whh1 + n * 128 + (k - 128));
                wl[i] = f2bf(*src);
            } else {
                int j = i - 262144;
                wgb[j] = f2bf(Wgs[j]);
            }
        }
    }
}

// ---------------------------------------------------------------------------
// h_in = elu(bn_in(sum part + b_in)); also writes h_inT bf16 [128][KP] + pad
// ---------------------------------------------------------------------------
__global__ __launch_bounds__(256) void xw_reduce_kernel(const float* __restrict__ part,
                                                        const float* __restrict__ bias,
                                                        const float* __restrict__ g,
                                                        const float* __restrict__ bb,
                                                        const float* __restrict__ rm,
                                                        const float* __restrict__ rv,
                                                        float* __restrict__ h,
                                                        unsigned short* __restrict__ hT)
{
    __shared__ unsigned short tb[128][8];
    const int tid = threadIdx.x;
    int idx = blockIdx.x * 256 + tid;
    const int c4 = (tid & 31) * 4;
    const int lr = tid >> 5;                       // 0..7
    const int m0g = blockIdx.x * 8;
    const size_t ch = (size_t)MPAD * NH / 4;
    const float4* p = (const float4*)part;
    float a[4] = {0.f, 0.f, 0.f, 0.f};
    #pragma unroll
    for (int c = 0; c < NSPLX; ++c) {
        float4 v = p[c * ch + idx];
        a[0] += v.x; a[1] += v.y; a[2] += v.z; a[3] += v.w;
    }
    float o[4];
    #pragma unroll
    for (int j = 0; j < 4; ++j) {
        int c = c4 + j;
        float sc = g[c] / sqrtf(rv[c] + BN_EPS);
        float t = (a[j] + bias[c] - rm[c]) * sc + bb[c];
        o[j] = t > 0.f ? t : expm1f(t);
        tb[c][lr] = f2bf(o[j]);
    }
    float4 ov; ov.x = o[0]; ov.y = o[1]; ov.z = o[2]; ov.w = o[3];
    *(float4*)(h + (size_t)idx * 4) = ov;
    __syncthreads();
    if (tid < 128) {
        ushort4 v0, v1;
        v0.x = tb[tid][0]; v0.y = tb[tid][1]; v0.z = tb[tid][2]; v0.w = tb[tid][3];
        v1.x = tb[tid][4]; v1.y = tb[tid][5]; v1.z = tb[tid][6]; v1.w = tb[tid][7];
        *(ushort4*)(hT + (size_t)tid * KP + m0g)     = v0;
        *(ushort4*)(hT + (size_t)tid * KP + m0g + 4) = v1;
        if (blockIdx.x == 0) {                     // zero the K-pad [10000,10016)
            ushort4 zz; zz.x = zz.y = zz.z = zz.w = 0;
            #pragma unroll
            for (int q = 0; q < 4; ++q)
                *(ushort4*)(hT + (size_t)tid * KP + 10000 + q * 4) = zz;
        }
    }
}

// ---------------------------------------------------------------------------
// GraphSAGE fused (+nreduce): A = [h | (sum_c bf16 part)/rowsum];
// jk = rownorm(relu(A@Wg^T + bg)); opt. jkT bf16. BM=64, K=256, grid MT.
// ---------------------------------------------------------------------------
template<bool WRITE_T>
__global__ __launch_bounds__(256) void gs_fused_kernel(const float* __restrict__ h,
                                                       const unsigned short* __restrict__ part,
                                                       const float* __restrict__ part_s,
                                                       const unsigned short* __restrict__ Wg,
                                                       const float* __restrict__ bg,
                                                       float* __restrict__ jk,
                                                       unsigned short* __restrict__ jkT)
{
    __shared__ unsigned short sa[64 * 32];
    __shared__ unsigned short sb[128 * 32];
    __shared__ float ssq_l[64][2];
    __shared__ unsigned short tb[WRITE_T ? 128 * 64 : 1];
    const int tid  = threadIdx.x;
    const int lane = tid & 63, w = tid >> 6;
    const int m0   = blockIdx.x * 64;
    const int r0   = (w & 1) * 32;
    const int c0   = (w >> 1) * 64;
    const int arow = tid >> 2, agrp = tid & 3;
    const int mg   = min(m0 + arow, N_NODES - 1);

    float inv;
    {
        float s = 0.f;
        #pragma unroll
        for (int c = 0; c < NSPLIT; ++c) s += part_s[(size_t)c * MPAD + mg];
        inv = 1.0f / s;
    }

    f32x4 acc[2][4];
    #pragma unroll
    for (int i = 0; i < 2; ++i)
        #pragma unroll
        for (int j = 0; j < 4; ++j) acc[i][j] = (f32x4){0.f, 0.f, 0.f, 0.f};

    for (int k0 = 0; k0 < 256; k0 += 32) {
        const int kg = k0 + agrp * 8;
        float a8[8];
        if (kg < 128) {
            const float* asrc = h + (size_t)mg * NH + kg;
            float4 u0 = *(const float4*)asrc;
            float4 u1 = *(const float4*)(asrc + 4);
            a8[0]=u0.x; a8[1]=u0.y; a8[2]=u0.z; a8[3]=u0.w;
            a8[4]=u1.x; a8[5]=u1.y; a8[6]=u1.z; a8[7]=u1.w;
        } else {
            const int cc = kg - 128;
            float s[8] = {0.f,0.f,0.f,0.f,0.f,0.f,0.f,0.f};
            #pragma unroll
            for (int c = 0; c < NSPLIT; ++c) {
                bf16x8 v = *(const bf16x8*)(part + (size_t)c * MPAD * NH + (size_t)mg * NH + cc);
                #pragma unroll
                for (int i = 0; i < 8; ++i) s[i] += bf2f((unsigned short)v[i]);
            }
            #pragma unroll
            for (int i = 0; i < 8; ++i) a8[i] = s[i] * inv;
        }
        bf16x8 b8[2];
        #pragma unroll
        for (int t = 0; t < 2; ++t) {
            int gi = tid + t * 256;
            int n = gi >> 2, grp = gi & 3;
            b8[t] = *(const bf16x8*)(Wg + (size_t)n * 256 + k0 + grp * 8);
        }
        __syncthreads();
        *(bf16x8*)(sa + arow * 32 + ((agrp ^ (arow & 3)) << 3)) = cvt8(a8);
        #pragma unroll
        for (int t = 0; t < 2; ++t) {
            int gi = tid + t * 256;
            int n = gi >> 2, grp = gi & 3;
            *(bf16x8*)(sb + n * 32 + ((grp ^ (n & 3)) << 3)) = b8[t];
        }
        __syncthreads();
        bf16x8 av[2], bv[4];
        #pragma unroll
        for (int rb = 0; rb < 2; ++rb) {
            int row = r0 + rb * 16 + (lane & 15);
            int g   = lane >> 4;
            av[rb] = *(const bf16x8*)(sa + row * 32 + ((g ^ (row & 3)) << 3));
        }
        #pragma unroll
        for (int cb = 0; cb < 4; ++cb) {
            int col = c0 + cb * 16 + (lane & 15);
            int g   = lane >> 4;
            bv[cb] = *(const bf16x8*)(sb + col * 32 + ((g ^ (col & 3)) << 3));
        }
        #pragma unroll
        for (int rb = 0; rb < 2; ++rb)
            #pragma unroll
            for (int cb = 0; cb < 4; ++cb)
                acc[rb][cb] = __builtin_amdgcn_mfma_f32_16x16x32_bf16(av[rb], bv[cb],
                                                                      acc[rb][cb], 0, 0, 0);
    }

    float vv[2][4][4];
    float ps[2][4] = {};
    #pragma unroll
    for (int rb = 0; rb < 2; ++rb)
        #pragma unroll
        for (int cb = 0; cb < 4; ++cb) {
            int colg = c0 + cb * 16 + (lane & 15);
            float b = bg[colg];
            #pragma unroll
            for (int reg = 0; reg < 4; ++reg) {
                float t = fmaxf(acc[rb][cb][reg] + b, 0.f);
                vv[rb][cb][reg] = t;
                ps[rb][reg] += t * t;
            }
        }
    #pragma unroll
    for (int msk = 1; msk < 16; msk <<= 1)
        #pragma unroll
        for (int rb = 0; rb < 2; ++rb)
            #pragma unroll
            for (int reg = 0; reg < 4; ++reg)
                ps[rb][reg] += __shfl_xor(ps[rb][reg], msk);
    if ((lane & 15) == 0) {
        #pragma unroll
        for (int rb = 0; rb < 2; ++rb)
            #pragma unroll
            for (int reg = 0; reg < 4; ++reg)
                ssq_l[r0 + rb * 16 + (lane >> 4) * 4 + reg][w >> 1] = ps[rb][reg];
    }
    __syncthreads();
    #pragma unroll
    for (int rb = 0; rb < 2; ++rb)
        #pragma unroll
        for (int reg = 0; reg < 4; ++reg) {
            int lr = r0 + rb * 16 + (lane >> 4) * 4 + reg;
            float s = ssq_l[lr][0] + ssq_l[lr][1];
            float sc = 1.0f / fmaxf(sqrtf(s), 1e-12f);
            int m = m0 + lr;
            #pragma unroll
            for (int cb = 0; cb < 4; ++cb) {
                int colg = c0 + cb * 16 + (lane & 15);
                float o = vv[rb][cb][reg] * sc;
                if (m < N_NODES) jk[(size_t)m * NH + colg] = o;
                if constexpr (WRITE_T) tb[colg * 64 + lr] = f2bf(o);
            }
        }
    if constexpr (WRITE_T) {
        __syncthreads();
        #pragma unroll
        for (int p = 0; p < 4; ++p) {
            int flat = (tid + p * 256) * 8;
            int c = flat >> 6, mo = flat & 63;
            int kglob = m0 + mo;
            if (kglob < KP) {
                unsigned short tmp[8];
                #pragma unroll
                for (int i = 0; i < 8; ++i)
                    tmp[i] = (kglob + i < N_NODES) ? tb[c * 64 + mo + i] : (unsigned short)0;
                ushort4 v0, v1;
                v0.x = tmp[0]; v0.y = tmp[1]; v0.z = tmp[2]; v0.w = tmp[3];
                v1.x = tmp[4]; v1.y = tmp[5]; v1.z = tmp[6]; v1.w = tmp[7];
                *(ushort4*)(jkT + (size_t)c * KP + kglob)     = v0;
                *(ushort4*)(jkT + (size_t)c * KP + kglob + 4) = v1;
            }
        }
    }
}

// ---------------------------------------------------------------------------
// Full LSTM JK chain in one kernel: 4 steps, h-states in LDS, c in registers.
// BM=32 rows/block, grid 313. Final step fuses JK-mean + bn_in + ELU -> hpost.
// ---------------------------------------------------------------------------
__global__ __launch_bounds__(256) void lstm4_kernel(
    const float* __restrict__ jk0, const float* __restrict__ jk1,
    const unsigned short* __restrict__ wl,   // [2][512][256] bf16
    const float* __restrict__ bih0, const float* __restrict__ bhh0,
    const float* __restrict__ bih1, const float* __restrict__ bhh1,
    const float* __restrict__ bng, const float* __restrict__ bnb,
    const float* __restrict__ bnrm, const float* __restrict__ bnrv,
    float* __restrict__ hpost)
{
    __shared__ unsigned short sa[32 * 32];
    __shared__ unsigned short sb[512 * 32];
    __shared__ unsigned short hb[2][32][136];   // +8 pad
    const int tid = threadIdx.x, lane = tid & 63, w = tid >> 6;
    const int m0 = blockIdx.x * 32;
    const int arow = tid >> 2, agrp = tid & 3;  // A staging (tid<128)
    const int mg = min(m0 + arow, N_NODES - 1);

    f32x4 acc[2][8];
    float cst[2][2][4];

    auto zacc = [&] {
        #pragma unroll
        for (int i = 0; i < 2; ++i)
            #pragma unroll
            for (int j = 0; j < 8; ++j) acc[i][j] = (f32x4){0.f, 0.f, 0.f, 0.f};
    };
    auto stage_sb = [&](const unsigned short* wlayer, int k0) {
        #pragma unroll
        for (int t = 0; t < 8; ++t) {
            int gi = tid + t * 256, n = gi >> 2, grp = gi & 3;
            *(bf16x8*)(sb + n * 32 + ((grp ^ (n & 3)) << 3)) =
                *(const bf16x8*)(wlayer + (size_t)n * 256 + k0 + grp * 8);
        }
    };
    auto stage_sa = [&](const float* a, int k0) {
        if (tid < 128) {
            int kg = k0 + agrp * 8;
            const float* src = a + (size_t)mg * NH + kg;
            float4 u0 = *(const float4*)src, u1 = *(const float4*)(src + 4);
            float a8[8] = {u0.x, u0.y, u0.z, u0.w, u1.x, u1.y, u1.z, u1.w};
            *(bf16x8*)(sa + arow * 32 + ((agrp ^ (arow & 3)) << 3)) = cvt8(a8);
        }
    };
    auto av_sa = [&](int rb) {
        int row = rb * 16 + (lane & 15), g = lane >> 4;
        return *(const bf16x8*)(sa + row * 32 + ((g ^ (row & 3)) << 3));
    };
    auto av_hb = [&](int i, int rb, int kl) {
        int row = rb * 16 + (lane & 15), g = lane >> 4;
        return *(const bf16x8*)(&hb[i][row][kl + g * 8]);
    };
    auto mfma_all = [&](bf16x8 a0, bf16x8 a1) {
        #pragma unroll
        for (int gate = 0; gate < 4; ++gate)
            #pragma unroll
            for (int cb = 0; cb < 2; ++cb) {
                int col = gate * 128 + w * 32 + cb * 16 + (lane & 15);
                int g = lane >> 4;
                bf16x8 bv = *(const bf16x8*)(sb + col * 32 + ((g ^ (col & 3)) << 3));
                acc[0][gate * 2 + cb] =
                    __builtin_amdgcn_mfma_f32_16x16x32_bf16(a0, bv, acc[0][gate * 2 + cb], 0, 0, 0);
                acc[1][gate * 2 + cb] =
                    __builtin_amdgcn_mfma_f32_16x16x32_bf16(a1, bv, acc[1][gate * 2 + cb], 0, 0, 0);
            }
    };
    auto epi = [&](const float* bih, const float* bhh, bool hasc, int hdst, bool fin) {
        __syncthreads();
        #pragma unroll
        for (int cb = 0; cb < 2; ++cb) {
            int cg = w * 32 + cb * 16 + (lane & 15);
            float bi  = bih[cg]       + bhh[cg];
            float bf_ = bih[128 + cg] + bhh[128 + cg];
            float bgg = bih[256 + cg] + bhh[256 + cg];
            float bo  = bih[384 + cg] + bhh[384 + cg];
            float sc = 0.f, sh = 0.f;
            if (fin) {
                sc = bng[cg] / sqrtf(bnrv[cg] + BN_EPS);
                sh = bnb[cg] - bnrm[cg] * sc;
            }
            #pragma unroll
            for (int rb = 0; rb < 2; ++rb)
                #pragma unroll
                for (int reg = 0; reg < 4; ++reg) {
                    int lr = rb * 16 + (lane >> 4) * 4 + reg;
                    float zi = acc[rb][0 + cb][reg] + bi;
                    float zf = acc[rb][2 + cb][reg] + bf_;
                    float zg = acc[rb][4 + cb][reg] + bgg;
                    float zo = acc[rb][6 + cb][reg] + bo;
                    float cn = sigm(zi) * tanhf(zg);
                    if (hasc) cn += sigm(zf) * cst[rb][cb][reg];
                    cst[rb][cb][reg] = cn;
                    float hv = sigm(zo) * tanhf(cn);
                    if (fin) {
                        float hm = bf2f(hb[0][lr][cg]);     // h2_0
                        float t = 0.5f * (hm + hv);
                        t = t * sc + sh;
                        int m = m0 + lr;
                        if (m < N_NODES) hpost[(size_t)m * NH + cg] = t > 0.f ? t : expm1f(t);
                    } else {
                        hb[hdst][lr][cg] = f2bf(hv);
                    }
                }
        }
        __syncthreads();
    };

    // step0: L1 t0, A = jk0, K=128
    zacc();
    for (int k0 = 0; k0 < 128; k0 += 32) {
        __syncthreads();
        stage_sa(jk0, k0);
        stage_sb(wl, k0);
        __syncthreads();
        mfma_all(av_sa(0), av_sa(1));
    }
    epi(bih0, bhh0, false, 0, false);           // h1_0 -> hb0

    // step1: L1 t1, A = [jk1 | hb0], K=256
    zacc();
    for (int k0 = 0; k0 < 256; k0 += 32) {
        __syncthreads();
        if (k0 < 128) stage_sa(jk1, k0);
        stage_sb(wl, k0);
        __syncthreads();
        if (k0 < 128) mfma_all(av_sa(0), av_sa(1));
        else          mfma_all(av_hb(0, 0, k0 - 128), av_hb(0, 1, k0 - 128));
    }
    epi(bih0, bhh0, true, 1, false);            // h1_1 -> hb1

    // step2: L2 t0, A = hb0 (h1_0), K=128
    const unsigned short* wl1 = wl + 512 * 256;
    zacc();
    for (int k0 = 0; k0 < 128; k0 += 32) {
        __syncthreads();
        stage_sb(wl1, k0);
        __syncthreads();
        mfma_all(av_hb(0, 0, k0), av_hb(0, 1, k0));
    }
    epi(bih1, bhh1, false, 0, false);           // h2_0 -> hb0

    // step3: L2 t1, A = [hb1 | hb0] = [h1_1 | h2_0], K=256, FINAL
    zacc();
    for (int k0 = 0; k0 < 256; k0 += 32) {
        __syncthreads();
        stage_sb(wl1, k0);
        __syncthreads();
        if (k0 < 128) mfma_all(av_hb(1, 0, k0), av_hb(1, 1, k0));
        else          mfma_all(av_hb(0, 0, k0 - 128), av_hb(0, 1, k0 - 128));
    }
    epi(bih1, bhh1, true, -1, true);            // hpost out
}

// ---------------------------------------------------------------------------
// Epilogue: e=elu(bn(embed@W_emb^T)) -> LDS; hfc=elu(bn([hpost|e]@W_fc^T))
// -> LDS; out = log_softmax(hfc@W_out^T + b). BM=64, grid MT.
// ---------------------------------------------------------------------------
__global__ __launch_bounds__(256) void epilogue_kernel(
    const float* __restrict__ embed,
    const float* __restrict__ W_emb, const float* __restrict__ b_emb,
    const float* __restrict__ bn_e_g, const float* __restrict__ bn_e_b,
    const float* __restrict__ bn_e_rm, const float* __restrict__ bn_e_rv,
    const float* __restrict__ hpost,
    const float* __restrict__ W_fc, const float* __restrict__ b_fc,
    const float* __restrict__ bn_f_g, const float* __restrict__ bn_f_b,
    const float* __restrict__ bn_f_rm, const float* __restrict__ bn_f_rv,
    const float* __restrict__ W_out, const float* __restrict__ b_out,
    float* __restrict__ out)
{
    __shared__ unsigned short sa[64 * 32];
    __shared__ unsigned short sb[192 * 32];
    __shared__ unsigned short ebuf[64][72];
    __shared__ float fbuf[64][204];
    const int tid = threadIdx.x, lane = tid & 63, w = tid >> 6;
    const int m0 = blockIdx.x * 64;
    const int arow = tid >> 2, agrp = tid & 3;
    const int mg = min(m0 + arow, N_NODES - 1);
    const int g = lane >> 4;

    // ---- phase E ----
    f32x4 aE[4];
    #pragma unroll
    for (int j = 0; j < 4; ++j) aE[j] = (f32x4){0.f, 0.f, 0.f, 0.f};
    for (int k0 = 0; k0 < NFE; k0 += 32) {
        float a8[8], b8[8];
        {
            const float* s = embed + (size_t)mg * NFE + k0 + agrp * 8;
            float4 u0 = *(const float4*)s, u1 = *(const float4*)(s + 4);
            a8[0]=u0.x; a8[1]=u0.y; a8[2]=u0.z; a8[3]=u0.w;
            a8[4]=u1.x; a8[5]=u1.y; a8[6]=u1.z; a8[7]=u1.w;
        }
        {
            const float* s = W_emb + (size_t)arow * NFE + k0 + agrp * 8;  // arow<64=NHE
            float4 u0 = *(const float4*)s, u1 = *(const float4*)(s + 4);
            b8[0]=u0.x; b8[1]=u0.y; b8[2]=u0.z; b8[3]=u0.w;
            b8[4]=u1.x; b8[5]=u1.y; b8[6]=u1.z; b8[7]=u1.w;
        }
        __syncthreads();
        *(bf16x8*)(sa + arow * 32 + ((agrp ^ (arow & 3)) << 3)) = cvt8(a8);
        *(bf16x8*)(sb + arow * 32 + ((agrp ^ (arow & 3)) << 3)) = cvt8(b8);
        __syncthreads();
        bf16x8 av;
        { int row = w * 16 + (lane & 15);
          av = *(const bf16x8*)(sa + row * 32 + ((g ^ (row & 3)) << 3)); }
        #pragma unroll
        for (int cb = 0; cb < 4; ++cb) {
            int col = cb * 16 + (lane & 15);
            bf16x8 bv = *(const bf16x8*)(sb + col * 32 + ((g ^ (col & 3)) << 3));
            aE[cb] = __builtin_amdgcn_mfma_f32_16x16x32_bf16(av, bv, aE[cb], 0, 0, 0);
        }
    }
    #pragma unroll
    for (int cb = 0; cb < 4; ++cb) {
        int col = cb * 16 + (lane & 15);
        float sc = bn_e_g[col] / sqrtf(bn_e_rv[col] + BN_EPS);
        float sh = bn_e_b[col] - bn_e_rm[col] * sc;
        float bb = b_emb[col];
        #pragma unroll
        for (int reg = 0; reg < 4; ++reg) {
            int row = w * 16 + (lane >> 4) * 4 + reg;
            float t = (aE[cb][reg] + bb) * sc + sh;
            ebuf[row][col] = f2bf(t > 0.f ? t : expm1f(t));
        }
    }
    __syncthreads();

    // ---- phase F ----
    f32x4 aF[4][3];
    #pragma unroll
    for (int i = 0; i < 4; ++i)
        #pragma unroll
        for (int j = 0; j < 3; ++j) aF[i][j] = (f32x4){0.f, 0.f, 0.f, 0.f};
    for (int k0 = 0; k0 < DCAT; k0 += 32) {
        const bool gl = (k0 < 128);
        float b8[3][8];
        #pragma unroll
        for (int t = 0; t < 3; ++t) {
            int gi = tid + t * 256, n = gi >> 2, grp = gi & 3;
            const float* s = W_fc + (size_t)n * DCAT + k0 + grp * 8;
            float4 u0 = *(const float4*)s, u1 = *(const float4*)(s + 4);
            b8[t][0]=u0.x; b8[t][1]=u0.y; b8[t][2]=u0.z; b8[t][3]=u0.w;
            b8[t][4]=u1.x; b8[t][5]=u1.y; b8[t][6]=u1.z; b8[t][7]=u1.w;
        }
        float a8[8];
        if (gl) {
            const float* s = hpost + (size_t)mg * NH + k0 + agrp * 8;
            float4 u0 = *(const float4*)s, u1 = *(const float4*)(s + 4);
            a8[0]=u0.x; a8[1]=u0.y; a8[2]=u0.z; a8[3]=u0.w;
            a8[4]=u1.x; a8[5]=u1.y; a8[6]=u1.z; a8[7]=u1.w;
        }
        __syncthreads();
        if (gl) *(bf16x8*)(sa + arow * 32 + ((agrp ^ (arow & 3)) << 3)) = cvt8(a8);
        #pragma unroll
        for (int t = 0; t < 3; ++t) {
            int gi = tid + t * 256, n = gi >> 2, grp = gi & 3;
            *(bf16x8*)(sb + n * 32 + ((grp ^ (n & 3)) << 3)) = cvt8(b8[t]);
        }
        __syncthreads();
        #pragma unroll
        for (int rf = 0; rf < 4; ++rf) {
            int row = rf * 16 + (lane & 15);
            bf16x8 av = gl ? *(const bf16x8*)(sa + row * 32 + ((g ^ (row & 3)) << 3))
                           : *(const bf16x8*)(&ebuf[row][(k0 - 128) + g * 8]);
            #pragma unroll
            for (int cf = 0; cf < 3; ++cf) {
                int col = w * 48 + cf * 16 + (lane & 15);
                bf16x8 bv = *(const bf16x8*)(sb + col * 32 + ((g ^ (col & 3)) << 3));
                aF[rf][cf] = __builtin_amdgcn_mfma_f32_16x16x32_bf16(av, bv, aF[rf][cf], 0, 0, 0);
            }
        }
    }
    #pragma unroll
    for (int cf = 0; cf < 3; ++cf) {
        int col = w * 48 + cf * 16 + (lane & 15);
        float sc = bn_f_g[col] / sqrtf(bn_f_rv[col] + BN_EPS);
        float sh = bn_f_b[col] - bn_f_rm[col] * sc;
        float bb = b_fc[col];
        #pragma unroll
        for (int rf = 0; rf < 4; ++rf)
            #pragma unroll
            for (int reg = 0; reg < 4; ++reg) {
                int row = rf * 16 + (lane >> 4) * 4 + reg;
                float t = (aF[rf][cf][reg] + bb) * sc + sh;
                fbuf[row][col] = t > 0.f ? t : expm1f(t);
            }
    }
    __syncthreads();

    // ---- phase O ----
    f32x4 aO[2];
    aO[0] = (f32x4){0.f, 0.f, 0.f, 0.f};
    aO[1] = (f32x4){0.f, 0.f, 0.f, 0.f};
    for (int k0 = 0; k0 < DCAT; k0 += 32) {
        float b8[8];
        const bool act = tid < 128;                       // 32 out-cols x 4 granules
        if (act) {
            if (arow < NOUT) {
                const float* s = W_out + (size_t)arow * DCAT + k0 + agrp * 8;
                float4 u0 = *(const float4*)s, u1 = *(const float4*)(s + 4);
                b8[0]=u0.x; b8[1]=u0.y; b8[2]=u0.z; b8[3]=u0.w;
                b8[4]=u1.x; b8[5]=u1.y; b8[6]=u1.z; b8[7]=u1.w;
            } else {
                #pragma unroll
                for (int i = 0; i < 8; ++i) b8[i] = 0.f;
            }
        }
        __syncthreads();
        if (act) *(bf16x8*)(sb + arow * 32 + ((agrp ^ (arow & 3)) << 3)) = cvt8(b8);
        __syncthreads();
        int row = w * 16 + (lane & 15);
        float4 f0 = *(const float4*)(&fbuf[row][k0 + g * 8]);
        float4 f1 = *(const float4*)(&fbuf[row][k0 + g * 8 + 4]);
        float f8[8] = {f0.x, f0.y, f0.z, f0.w, f1.x, f1.y, f1.z, f1.w};
        bf16x8 av = cvt8(f8);
        #pragma unroll
        for (int cf = 0; cf < 2; ++cf) {
            int col = cf * 16 + (lane & 15);
            bf16x8 bv = *(const bf16x8*)(sb + col * 32 + ((g ^ (col & 3)) << 3));
            aO[cf] = __builtin_amdgcn_mfma_f32_16x16x32_bf16(av, bv, aO[cf], 0, 0, 0);
        }
    }
    const int c0i = lane & 15, c1i = 16 + (lane & 15);
    const bool v1 = c1i < NOUT;
    #pragma unroll
    for (int reg = 0; reg < 4; ++reg) {
        int row = w * 16 + (lane >> 4) * 4 + reg;
        int m = m0 + row;
        float l0 = aO[0][reg] + b_out[c0i];
        float l1 = v1 ? (aO[1][reg] + b_out[c1i]) : -INFINITY;
        float mx = fmaxf(l0, l1);
        #pragma unroll
        for (int msk = 1; msk < 16; msk <<= 1) mx = fmaxf(mx, __shfl_xor(mx, msk));
        float s = expf(l0 - mx) + (v1 ? expf(l1 - mx) : 0.f);
        #pragma unroll
        for (int msk = 1; msk < 16; msk <<= 1) s += __shfl_xor(s, msk);
        float lse = mx + logf(s);
        if (m < N_NODES) {
            out[(size_t)m * NOUT + c0i] = l0 - lse;
            if (v1) out[(size_t)m * NOUT + c1i] = l1 - lse;
        }
    }
}

// ---------------------------------------------------------------------------
extern "C" void kernel_launch(void* const* d_in, const int* in_sizes, int n_in,
                              void* d_out, int out_size, void* d_ws, size_t ws_size,
                              hipStream_t stream)
{
    const float* x       = (const float*)d_in[0];
    const float* embed   = (const float*)d_in[1];
    const float* adj     = (const float*)d_in[2];
    const float* W_in    = (const float*)d_in[3];
    const float* b_in    = (const float*)d_in[4];
    const float* bn_in_g = (const float*)d_in[5];
    const float* bn_in_b = (const float*)d_in[6];
    const float* bn_in_rm= (const float*)d_in[7];
    const float* bn_in_rv= (const float*)d_in[8];
    const float* W_gs    = (const float*)d_in[9];
    const float* b_gs    = (const float*)d_in[10];
    const float* Wih0    = (const float*)d_in[11];
    const float* Whh0    = (const float*)d_in[12];
    const float* bih0    = (const float*)d_in[13];
    const float* bhh0    = (const float*)d_in[14];
    const float* Wih1    = (const float*)d_in[15];
    const float* Whh1    = (const float*)d_in[16];
    const float* bih1    = (const float*)d_in[17];
    const float* bhh1    = (const float*)d_in[18];
    const float* W_emb   = (const float*)d_in[19];
    const float* b_emb   = (const float*)d_in[20];
    const float* bn_e_g  = (const float*)d_in[21];
    const float* bn_e_b  = (const float*)d_in[22];
    const float* bn_e_rm = (const float*)d_in[23];
    const float* bn_e_rv = (const float*)d_in[24];
    const float* W_fc    = (const float*)d_in[25];
    const float* b_fc    = (const float*)d_in[26];
    const float* bn_f_g  = (const float*)d_in[27];
    const float* bn_f_b  = (const float*)d_in[28];
    const float* bn_f_rm = (const float*)d_in[29];
    const float* bn_f_rv = (const float*)d_in[30];
    const float* W_out   = (const float*)d_in[31];
    const float* b_out   = (const float*)d_in[32];
    float* outp = (float*)d_out;

    const size_t HB = (size_t)N_NODES * NH * sizeof(float);
    char* wp = (char*)d_ws;
    auto carve = [&](size_t bytes) {
        void* p = (void*)wp;
        wp += (bytes + 1023) & ~(size_t)1023;
        return p;
    };
    void* partRaw = carve((size_t)NSPLIT * MPAD * NH * 2);     // 41.2 MB (bf16 view)
    unsigned short* partB = (unsigned short*)partRaw;
    float* partF = (float*)partRaw;                             // xw f32 view (4 chunks fit)
    float* part_s= (float*)carve((size_t)NSPLIT * MPAD * sizeof(float));
    float* h_in  = (float*)carve(HB);
    float* jk0   = (float*)carve(HB);
    float* jk1   = (float*)carve(HB);
    float* hpost = (float*)carve(HB);
    unsigned short* hT  = (unsigned short*)carve((size_t)NH * KP * 2);
    unsigned short* wl  = (unsigned short*)carve((size_t)2 * 512 * 256 * 2);
    unsigned short* wgb = (unsigned short*)carve((size_t)2 * 128 * 256 * 2);
    if ((size_t)(wp - (char*)d_ws) > ws_size) return;

    const dim3 blk(256);

    // 1. h_in = elu(bn_in(x @ W_in.T + b_in)); also h_inT; weight packing folded in
    xw_mfma_kernel<<<dim3(MT, NSPLX), blk, 0, stream>>>(x, W_in, partF,
                                                        Wih0, Whh0, Wih1, Whh1, W_gs,
                                                        wl, wgb);
    xw_reduce_kernel<<<1250, blk, 0, stream>>>(partF, b_in, bn_in_g, bn_in_b,
                                               bn_in_rm, bn_in_rv, h_in, hT);

    // 2. GraphSAGE layer 0 (forward block order)
    adjmm_kernel<0><<<dim3(MT, NSPLIT), blk, 0, stream>>>(adj, hT, partB, part_s);
    gs_fused_kernel<true><<<MT, blk, 0, stream>>>(h_in, partB, part_s, wgb, b_gs, jk0, hT);

    // 3. GraphSAGE layer 1 (REVERSED block order -> L3 tail reuse of adj)
    adjmm_kernel<1><<<dim3(MT, NSPLIT), blk, 0, stream>>>(adj, hT, partB, part_s);
    gs_fused_kernel<false><<<MT, blk, 0, stream>>>(jk0, partB, part_s, wgb + 128 * 256,
                                                   b_gs + 128, jk1, nullptr);

    // 4. LSTM JK chain (4 steps in one kernel) + JK-mean + bn + elu
    lstm4_kernel<<<313, blk, 0, stream>>>(jk0, jk1, wl, bih0, bhh0, bih1, bhh1,
                                          bn_in_g, bn_in_b, bn_in_rm, bn_in_rv, hpost);

    // 5. emb + fc + log_softmax fused epilogue
    epilogue_kernel<<<MT, blk, 0, stream>>>(embed, W_emb, b_emb,
                                            bn_e_g, bn_e_b, bn_e_rm, bn_e_rv,
                                            hpost, W_fc, b_fc,
                                            bn_f_g, bn_f_b, bn_f_rm, bn_f_rv,
                                            W_out, b_out, outp);
}